// Round 4
// baseline (726.734 us; speedup 1.0000x reference)
//
#include <hip/hip_runtime.h>
#include <hip/hip_bf16.h>

// Problem constants (fixed by setup_inputs)
#define M_ROWS 262144   // B*A*T = 16*64*256
#define TILE_M 64
#define BK 32
#define REP 64          // second-level stats partials (matches finalize_k layout)
#define NBLOCKS 256     // persistent fused kernel: 1 block per CU
#define INVM (1.0f / 262144.0f)

typedef unsigned short ushort_t;
typedef unsigned int uint_t;
typedef __attribute__((ext_vector_type(8))) short short8_t;   // 8 bf16 = 4 VGPRs
typedef __attribute__((ext_vector_type(4))) float float4_t;   // MFMA acc

// bf16 (stored as ushort) <-> fp32 helpers. Load is exact; store is RNE.
__device__ __forceinline__ float b2f(ushort_t u) {
    union { uint_t i; float f; } c; c.i = ((uint_t)u) << 16; return c.f;
}
__device__ __forceinline__ ushort_t f2b(float f) {
    union { float f; uint_t i; } c; c.f = f;
    uint_t u = c.i;
    return (ushort_t)((u + 0x7fffu + ((u >> 16) & 1u)) >> 16);
}
// packed 2xfp32 -> 2xbf16 (v_cvt_pk_bf16_f32 on gfx950, RNE)
__device__ __forceinline__ uint_t pack2(float a, float b) {
    union { __hip_bfloat162 h; uint_t u; } c;
    c.h = __float22bfloat162_rn(make_float2(a, b));
    return c.u;
}

// async global->LDS DMA, 16 B per lane; data lands at ldsbase + lane*16
__device__ __forceinline__ void gld_lds16(const ushort_t* g, ushort_t* l) {
    __builtin_amdgcn_global_load_lds((const __attribute__((address_space(1))) void*)g,
                                     (__attribute__((address_space(3))) void*)l, 16, 0, 0);
}

// same-wave LDS ordering (all hazards are within one wave)
#define LGKM0 asm volatile("s_waitcnt lgkmcnt(0)" ::: "memory")

// ---------------------------------------------------------------------------
// Persistent fused L1..L4 kernel (cooperative), wave-independent decomposition
// with operand-swapped MFMA (Y^T = W^T * X^T):
//  - weight frags live in REGISTERS (A operand), loaded once per phase
//  - X frags: act -> private 8 KB LDS tile -> b128 frag reads (B operand)
//  - epilogue: bias+stats in regs, then a small swizzled LDS bounce so global
//    stores are 128 B-segment dwordx4 (r3's direct 8 B stores caused 32 B
//    scattered writes -> 2x HBM write amplification; this restores r2's
//    proven store pattern at ~100 cyc LDS cost)
//  - BN stats accumulated per-lane, reduced once per phase (shfl + atomics)
// L1's kt0 weight half stays in a 32 KB LDS tile to bound VGPR pressure.
// ---------------------------------------------------------------------------
struct __attribute__((aligned(16))) SmemT {
    ushort_t AW[8][4096];      // 64 KB  per-wave X-tile buffers (32 x 256B, XOR-swizzled)
    ushort_t Ws[128 * 128];    // 32 KB  L1 kt0 weight half [n][k0] (XOR-swizzled)
    float    s_sc[128];
    float    s_sh[128];
};

__device__ __forceinline__ void grid_sync(unsigned* cnt) {
    __syncthreads();
    if (threadIdx.x == 0) {
        __threadfence();
        __hip_atomic_fetch_add(cnt, 1u, __ATOMIC_ACQ_REL, __HIP_MEMORY_SCOPE_AGENT);
        while (__hip_atomic_load(cnt, __ATOMIC_ACQUIRE, __HIP_MEMORY_SCOPE_AGENT) < (unsigned)NBLOCKS) {
            __builtin_amdgcn_s_sleep(2);
        }
    }
    __syncthreads();
}

__device__ __forceinline__ void compute_scsh(SmemT& sm, const float* accum,
                                             const float* g, const float* be) {
    int f = threadIdx.x;
    if (f < 128) {
        float s = __hip_atomic_load(accum + f, __ATOMIC_RELAXED, __HIP_MEMORY_SCOPE_AGENT);
        float q = __hip_atomic_load(accum + 128 + f, __ATOMIC_RELAXED, __HIP_MEMORY_SCOPE_AGENT);
        float mean = s * INVM;
        float var = q * INVM - mean * mean;
        float sc = g[f] * rsqrtf(var + 1e-5f);
        sm.s_sc[f] = sc;
        sm.s_sh[f] = fmaf(-mean, sc, be[f]);
    }
    __syncthreads();
}

// One layer pass. KW: GEMM K (256 for L1 concat, else 128). NWT: total output
// cols (128 or 64); wave-task = (sequence, column-half). SCAN: causal cummax
// (in-lane serial, carries in regs). CONCAT: A = [act | cummax] (L1).
template<int KW, int NWT, bool SCAN, bool CONCAT, bool STATS, bool OUTF32>
__device__ __forceinline__ void phase_run(SmemT& sm, const ushort_t* __restrict__ Yin,
                                          char* __restrict__ Yout,
                                          const ushort_t* __restrict__ WT,
                                          const float* __restrict__ bias,
                                          float* __restrict__ accum, int blockRow0) {
    constexpr int NH = NWT / 2;      // cols per wave-task (64 or 32)
    constexpr int NT = NH / 16;      // 4 or 2
    constexpr int WB = KW * 2;       // WT row bytes

    const int tid = threadIdx.x;
    const int lane = tid & 63;
    const int wave = tid >> 6;       // 0..7
    const int seqw = wave >> 1;      // local sequence 0..3
    const int nh = wave & 1;         // column half
    const int quad = lane >> 4, l16 = lane & 15;
    const int row0 = blockRow0 + seqw * 256;
    char* AWb = (char*)sm.AW[wave];

    // ---- L1 only: stage kt0 weight half (128 n x 128 k) via swizzled DMA ----
    if constexpr (CONCAT) {
        #pragma unroll
        for (int i = 0; i < 4; ++i) {
            int tch = i * 8 + wave;
            int r = tch * 4 + (lane >> 4);
            int js = (lane & 15) ^ (r & 15);
            gld_lds16(WT + (size_t)r * 256 + js * 8, sm.Ws + tch * 512);
        }
        __syncthreads();   // DMA drained (vmcnt(0) before barrier) + visible
    }

    // bias for lane's n-range: n = nh*NH + nt*16 + quad*4 + rr
    float4 bv4[NT];
    #pragma unroll
    for (int nt = 0; nt < NT; ++nt)
        bv4[nt] = *(const float4*)&bias[nh * NH + nt * 16 + quad * 4];

    // hoisted weight frags (A operand): lane=n-row, quad=k-octet.
    // CONCAT: this is the kt1 (P) half, k-octets 16..31.
    short8_t wf[NT][4];
    #pragma unroll
    for (int nt = 0; nt < NT; ++nt)
        #pragma unroll
        for (int kk = 0; kk < 4; ++kk)
            wf[nt][kk] = *(const short8_t*)((const char*)WT +
                (size_t)(nh * NH + nt * 16 + l16) * WB +
                ((CONCAT ? 16 : 0) + kk * 4 + quad) * 16);

    // act coefficients for lane's input cols l16*8..+7
    float scr[8], shr[8];
    #pragma unroll
    for (int e = 0; e < 8; ++e) { scr[e] = sm.s_sc[l16 * 8 + e]; shr[e] = sm.s_sh[l16 * 8 + e]; }

    float sS[STATS ? NT : 1][4], sQ[STATS ? NT : 1][4];
    if constexpr (STATS) {
        #pragma unroll
        for (int nt = 0; nt < NT; ++nt)
            #pragma unroll
            for (int r = 0; r < 4; ++r) { sS[nt][r] = 0.f; sQ[nt][r] = 0.f; }
    }

    float run0 = 0.f, run1 = 0.f;    // scan carries (lane owns cols 2*lane, 2*lane+1)
    const int sc_r = lane >> 2;
    const int sc_b = (lane & 3) * 4;

    uint4 cur[8];
    {
        const uint4* p = (const uint4*)(Yin + (size_t)row0 * 128);
        #pragma unroll
        for (int u = 0; u < 8; ++u) cur[u] = p[u * 64 + lane];
    }

    for (int t = 0; t < 8; ++t) {
        // ---- act on current regs -> private LDS (32 x 256B, XOR-swizzled) ----
        #pragma unroll
        for (int u = 0; u < 8; ++u) {
            ushort_t e[8];
            *(uint4*)e = cur[u];
            uint_t w[4];
            #pragma unroll
            for (int z = 0; z < 4; ++z)
                w[z] = pack2(fmaxf(fmaf(b2f(e[2 * z]),     scr[2 * z],     shr[2 * z]),     0.f),
                             fmaxf(fmaf(b2f(e[2 * z + 1]), scr[2 * z + 1], shr[2 * z + 1]), 0.f));
            int ru = u * 4 + (lane >> 4);
            *(uint4*)(AWb + ru * 256 + ((l16 ^ (ru & 15)) & 15) * 16) = *(uint4*)w;
        }

        if (t < 7) {   // reissue input loads for next tile (cur regs just freed)
            const uint4* p = (const uint4*)(Yin + (size_t)(row0 + (t + 1) * 32) * 128);
            #pragma unroll
            for (int u = 0; u < 8; ++u) cur[u] = p[u * 64 + lane];
        }
        LGKM0;   // act tile committed before own-wave LDS reads

        float4_t acc[2][NT];
        #pragma unroll
        for (int mt = 0; mt < 2; ++mt)
            #pragma unroll
            for (int nt = 0; nt < NT; ++nt) acc[mt][nt] = (float4_t)0.f;

        if constexpr (CONCAT) {   // L1 kt0: act half, weights from LDS Ws
            #pragma unroll
            for (int kk = 0; kk < 4; ++kk) {
                int j = kk * 4 + quad;
                short8_t x0 = *(const short8_t*)(AWb + l16 * 256 + ((j ^ l16) & 15) * 16);
                short8_t x1 = *(const short8_t*)(AWb + (16 + l16) * 256 + ((j ^ l16) & 15) * 16);
                #pragma unroll
                for (int nt = 0; nt < NT; ++nt) {
                    short8_t w0 = *(const short8_t*)&sm.Ws[(nh * NH + nt * 16 + l16) * 128 +
                                                           ((j ^ l16) & 15) * 8];
                    acc[0][nt] = __builtin_amdgcn_mfma_f32_16x16x32_bf16(w0, x0, acc[0][nt], 0, 0, 0);
                    acc[1][nt] = __builtin_amdgcn_mfma_f32_16x16x32_bf16(w0, x1, acc[1][nt], 0, 0, 0);
                }
            }
            LGKM0;   // kt0 frag reads done before in-place scan writes
        }

        if constexpr (SCAN) {
            // in-lane serial cummax over 32 rows, two 16-row register chunks
            #pragma unroll
            for (int h = 0; h < 2; ++h) {
                uint_t sv[16];
                #pragma unroll
                for (int i = 0; i < 16; ++i) {
                    int r = h * 16 + i;
                    sv[i] = *(const uint_t*)(AWb + r * 256 + ((sc_r ^ (r & 15)) & 15) * 16 + sc_b);
                }
                #pragma unroll
                for (int i = 0; i < 16; ++i) {
                    int r = h * 16 + i;
                    run0 = fmaxf(run0, b2f((ushort_t)(sv[i] & 0xffff)));
                    run1 = fmaxf(run1, b2f((ushort_t)(sv[i] >> 16)));
                    *(uint_t*)(AWb + r * 256 + ((sc_r ^ (r & 15)) & 15) * 16 + sc_b) = pack2(run0, run1);
                }
            }
            LGKM0;   // P committed before own-wave frag reads
        }

        // main MFMA: hoisted weight frags (P-half for L1)
        #pragma unroll
        for (int kk = 0; kk < 4; ++kk) {
            int j = kk * 4 + quad;
            short8_t x0 = *(const short8_t*)(AWb + l16 * 256 + ((j ^ l16) & 15) * 16);
            short8_t x1 = *(const short8_t*)(AWb + (16 + l16) * 256 + ((j ^ l16) & 15) * 16);
            #pragma unroll
            for (int nt = 0; nt < NT; ++nt) {
                acc[0][nt] = __builtin_amdgcn_mfma_f32_16x16x32_bf16(wf[nt][kk], x0, acc[0][nt], 0, 0, 0);
                acc[1][nt] = __builtin_amdgcn_mfma_f32_16x16x32_bf16(wf[nt][kk], x1, acc[1][nt], 0, 0, 0);
            }
        }
        LGKM0;   // frag reads done before epilogue overwrites AWb

        // ---- epilogue: bias + stats in regs; swizzled bounce (32 x 128B) ----
        #pragma unroll
        for (int mt = 0; mt < 2; ++mt) {
            int row = mt * 16 + l16;
            #pragma unroll
            for (int nt = 0; nt < NT; ++nt) {
                float v0 = acc[mt][nt][0] + bv4[nt].x;
                float v1 = acc[mt][nt][1] + bv4[nt].y;
                float v2 = acc[mt][nt][2] + bv4[nt].z;
                float v3 = acc[mt][nt][3] + bv4[nt].w;
                if constexpr (STATS) {
                    sS[nt][0] += v0; sQ[nt][0] = fmaf(v0, v0, sQ[nt][0]);
                    sS[nt][1] += v1; sQ[nt][1] = fmaf(v1, v1, sQ[nt][1]);
                    sS[nt][2] += v2; sQ[nt][2] = fmaf(v2, v2, sQ[nt][2]);
                    sS[nt][3] += v3; sQ[nt][3] = fmaf(v3, v3, sQ[nt][3]);
                }
                if constexpr (OUTF32) {
                    int ch = nt * 4 + quad;                        // 0..7
                    *(float4*)(AWb + row * 128 + ((ch ^ (row & 7)) << 4)) =
                        make_float4(v0, v1, v2, v3);
                } else {
                    int cb = nt * 32 + quad * 8;                   // byte col in 128B row
                    int ch = cb >> 4;                              // 0..7
                    uint2 o; o.x = pack2(v0, v1); o.y = pack2(v2, v3);
                    *(uint2*)(AWb + row * 128 + ((ch ^ (row & 7)) << 4) + (cb & 15)) = o;
                }
            }
        }
        LGKM0;   // epi tile committed

        // ---- coalesced stores: 8 rows x 128 B contiguous per instruction ----
        {
            size_t gr0 = (size_t)row0 + (size_t)t * 32;
            #pragma unroll
            for (int p2 = 0; p2 < 4; ++p2) {
                int idx = p2 * 64 + lane;
                int dr = idx >> 3, ch = idx & 7;
                uint4 v = *(const uint4*)(AWb + dr * 128 + ((ch ^ (dr & 7)) << 4));
                *(uint4*)(Yout + (gr0 + dr) * 256 + nh * 128 + ch * 16) = v;
            }
        }
        LGKM0;   // bounce reads done before next tile's act writes
    }

    if constexpr (STATS) {
        // reduce over the 16 m-lanes (lane bits 0..3); quad selects n
        #pragma unroll
        for (int nt = 0; nt < NT; ++nt)
            #pragma unroll
            for (int rr = 0; rr < 4; ++rr) {
                float s = sS[nt][rr], q = sQ[nt][rr];
                s += __shfl_xor(s, 1); s += __shfl_xor(s, 2);
                s += __shfl_xor(s, 4); s += __shfl_xor(s, 8);
                q += __shfl_xor(q, 1); q += __shfl_xor(q, 2);
                q += __shfl_xor(q, 4); q += __shfl_xor(q, 8);
                if (l16 == 0) {
                    int n = nh * NH + nt * 16 + quad * 4 + rr;
                    atomicAdd(accum + n, s);
                    atomicAdd(accum + 128 + n, q);
                }
            }
    }
}

__launch_bounds__(512, 2)
__global__ void fused_k(ushort_t* h0, ushort_t* h1,
                        const ushort_t* wt1, const ushort_t* wt2,
                        const ushort_t* wt3, const ushort_t* wt4,
                        const float* b1, const float* b2, const float* b3, const float* b4,
                        const float* g1, const float* be1, const float* g2, const float* be2,
                        const float* g3, const float* be3,
                        const float* sc0, const float* sh0,
                        float* accum, float* out, unsigned* cnts) {
    __shared__ SmemT sm;
    const int blockRow0 = blockIdx.x * 1024;  // 4 sequences per block

    if (threadIdx.x < 128) {
        sm.s_sc[threadIdx.x] = sc0[threadIdx.x];
        sm.s_sh[threadIdx.x] = sh0[threadIdx.x];
    }
    __syncthreads();

    // L1: y1 = [bnrelu0(y0), cummax(bnrelu0(y0))] @ W1 + b1   (h0 -> h1)
    phase_run<256, 128, true, true, true, false>(sm, h0, (char*)h1, wt1, b1, accum, blockRow0);
    grid_sync(cnts + 0);
    compute_scsh(sm, accum, g1, be1);
    // L2: y2 = bnrelu1(y1) @ W2 + b2                          (h1 -> h0)
    phase_run<128, 128, false, false, true, false>(sm, h1, (char*)h0, wt2, b2, accum + 256, blockRow0);
    grid_sync(cnts + 1);
    compute_scsh(sm, accum + 256, g2, be2);
    // L3: y3 = cummax(bnrelu2(y2)) @ W3 + b3                  (h0 -> h1)
    phase_run<128, 128, true, false, true, false>(sm, h0, (char*)h1, wt3, b3, accum + 512, blockRow0);
    grid_sync(cnts + 2);
    compute_scsh(sm, accum + 512, g3, be3);
    // L4: out = bnrelu3(y3) @ W4 + b4 (fp32)                  (h1 -> out)
    phase_run<128, 64, false, false, false, true>(sm, h1, (char*)out, wt4, b4, nullptr, blockRow0);
}

// ---------------------------------------------------------------------------
// fp32 vector GEMM (layer 0: K=32, fp32 input) with fused stats partials.
// ---------------------------------------------------------------------------
template<int K, int N>
__launch_bounds__(256)
__global__ void gemm_f32_k(const float* __restrict__ A, const float* __restrict__ W,
                           const float* __restrict__ bias, ushort_t* __restrict__ C,
                           float* __restrict__ sumP, float* __restrict__ sqP) {
    constexpr int TX = N / 4;        // 32
    constexpr int TY = 256 / TX;     // 8
    constexpr int RM = TILE_M / TY;  // 8

    __shared__ float As[TILE_M][BK + 1];
    __shared__ float Ws[BK][N];
    __shared__ float redst[2][TY][N];

    const int tid = threadIdx.x;
    const int tx = tid % TX;
    const int ty = tid / TX;
    const int row0 = blockIdx.x * TILE_M;
    const int arow = tid >> 2;
    const int acol = (tid & 3) * 8;

    float acc[RM][4];
    #pragma unroll
    for (int r = 0; r < RM; ++r)
        #pragma unroll
        for (int c = 0; c < 4; ++c) acc[r][c] = 0.f;

    for (int k0 = 0; k0 < K; k0 += BK) {
        {
            const float4* p = (const float4*)&A[(size_t)(row0 + arow) * K + k0 + acol];
            float4 x0 = p[0], x1 = p[1];
            As[arow][acol + 0] = x0.x; As[arow][acol + 1] = x0.y;
            As[arow][acol + 2] = x0.z; As[arow][acol + 3] = x0.w;
            As[arow][acol + 4] = x1.x; As[arow][acol + 5] = x1.y;
            As[arow][acol + 6] = x1.z; As[arow][acol + 7] = x1.w;
        }
        #pragma unroll
        for (int i = 0; i < (BK * N) / 256; ++i) {
            int e = i * 256 + tid;
            Ws[e / N][e % N] = W[(size_t)(k0 + e / N) * N + e % N];
        }
        __syncthreads();
        #pragma unroll
        for (int kk = 0; kk < BK; ++kk) {
            float4 wv = *(const float4*)&Ws[kk][tx * 4];
            #pragma unroll
            for (int r = 0; r < RM; ++r) {
                float a = As[ty * RM + r][kk];
                acc[r][0] = fmaf(a, wv.x, acc[r][0]);
                acc[r][1] = fmaf(a, wv.y, acc[r][1]);
                acc[r][2] = fmaf(a, wv.z, acc[r][2]);
                acc[r][3] = fmaf(a, wv.w, acc[r][3]);
            }
        }
        __syncthreads();
    }
    float4 bv = *(const float4*)&bias[tx * 4];
    float s[4] = {0, 0, 0, 0}, q[4] = {0, 0, 0, 0};
    #pragma unroll
    for (int r = 0; r < RM; ++r) {
        float o[4];
        o[0] = acc[r][0] + bv.x; o[1] = acc[r][1] + bv.y;
        o[2] = acc[r][2] + bv.z; o[3] = acc[r][3] + bv.w;
        #pragma unroll
        for (int c = 0; c < 4; ++c) { s[c] += o[c]; q[c] = fmaf(o[c], o[c], q[c]); }
        size_t off = (size_t)(row0 + ty * RM + r) * N + tx * 4;
        uint2 ov;
        ov.x = pack2(o[0], o[1]);
        ov.y = pack2(o[2], o[3]);
        *(uint2*)&C[off] = ov;
    }
    #pragma unroll
    for (int c = 0; c < 4; ++c) {
        redst[0][ty][tx * 4 + c] = s[c];
        redst[1][ty][tx * 4 + c] = q[c];
    }
    __syncthreads();
    {
        int col = tid & (N - 1), qs = tid / N;
        float v = 0.f;
        #pragma unroll
        for (int t = 0; t < TY; ++t) v += redst[qs][t][col];
        (qs ? sqP : sumP)[(size_t)blockIdx.x * N + col] = v;
    }
}

// ---------------------------------------------------------------------------
// Tree-reduce block partials: P[NBLK][128] -> R2[col*64 + chunk] (64 chunks).
// ---------------------------------------------------------------------------
template<int NBLK>
__global__ __launch_bounds__(256) void reduce1_k(const float* __restrict__ sumP,
                                                 const float* __restrict__ sqP,
                                                 float* __restrict__ sumR2,
                                                 float* __restrict__ sqR2) {
    constexpr int ROWS = NBLK / 64;
    const int tid = threadIdx.x;
    const int qs = blockIdx.x & 1;
    const int chunk = blockIdx.x >> 1;
    const float* src = qs ? sqP : sumP;
    float* dst = qs ? sqR2 : sumR2;
    const int col = tid & 127;
    const int half = tid >> 7;
    float s = 0.f;
    for (int r = half; r < ROWS; r += 2)
        s += src[(size_t)(chunk * ROWS + r) * 128 + col];
    __shared__ float red[256];
    red[tid] = s;
    __syncthreads();
    if (tid < 128) dst[col * 64 + chunk] = red[tid] + red[tid + 128];
}

// Reduce 64 chunks; scale = g*rsqrt(var+eps); shift = be - mean*scale
__global__ void finalize_k(const float* __restrict__ sumR2, const float* __restrict__ sqR2,
                           const float* __restrict__ g, const float* __restrict__ be,
                           float* __restrict__ scale, float* __restrict__ shift) {
    const int f = threadIdx.x;  // 128
    const float4* ps = (const float4*)&sumR2[f * REP];
    const float4* pq = (const float4*)&sqR2[f * REP];
    float s = 0.f, q = 0.f;
    #pragma unroll
    for (int i = 0; i < REP / 4; ++i) {
        float4 a = ps[i]; s += (a.x + a.y) + (a.z + a.w);
        float4 b = pq[i]; q += (b.x + b.y) + (b.z + b.w);
    }
    const float invM = 1.f / (float)M_ROWS;
    float mean = s * invM;
    float var = q * invM - mean * mean;
    float sc = g[f] * rsqrtf(var + 1e-5f);
    scale[f] = sc;
    shift[f] = fmaf(-mean, sc, be[f]);
}

// All four weight transposes in one launch: fp32 W[K][N] -> bf16 WT[N][K]
__global__ void transpose_all_k(const float* __restrict__ W1, const float* __restrict__ W2,
                                const float* __restrict__ W3, const float* __restrict__ W4,
                                ushort_t* __restrict__ wt1, ushort_t* __restrict__ wt2,
                                ushort_t* __restrict__ wt3, ushort_t* __restrict__ wt4) {
    int idx = blockIdx.x * 256 + threadIdx.x;
    if (idx < 32768) {                       // W1: 256 x 128
        int k = idx >> 7, n = idx & 127;
        wt1[(size_t)n * 256 + k] = f2b(W1[idx]);
    } else if (idx < 49152) {                // W2: 128 x 128
        int i = idx - 32768;
        int k = i >> 7, n = i & 127;
        wt2[(size_t)n * 128 + k] = f2b(W2[i]);
    } else if (idx < 65536) {                // W3: 128 x 128
        int i = idx - 49152;
        int k = i >> 7, n = i & 127;
        wt3[(size_t)n * 128 + k] = f2b(W3[i]);
    } else if (idx < 73728) {                // W4: 128 x 64
        int i = idx - 65536;
        int k = i >> 6, n = i & 63;
        wt4[(size_t)n * 128 + k] = f2b(W4[i]);
    }
}

extern "C" void kernel_launch(void* const* d_in, const int* in_sizes, int n_in,
                              void* d_out, int out_size, void* d_ws, size_t ws_size,
                              hipStream_t stream) {
    const float* poly = (const float*)d_in[0];
    const float* W0 = (const float*)d_in[1];
    const float* b0 = (const float*)d_in[2];
    const float* g0 = (const float*)d_in[3];
    const float* be0 = (const float*)d_in[4];
    const float* W1 = (const float*)d_in[5];
    const float* b1 = (const float*)d_in[6];
    const float* g1 = (const float*)d_in[7];
    const float* be1 = (const float*)d_in[8];
    const float* W2 = (const float*)d_in[9];
    const float* b2 = (const float*)d_in[10];
    const float* g2 = (const float*)d_in[11];
    const float* be2 = (const float*)d_in[12];
    const float* W3 = (const float*)d_in[13];
    const float* b3 = (const float*)d_in[14];
    const float* g3 = (const float*)d_in[15];
    const float* be3 = (const float*)d_in[16];
    const float* W4 = (const float*)d_in[17];
    const float* b4 = (const float*)d_in[18];
    float* outp = (float*)d_out;

    float* st = (float*)d_ws;
    float* sumP = st;
    float* sqP = st + 524288;
    float* sumR2 = st + 1048576;
    float* sqR2 = sumR2 + 8192;
    float* scsh = st + 1064960;
    ushort_t* wt1 = (ushort_t*)((char*)d_ws + 4263936);         // 128 x 256
    ushort_t* wt2 = wt1 + 128 * 256;                            // 128 x 128
    ushort_t* wt3 = wt2 + 128 * 128;                            // 128 x 128
    ushort_t* wt4 = wt3 + 128 * 128;                            // 64 x 128
    ushort_t* h0 = (ushort_t*)((char*)d_ws + 4263936 + 147456);
    ushort_t* h1 = h0 + (size_t)M_ROWS * 128;

    const int G64 = M_ROWS / TILE_M;    // 4096 (L0)

    transpose_all_k<<<288, 256, 0, stream>>>(W1, W2, W3, W4, wt1, wt2, wt3, wt4);

    // Layer 0 (fp32 precision): y0 = poly @ W0 + b0 -> h0 (raw bf16) + partials
    gemm_f32_k<32, 128><<<G64, 256, 0, stream>>>(poly, W0, b0, h0, sumP, sqP);
    reduce1_k<4096><<<128, 256, 0, stream>>>(sumP, sqP, sumR2, sqR2);
    finalize_k<<<1, 128, 0, stream>>>(sumR2, sqR2, g0, be0, scsh, scsh + 128);

    // zero fused-kernel stat accumulators (3 layers x 256) + 3 barrier counters
    hipMemsetAsync(sumR2, 0, (768 + 8) * sizeof(float), stream);
    float* accum = sumR2;
    unsigned* cnts = (unsigned*)(sumR2 + 768);
    const float* sc0 = scsh;
    const float* sh0 = scsh + 128;

    // Persistent cooperative kernel: L1..L4 + both scans + all BN stats
    void* args[] = { &h0, &h1, &wt1, &wt2, &wt3, &wt4,
                     &b1, &b2, &b3, &b4,
                     &g1, &be1, &g2, &be2, &g3, &be3,
                     &sc0, &sh0, &accum, &outp, &cnts };
    hipLaunchCooperativeKernel((void*)fused_k, dim3(NBLOCKS), dim3(512), args, 0, stream);
}

// Round 5
// 424.423 us; speedup vs baseline: 1.7123x; 1.7123x over previous
//
#include <hip/hip_runtime.h>
#include <hip/hip_bf16.h>

// Problem constants (fixed by setup_inputs)
#define M_ROWS 262144   // B*A*T = 16*64*256
#define TILE_M 64
#define BK 32

typedef unsigned short ushort_t;
typedef unsigned int uint_t;
typedef __attribute__((ext_vector_type(8))) short short8_t;   // 8 bf16 = 4 VGPRs
typedef __attribute__((ext_vector_type(4))) float float4_t;   // MFMA acc

// bf16 (stored as ushort) <-> fp32 helpers. Load is exact; store is RNE.
__device__ __forceinline__ float b2f(ushort_t u) {
    union { uint_t i; float f; } c; c.i = ((uint_t)u) << 16; return c.f;
}
__device__ __forceinline__ ushort_t f2b(float f) {
    union { float f; uint_t i; } c; c.f = f;
    uint_t u = c.i;
    return (ushort_t)((u + 0x7fffu + ((u >> 16) & 1u)) >> 16);
}
// packed 2xfp32 -> 2xbf16 (v_cvt_pk_bf16_f32 on gfx950, RNE)
__device__ __forceinline__ uint_t pack2(float a, float b) {
    union { __hip_bfloat162 h; uint_t u; } c;
    c.h = __float22bfloat162_rn(make_float2(a, b));
    return c.u;
}

// async global->LDS DMA, 16 B per lane; data lands at ldsbase + lane*16
__device__ __forceinline__ void gld_lds16(const ushort_t* g, ushort_t* l) {
    __builtin_amdgcn_global_load_lds((const __attribute__((address_space(1))) void*)g,
                                     (__attribute__((address_space(3))) void*)l, 16, 0, 0);
}

// ---------------------------------------------------------------------------
// Layer-1 N-SPLIT pipelined GEMM: C = [bnrelu0(X), P] @ W1 + b1 (K=256).
// Grid = 1024 blocks: blockIdx = tile*2 + nhalf; each block computes a 64-col
// half of N=128 for RPT=8 row-tiles. B half (64 rows x 256 K = 32 KB) resident;
// A double-buffered over (tile, kt) steps with DMA prefetch one step ahead.
// LDS ~67 KB -> 2 blocks/CU (8 waves/CU). Output C must NOT alias X or P
// (sibling blocks read full rows) -> C = d_out scratch.
// Waves 2x2 over the 64x64 sub-tile. Epilogue into Abuf[1] (free after kt=1).
// Stats: per-block partials reduced in LDS, then atomicAdd into accum[256].
// ---------------------------------------------------------------------------
template<int RPT>
__launch_bounds__(256)
__global__ void gemm1s_k(const ushort_t* __restrict__ X, const ushort_t* __restrict__ P,
                         const ushort_t* __restrict__ WT, const float* __restrict__ bias,
                         const float* __restrict__ scale, const float* __restrict__ shift,
                         ushort_t* __restrict__ C, float* __restrict__ accum) {
    __shared__ __attribute__((aligned(16))) ushort_t Bs[64 * 256];       // 32 KB
    __shared__ __attribute__((aligned(16))) ushort_t Abuf[2][64 * 128];  // 2x16 KB
    __shared__ float sred[4 * 64 * 2];
    __shared__ float s_sc[128], s_sh[128];

    const int tid = threadIdx.x;
    const int lane = tid & 63;
    const int wave = tid >> 6;
    const int wm = wave & 1, wn = wave >> 1;
    const int quad = lane >> 4, l16 = lane & 15;
    const int srow = lane >> 4, sp16 = lane & 15;   // A staging
    const int brow = lane >> 5, bs32 = lane & 31;   // B staging (512 B rows)
    const int tileId = blockIdx.x >> 1;
    const int n0 = (blockIdx.x & 1) * 64;           // column-half offset
    const int row0 = tileId * (RPT * 64);

    if (tid < 128) { s_sc[tid] = scale[tid]; s_sh[tid] = shift[tid]; }

    // ---- stage B half (rows n0..n0+63 of WT, 512 B each): 32 chunks x 1 KB ----
    #pragma unroll
    for (int i = 0; i < 8; ++i) {
        int t = i * 4 + wave;
        int r = t * 2 + brow;                        // local B row 0..63
        int sp = (bs32 & 16) | ((bs32 ^ r) & 15);    // half-preserving XOR swizzle
        gld_lds16(WT + (size_t)(n0 + r) * 256 + sp * 8, Bs + t * 512);
    }

    auto stageA = [&](int it, int kt, int buf) {
        const ushort_t* src = kt ? P : X;
        int r0 = row0 + it * 64;
        #pragma unroll
        for (int i = 0; i < 4; ++i) {
            int t = i * 4 + wave;
            int r = t * 4 + srow;
            int sp = sp16 ^ (r & 15);
            gld_lds16(src + (size_t)(r0 + r) * 128 + sp * 8, Abuf[buf] + t * 512);
        }
    };
    stageA(0, 0, 0);

    float bvs[2];
    #pragma unroll
    for (int nt = 0; nt < 2; ++nt) bvs[nt] = bias[n0 + wn * 32 + nt * 16 + l16];
    float sSum[2] = {0.f, 0.f}, sSq[2] = {0.f, 0.f};

    int step = 0;
    for (int it = 0; it < RPT; ++it) {
        float4_t acc[2][2];
        #pragma unroll
        for (int mt = 0; mt < 2; ++mt)
            #pragma unroll
            for (int nt = 0; nt < 2; ++nt) acc[mt][nt] = (float4_t)0.f;

        #pragma unroll
        for (int kt = 0; kt < 2; ++kt) {
            __syncthreads();   // A(step) [+Bs on step 0] resident; prior epi reads done
            if (step + 1 < 2 * RPT) {
                int ns = step + 1;
                stageA(ns >> 1, ns & 1, ns & 1);
            }
            const ushort_t* As = Abuf[step & 1];
            #pragma unroll
            for (int kk = 0; kk < 4; ++kk) {
                int j = kk * 4 + quad;
                short8_t a0 = *(const short8_t*)&As[(wm * 32 + l16) * 128 + ((j ^ l16) * 8)];
                short8_t a1 = *(const short8_t*)&As[(wm * 32 + 16 + l16) * 128 + ((j ^ l16) * 8)];
                if (kt == 0) {   // bnrelu0 on X fragments
                    int kb = kk * 32 + quad * 8;
                    float4 c0 = *(const float4*)&s_sc[kb], c1 = *(const float4*)&s_sc[kb + 4];
                    float4 h0 = *(const float4*)&s_sh[kb], h1 = *(const float4*)&s_sh[kb + 4];
                    #pragma unroll
                    for (int z = 0; z < 2; ++z) {
                        ushort_t u[8];
                        *(short8_t*)u = z ? a1 : a0;
                        uint_t w[4];
                        w[0] = pack2(fmaxf(fmaf(b2f(u[0]), c0.x, h0.x), 0.f),
                                     fmaxf(fmaf(b2f(u[1]), c0.y, h0.y), 0.f));
                        w[1] = pack2(fmaxf(fmaf(b2f(u[2]), c0.z, h0.z), 0.f),
                                     fmaxf(fmaf(b2f(u[3]), c0.w, h0.w), 0.f));
                        w[2] = pack2(fmaxf(fmaf(b2f(u[4]), c1.x, h1.x), 0.f),
                                     fmaxf(fmaf(b2f(u[5]), c1.y, h1.y), 0.f));
                        w[3] = pack2(fmaxf(fmaf(b2f(u[6]), c1.z, h1.z), 0.f),
                                     fmaxf(fmaf(b2f(u[7]), c1.w, h1.w), 0.f));
                        short8_t rr;
                        *(uint4*)&rr = *(const uint4*)w;
                        if (z) a1 = rr; else a0 = rr;
                    }
                }
                #pragma unroll
                for (int nt = 0; nt < 2; ++nt) {
                    int br = wn * 32 + nt * 16 + l16;
                    short8_t bf = *(const short8_t*)&Bs[br * 256 + kt * 128 + ((j ^ l16) * 8)];
                    acc[0][nt] = __builtin_amdgcn_mfma_f32_16x16x32_bf16(a0, bf, acc[0][nt], 0, 0, 0);
                    acc[1][nt] = __builtin_amdgcn_mfma_f32_16x16x32_bf16(a1, bf, acc[1][nt], 0, 0, 0);
                }
            }
            ++step;
        }

        // ---- bias + stats accumulate ----
        #pragma unroll
        for (int mt = 0; mt < 2; ++mt)
            #pragma unroll
            for (int nt = 0; nt < 2; ++nt)
                #pragma unroll
                for (int r = 0; r < 4; ++r) {
                    float v = acc[mt][nt][r] + bvs[nt];
                    acc[mt][nt][r] = v;
                    sSum[nt] += v; sSq[nt] = fmaf(v, v, sSq[nt]);
                }
        if (it == RPT - 1) {
            #pragma unroll
            for (int nt = 0; nt < 2; ++nt) {
                float s = sSum[nt], q = sSq[nt];
                s += __shfl_xor(s, 16); q += __shfl_xor(q, 16);
                s += __shfl_xor(s, 32); q += __shfl_xor(q, 32);
                if (lane < 16) {
                    int colL = wn * 32 + nt * 16 + l16;
                    sred[(wave * 64 + colL) * 2 + 0] = s;
                    sred[(wave * 64 + colL) * 2 + 1] = q;
                }
            }
        }
        __syncthreads();   // kt=1 reads of Abuf[1] done; sred visible

        // ---- swizzled transpose into Abuf[1] (free; in-flight DMA targets buf0) ----
        char* eb = (char*)Abuf[1];
        #pragma unroll
        for (int mt = 0; mt < 2; ++mt)
            #pragma unroll
            for (int nt = 0; nt < 2; ++nt) {
                int colL = wn * 32 + nt * 16 + l16;
                int bc = colL * 2;
                #pragma unroll
                for (int r = 0; r < 4; ++r) {
                    int row = wm * 32 + mt * 16 + quad * 4 + r;
                    int addr = row * 128 + ((((bc >> 4) ^ (row & 7)) << 4) | (bc & 15));
                    *(ushort_t*)(eb + addr) = f2b(acc[mt][nt][r]);
                }
            }
        if (it == RPT - 1 && tid < 128) {
            int colL = tid & 63, qs = tid >> 6;
            int wb = (colL >> 5) * 2;   // the two waves (wm=0,1) owning this col
            float v = sred[(wb * 64 + colL) * 2 + qs] + sred[((wb + 1) * 64 + colL) * 2 + qs];
            atomicAdd(accum + qs * 128 + n0 + colL, v);
        }
        __syncthreads();

        // ---- coalesced 16 B stores of the 64-col half (128 B per row) ----
        int r0s = row0 + it * 64;
        #pragma unroll
        for (int p = 0; p < 2; ++p) {
            int s = p * 256 + tid;
            int row = s >> 3, g = s & 7;
            uint4 v = *(const uint4*)(eb + row * 128 + ((g ^ (row & 7)) << 4));
            *(uint4*)((char*)(C + (size_t)(r0s + row) * 128 + n0) + g * 16) = v;
        }
    }
}

// ---------------------------------------------------------------------------
// Persistent pipelined MFMA GEMM for K=128 layers: C = act(A)@W + bias.
// ---------------------------------------------------------------------------
template<int N, int MODE, int STATS, int RPT, typename CT>
__launch_bounds__(256)
__global__ void mfma_gemm3_k(const ushort_t* __restrict__ A, const ushort_t* __restrict__ WT,
                             const float* __restrict__ bias,
                             const float* __restrict__ scale, const float* __restrict__ shift,
                             CT* __restrict__ C, float* __restrict__ accum) {
    constexpr int WN = N / 2;        // cols per wave-column (64 or 32)
    constexpr int NT = WN / 16;      // 4 (N=128) or 2 (N=64)

    __shared__ __attribute__((aligned(16))) ushort_t Bs[N * 128];
    __shared__ __attribute__((aligned(16))) ushort_t Abuf[2][64 * 128];
    __shared__ float sred[STATS ? 4 * N * 2 : 1];
    __shared__ float s_sc[MODE == 1 ? 128 : 1];
    __shared__ float s_sh[MODE == 1 ? 128 : 1];

    const int tid = threadIdx.x;
    const int lane = tid & 63;
    const int wave = tid >> 6;
    const int wm = wave & 1;
    const int wn = wave >> 1;
    const int quad = lane >> 4;
    const int l16 = lane & 15;
    const int srow = lane >> 4;
    const int sp16 = lane & 15;

    if (MODE == 1 && tid < 128) { s_sc[tid] = scale[tid]; s_sh[tid] = shift[tid]; }

    #pragma unroll
    for (int i = 0; i < N / 16; ++i) {
        int t = i * 4 + wave;
        int r = t * 4 + srow;
        int sp = sp16 ^ (r & 15);
        gld_lds16(WT + (size_t)r * 128 + sp * 8, Bs + t * 512);
    }
    {
        int r0 = blockIdx.x * (RPT * 64);
        #pragma unroll
        for (int i = 0; i < 4; ++i) {
            int t = i * 4 + wave;
            int r = t * 4 + srow;
            int sp = sp16 ^ (r & 15);
            gld_lds16(A + (size_t)(r0 + r) * 128 + sp * 8, Abuf[0] + t * 512);
        }
    }

    float bvs[NT];
    #pragma unroll
    for (int nt = 0; nt < NT; ++nt) bvs[nt] = bias[wn * WN + nt * 16 + l16];
    float sSum[STATS ? NT : 1] = {0.f}, sSq[STATS ? NT : 1] = {0.f};

    for (int it = 0; it < RPT; ++it) {
        __syncthreads();
        if (it + 1 < RPT) {
            int r0 = blockIdx.x * (RPT * 64) + (it + 1) * 64;
            #pragma unroll
            for (int i = 0; i < 4; ++i) {
                int t = i * 4 + wave;
                int r = t * 4 + srow;
                int sp = sp16 ^ (r & 15);
                gld_lds16(A + (size_t)(r0 + r) * 128 + sp * 8, Abuf[(it + 1) & 1] + t * 512);
            }
        }
        const ushort_t* As = Abuf[it & 1];

        float4_t acc[2][NT];
        #pragma unroll
        for (int mt = 0; mt < 2; ++mt)
            #pragma unroll
            for (int nt = 0; nt < NT; ++nt) acc[mt][nt] = (float4_t)0.f;

        #pragma unroll
        for (int kk = 0; kk < 4; ++kk) {
            int j = kk * 4 + quad;
            short8_t a0 = *(const short8_t*)&As[(wm * 32 + l16) * 128 + ((j ^ l16) * 8)];
            short8_t a1 = *(const short8_t*)&As[(wm * 32 + 16 + l16) * 128 + ((j ^ l16) * 8)];
            if (MODE == 1) {
                int kb = kk * 32 + quad * 8;
                float4 c0 = *(const float4*)&s_sc[kb], c1 = *(const float4*)&s_sc[kb + 4];
                float4 h0 = *(const float4*)&s_sh[kb], h1 = *(const float4*)&s_sh[kb + 4];
                #pragma unroll
                for (int z = 0; z < 2; ++z) {
                    ushort_t u[8];
                    *(short8_t*)u = z ? a1 : a0;
                    uint_t w[4];
                    w[0] = pack2(fmaxf(fmaf(b2f(u[0]), c0.x, h0.x), 0.f),
                                 fmaxf(fmaf(b2f(u[1]), c0.y, h0.y), 0.f));
                    w[1] = pack2(fmaxf(fmaf(b2f(u[2]), c0.z, h0.z), 0.f),
                                 fmaxf(fmaf(b2f(u[3]), c0.w, h0.w), 0.f));
                    w[2] = pack2(fmaxf(fmaf(b2f(u[4]), c1.x, h1.x), 0.f),
                                 fmaxf(fmaf(b2f(u[5]), c1.y, h1.y), 0.f));
                    w[3] = pack2(fmaxf(fmaf(b2f(u[6]), c1.z, h1.z), 0.f),
                                 fmaxf(fmaf(b2f(u[7]), c1.w, h1.w), 0.f));
                    short8_t rr;
                    *(uint4*)&rr = *(const uint4*)w;
                    if (z) a1 = rr; else a0 = rr;
                }
            }
            #pragma unroll
            for (int nt = 0; nt < NT; ++nt) {
                short8_t bf = *(const short8_t*)&Bs[(wn * WN + nt * 16 + l16) * 128 + ((j ^ l16) * 8)];
                acc[0][nt] = __builtin_amdgcn_mfma_f32_16x16x32_bf16(a0, bf, acc[0][nt], 0, 0, 0);
                acc[1][nt] = __builtin_amdgcn_mfma_f32_16x16x32_bf16(a1, bf, acc[1][nt], 0, 0, 0);
            }
        }

        #pragma unroll
        for (int mt = 0; mt < 2; ++mt)
            #pragma unroll
            for (int nt = 0; nt < NT; ++nt)
                #pragma unroll
                for (int r = 0; r < 4; ++r) {
                    float v = acc[mt][nt][r] + bvs[nt];
                    acc[mt][nt][r] = v;
                    if (STATS) { sSum[nt] += v; sSq[nt] = fmaf(v, v, sSq[nt]); }
                }
        if (STATS && it == RPT - 1) {
            #pragma unroll
            for (int nt = 0; nt < NT; ++nt) {
                float s = sSum[nt], q = sSq[nt];
                s += __shfl_xor(s, 16); q += __shfl_xor(q, 16);
                s += __shfl_xor(s, 32); q += __shfl_xor(q, 32);
                if (lane < 16) {
                    int col = wn * WN + nt * 16 + l16;
                    sred[(wave * N + col) * 2 + 0] = s;
                    sred[(wave * N + col) * 2 + 1] = q;
                }
            }
        }
        __syncthreads();

        char* eb = (char*)Abuf[it & 1];
        #pragma unroll
        for (int mt = 0; mt < 2; ++mt)
            #pragma unroll
            for (int nt = 0; nt < NT; ++nt) {
                int col = wn * WN + nt * 16 + l16;
                int bc = col * (int)sizeof(CT);
                #pragma unroll
                for (int r = 0; r < 4; ++r) {
                    int row = wm * 32 + mt * 16 + quad * 4 + r;
                    int addr = row * 256 + ((((bc >> 4) ^ (row & 15)) << 4) | (bc & 15));
                    if constexpr (sizeof(CT) == 4) *(float*)(eb + addr) = acc[mt][nt][r];
                    else                           *(ushort_t*)(eb + addr) = f2b(acc[mt][nt][r]);
                }
            }
        if (STATS && it == RPT - 1) {
            int col = tid & (N - 1), qs = tid / N;
            int wb = (col / WN) * 2;
            float v = sred[(wb * N + col) * 2 + qs] + sred[((wb + 1) * N + col) * 2 + qs];
            atomicAdd(accum + qs * 128 + col, v);
        }
        __syncthreads();

        int r0 = blockIdx.x * (RPT * 64) + it * 64;
        #pragma unroll
        for (int p = 0; p < 4; ++p) {
            int s = p * 256 + tid;
            int row = s >> 4, g = s & 15;
            uint4 v = *(const uint4*)(eb + row * 256 + ((g ^ (row & 15)) << 4));
            *(uint4*)((char*)(C + (size_t)(r0 + row) * N) + g * 16) = v;
        }
    }
}

// ---------------------------------------------------------------------------
// fp32 vector GEMM (layer 0: K=32, fp32 input) with fused stats partials
// (atomicAdd into accum[256]).
// ---------------------------------------------------------------------------
template<int K, int N>
__launch_bounds__(256)
__global__ void gemm_f32_k(const float* __restrict__ A, const float* __restrict__ W,
                           const float* __restrict__ bias, ushort_t* __restrict__ C,
                           float* __restrict__ accum) {
    constexpr int TX = N / 4;        // 32
    constexpr int TY = 256 / TX;     // 8
    constexpr int RM = TILE_M / TY;  // 8

    __shared__ float As[TILE_M][BK + 1];
    __shared__ float Ws[BK][N];
    __shared__ float redst[2][TY][N];

    const int tid = threadIdx.x;
    const int tx = tid % TX;
    const int ty = tid / TX;
    const int row0 = blockIdx.x * TILE_M;
    const int arow = tid >> 2;
    const int acol = (tid & 3) * 8;

    float acc[RM][4];
    #pragma unroll
    for (int r = 0; r < RM; ++r)
        #pragma unroll
        for (int c = 0; c < 4; ++c) acc[r][c] = 0.f;

    for (int k0 = 0; k0 < K; k0 += BK) {
        {
            const float4* p = (const float4*)&A[(size_t)(row0 + arow) * K + k0 + acol];
            float4 x0 = p[0], x1 = p[1];
            As[arow][acol + 0] = x0.x; As[arow][acol + 1] = x0.y;
            As[arow][acol + 2] = x0.z; As[arow][acol + 3] = x0.w;
            As[arow][acol + 4] = x1.x; As[arow][acol + 5] = x1.y;
            As[arow][acol + 6] = x1.z; As[arow][acol + 7] = x1.w;
        }
        #pragma unroll
        for (int i = 0; i < (BK * N) / 256; ++i) {
            int e = i * 256 + tid;
            Ws[e / N][e % N] = W[(size_t)(k0 + e / N) * N + e % N];
        }
        __syncthreads();
        #pragma unroll
        for (int kk = 0; kk < BK; ++kk) {
            float4 wv = *(const float4*)&Ws[kk][tx * 4];
            #pragma unroll
            for (int r = 0; r < RM; ++r) {
                float a = As[ty * RM + r][kk];
                acc[r][0] = fmaf(a, wv.x, acc[r][0]);
                acc[r][1] = fmaf(a, wv.y, acc[r][1]);
                acc[r][2] = fmaf(a, wv.z, acc[r][2]);
                acc[r][3] = fmaf(a, wv.w, acc[r][3]);
            }
        }
        __syncthreads();
    }
    float4 bv = *(const float4*)&bias[tx * 4];
    float s[4] = {0, 0, 0, 0}, q[4] = {0, 0, 0, 0};
    #pragma unroll
    for (int r = 0; r < RM; ++r) {
        float o[4];
        o[0] = acc[r][0] + bv.x; o[1] = acc[r][1] + bv.y;
        o[2] = acc[r][2] + bv.z; o[3] = acc[r][3] + bv.w;
        #pragma unroll
        for (int c = 0; c < 4; ++c) { s[c] += o[c]; q[c] = fmaf(o[c], o[c], q[c]); }
        size_t off = (size_t)(row0 + ty * RM + r) * N + tx * 4;
        uint2 ov;
        ov.x = pack2(o[0], o[1]);
        ov.y = pack2(o[2], o[3]);
        *(uint2*)&C[off] = ov;
    }
    #pragma unroll
    for (int c = 0; c < 4; ++c) {
        redst[0][ty][tx * 4 + c] = s[c];
        redst[1][ty][tx * 4 + c] = q[c];
    }
    __syncthreads();
    {
        int col = tid & (N - 1), qs = tid / N;
        float v = 0.f;
        #pragma unroll
        for (int t = 0; t < TY; ++t) v += redst[qs][t][col];
        atomicAdd(accum + qs * 128 + col, v);
    }
}

// scale = g*rsqrt(var+eps); shift = be - mean*scale, reading accum[256] directly
__global__ void finalize_acc_k(const float* __restrict__ accum,
                               const float* __restrict__ g, const float* __restrict__ be,
                               float* __restrict__ scale, float* __restrict__ shift) {
    const int f = threadIdx.x;  // 128
    float s = accum[f];
    float q = accum[128 + f];
    const float invM = 1.f / (float)M_ROWS;
    float mean = s * invM;
    float var = q * invM - mean * mean;
    float sc = g[f] * rsqrtf(var + 1e-5f);
    scale[f] = sc;
    shift[f] = fmaf(-mean, sc, be[f]);
}

// All four weight transposes in one launch: fp32 W[K][N] -> bf16 WT[N][K]
__global__ void transpose_all_k(const float* __restrict__ W1, const float* __restrict__ W2,
                                const float* __restrict__ W3, const float* __restrict__ W4,
                                ushort_t* __restrict__ wt1, ushort_t* __restrict__ wt2,
                                ushort_t* __restrict__ wt3, ushort_t* __restrict__ wt4) {
    int idx = blockIdx.x * 256 + threadIdx.x;
    if (idx < 32768) {                       // W1: 256 x 128
        int k = idx >> 7, n = idx & 127;
        wt1[(size_t)n * 256 + k] = f2b(W1[idx]);
    } else if (idx < 49152) {                // W2: 128 x 128
        int i = idx - 32768;
        int k = i >> 7, n = i & 127;
        wt2[(size_t)n * 128 + k] = f2b(W2[i]);
    } else if (idx < 65536) {                // W3: 128 x 128
        int i = idx - 49152;
        int k = i >> 7, n = i & 127;
        wt3[(size_t)n * 128 + k] = f2b(W3[i]);
    } else if (idx < 73728) {                // W4: 128 x 64
        int i = idx - 65536;
        int k = i >> 6, n = i & 63;
        wt4[(size_t)n * 128 + k] = f2b(W4[i]);
    }
}

// ---------------------------------------------------------------------------
// Chunked causal cummax, one block per (ba) sequence (T=256, 128 feats).
// ---------------------------------------------------------------------------
template<int INPLACE>
__global__ __launch_bounds__(512) void scan_k(const ushort_t* __restrict__ Y,
                                              const float* __restrict__ scale,
                                              const float* __restrict__ shift,
                                              ushort_t* __restrict__ P) {
    const int tid = threadIdx.x;
    const int fp = tid & 63;
    const int chunk = tid >> 6;
    const size_t base = (size_t)blockIdx.x * 256 * 128 + fp * 2;
    const float sc0 = scale[fp * 2], sh0 = shift[fp * 2];
    const float sc1 = scale[fp * 2 + 1], sh1 = shift[fp * 2 + 1];

    __shared__ float cmax[8][128];

    uint_t vals[32];
    float run0 = 0.f, run1 = 0.f;
    #pragma unroll
    for (int i = 0; i < 32; ++i) {
        size_t idx = base + (size_t)(chunk * 32 + i) * 128;
        uint_t u = *(const uint_t*)&Y[idx];
        float v0 = fmaxf(fmaf(b2f((ushort_t)(u & 0xffff)), sc0, sh0), 0.f);
        float v1 = fmaxf(fmaf(b2f((ushort_t)(u >> 16)), sc1, sh1), 0.f);
        run0 = fmaxf(run0, v0);
        run1 = fmaxf(run1, v1);
        vals[i] = pack2(v0, v1);
    }
    cmax[chunk][fp * 2] = run0;
    cmax[chunk][fp * 2 + 1] = run1;
    __syncthreads();
    float p0 = 0.f, p1 = 0.f;
    for (int c = 0; c < chunk; ++c) {
        p0 = fmaxf(p0, cmax[c][fp * 2]);
        p1 = fmaxf(p1, cmax[c][fp * 2 + 1]);
    }
    run0 = p0; run1 = p1;
    ushort_t* dst = INPLACE ? (ushort_t*)Y : P;
    #pragma unroll
    for (int i = 0; i < 32; ++i) {
        uint_t u = vals[i];
        run0 = fmaxf(run0, b2f((ushort_t)(u & 0xffff)));
        run1 = fmaxf(run1, b2f((ushort_t)(u >> 16)));
        *(uint_t*)&dst[base + (size_t)(chunk * 32 + i) * 128] = pack2(run0, run1);
    }
}

extern "C" void kernel_launch(void* const* d_in, const int* in_sizes, int n_in,
                              void* d_out, int out_size, void* d_ws, size_t ws_size,
                              hipStream_t stream) {
    const float* poly = (const float*)d_in[0];
    const float* W0 = (const float*)d_in[1];
    const float* b0 = (const float*)d_in[2];
    const float* g0 = (const float*)d_in[3];
    const float* be0 = (const float*)d_in[4];
    const float* W1 = (const float*)d_in[5];
    const float* b1 = (const float*)d_in[6];
    const float* g1 = (const float*)d_in[7];
    const float* be1 = (const float*)d_in[8];
    const float* W2 = (const float*)d_in[9];
    const float* b2 = (const float*)d_in[10];
    const float* g2 = (const float*)d_in[11];
    const float* be2 = (const float*)d_in[12];
    const float* W3 = (const float*)d_in[13];
    const float* b3 = (const float*)d_in[14];
    const float* g3 = (const float*)d_in[15];
    const float* be3 = (const float*)d_in[16];
    const float* W4 = (const float*)d_in[17];
    const float* b4 = (const float*)d_in[18];
    float* out = (float*)d_out;

    float* st = (float*)d_ws;
    float* accum = st + 1048576;            // 4 layers x 256 floats
    float* scsh = st + 1064960;
    auto scP = [&](int i) { return scsh + i * 256; };
    auto shP = [&](int i) { return scsh + i * 256 + 128; };
    ushort_t* wt1 = (ushort_t*)((char*)d_ws + 4263936);         // 128 x 256
    ushort_t* wt2 = wt1 + 128 * 256;                            // 128 x 128
    ushort_t* wt3 = wt2 + 128 * 128;                            // 128 x 128
    ushort_t* wt4 = wt3 + 128 * 128;                            // 64 x 128
    ushort_t* h0 = (ushort_t*)((char*)d_ws + 4263936 + 147456);
    ushort_t* h1 = h0 + (size_t)M_ROWS * 128;
    ushort_t* y1 = (ushort_t*)out;   // d_out doubles as y1 scratch (M*128 bf16
                                     // == out_size bytes); overwritten by L4.

    const int G64 = M_ROWS / TILE_M;    // 4096 (L0)
    const int GP = M_ROWS / (64 * 8);   // 512 (persistent kernels, RPT=8)
    const int GBA = 1024;               // one block per (b,a) sequence

    // zero all stat accumulators (4 layers x 256 floats) before any atomics
    hipMemsetAsync(accum, 0, 1024 * sizeof(float), stream);

    // Layer 0 (fp32 precision): y0 = poly @ W0 + b0 -> h0 (raw bf16) + partials
    gemm_f32_k<32, 128><<<G64, 256, 0, stream>>>(poly, W0, b0, h0, accum);
    transpose_all_k<<<288, 256, 0, stream>>>(W1, W2, W3, W4, wt1, wt2, wt3, wt4);
    finalize_acc_k<<<1, 128, 0, stream>>>(accum, g0, be0, scP(0), shP(0));

    // P = cummax(bnrelu0(y0)) -> h1 ; h0 stays RAW y0
    scan_k<0><<<GBA, 512, 0, stream>>>(h0, scP(0), shP(0), h1);

    // Layer 1: y1 = [bnrelu0(y0), P] @ W1 + b1 -> d_out scratch (N-split, 2 blk/CU)
    gemm1s_k<8><<<2 * GP, 256, 0, stream>>>(h0, h1, wt1, b1, scP(0), shP(0), y1, accum + 256);
    finalize_acc_k<<<1, 128, 0, stream>>>(accum + 256, g1, be1, scP(1), shP(1));

    // Layer 2: y2 = bnrelu1(y1) @ W2 + b2 : d_out -> h0
    mfma_gemm3_k<128, 1, 1, 8, ushort_t><<<GP, 256, 0, stream>>>(
        y1, wt2, b2, scP(1), shP(1), h0, accum + 512);
    finalize_acc_k<<<1, 128, 0, stream>>>(accum + 512, g2, be2, scP(2), shP(2));

    // pooled = cummax(bnrelu2(y2)) in place in h0
    scan_k<1><<<GBA, 512, 0, stream>>>(h0, scP(2), shP(2), nullptr);

    // Layer 3: y3 = pooled @ W3 + b3 -> h0 (in place), persistent pipeline
    mfma_gemm3_k<128, 0, 1, 8, ushort_t><<<GP, 256, 0, stream>>>(
        h0, wt3, b3, nullptr, nullptr, h0, accum + 768);
    finalize_acc_k<<<1, 128, 0, stream>>>(accum + 768, g3, be3, scP(3), shP(3));

    // Layer 4: out = bnrelu3(y3) @ W4 + b4 -> d_out (fp32; overwrites y1 scratch)
    mfma_gemm3_k<64, 1, 0, 8, float><<<GP, 256, 0, stream>>>(
        h0, wt4, b4, scP(3), shP(3), out, nullptr);
}

// Round 7
// 355.515 us; speedup vs baseline: 2.0442x; 1.1938x over previous
//
#include <hip/hip_runtime.h>
#include <hip/hip_bf16.h>

// Problem constants (fixed by setup_inputs)
#define M_ROWS 262144   // B*A*T = 16*64*256
#define TILE_M 64
#define BK 32

typedef unsigned short ushort_t;
typedef unsigned int uint_t;
typedef __attribute__((ext_vector_type(8))) short short8_t;   // 8 bf16 = 4 VGPRs
typedef __attribute__((ext_vector_type(4))) float float4_t;   // MFMA acc

// bf16 (stored as ushort) <-> fp32 helpers. Load is exact; store is RNE.
__device__ __forceinline__ float b2f(ushort_t u) {
    union { uint_t i; float f; } c; c.i = ((uint_t)u) << 16; return c.f;
}
__device__ __forceinline__ ushort_t f2b(float f) {
    union { float f; uint_t i; } c; c.f = f;
    uint_t u = c.i;
    return (ushort_t)((u + 0x7fffu + ((u >> 16) & 1u)) >> 16);
}
// packed 2xfp32 -> 2xbf16 (v_cvt_pk_bf16_f32 on gfx950, RNE)
__device__ __forceinline__ uint_t pack2(float a, float b) {
    union { __hip_bfloat162 h; uint_t u; } c;
    c.h = __float22bfloat162_rn(make_float2(a, b));
    return c.u;
}

// async global->LDS DMA, 16 B per lane; data lands at ldsbase + lane*16
__device__ __forceinline__ void gld_lds16(const ushort_t* g, ushort_t* l) {
    __builtin_amdgcn_global_load_lds((const __attribute__((address_space(1))) void*)g,
                                     (__attribute__((address_space(3))) void*)l, 16, 0, 0);
}

// ---------------------------------------------------------------------------
// Layer-1 N-SPLIT pipelined GEMM: C = [bnrelu0(X), P] @ W1 + b1 (K=256).
// Grid = 1024 blocks: blockIdx = tile*2 + nhalf; each block computes a 64-col
// half of N=128 for RPT=8 row-tiles. B half (64 rows x 256 K = 32 KB) resident;
// A double-buffered over (tile, kt) steps with DMA prefetch one step ahead.
// LDS ~67 KB -> 2 blocks/CU (8 waves/CU). Output C must NOT alias X or P
// (sibling blocks read full rows) -> C = d_out scratch.
// Waves 2x2 over the 64x64 sub-tile. Epilogue into Abuf[1] (free after kt=1).
// Stats: per-block partials reduced in LDS, then atomicAdd into accum[256].
// ---------------------------------------------------------------------------
template<int RPT>
__launch_bounds__(256)
__global__ void gemm1s_k(const ushort_t* __restrict__ X, const ushort_t* __restrict__ P,
                         const ushort_t* __restrict__ WT, const float* __restrict__ bias,
                         const float* __restrict__ scale, const float* __restrict__ shift,
                         ushort_t* __restrict__ C, float* __restrict__ accum) {
    __shared__ __attribute__((aligned(16))) ushort_t Bs[64 * 256];       // 32 KB
    __shared__ __attribute__((aligned(16))) ushort_t Abuf[2][64 * 128];  // 2x16 KB
    __shared__ float sred[4 * 64 * 2];
    __shared__ float s_sc[128], s_sh[128];

    const int tid = threadIdx.x;
    const int lane = tid & 63;
    const int wave = tid >> 6;
    const int wm = wave & 1, wn = wave >> 1;
    const int quad = lane >> 4, l16 = lane & 15;
    const int srow = lane >> 4, sp16 = lane & 15;   // A staging
    const int brow = lane >> 5, bs32 = lane & 31;   // B staging (512 B rows)
    const int tileId = blockIdx.x >> 1;
    const int n0 = (blockIdx.x & 1) * 64;           // column-half offset
    const int row0 = tileId * (RPT * 64);

    if (tid < 128) { s_sc[tid] = scale[tid]; s_sh[tid] = shift[tid]; }

    // ---- stage B half (rows n0..n0+63 of WT, 512 B each): 32 chunks x 1 KB ----
    #pragma unroll
    for (int i = 0; i < 8; ++i) {
        int t = i * 4 + wave;
        int r = t * 2 + brow;                        // local B row 0..63
        int sp = (bs32 & 16) | ((bs32 ^ r) & 15);    // half-preserving XOR swizzle
        gld_lds16(WT + (size_t)(n0 + r) * 256 + sp * 8, Bs + t * 512);
    }

    auto stageA = [&](int it, int kt, int buf) {
        const ushort_t* src = kt ? P : X;
        int r0 = row0 + it * 64;
        #pragma unroll
        for (int i = 0; i < 4; ++i) {
            int t = i * 4 + wave;
            int r = t * 4 + srow;
            int sp = sp16 ^ (r & 15);
            gld_lds16(src + (size_t)(r0 + r) * 128 + sp * 8, Abuf[buf] + t * 512);
        }
    };
    stageA(0, 0, 0);

    float bvs[2];
    #pragma unroll
    for (int nt = 0; nt < 2; ++nt) bvs[nt] = bias[n0 + wn * 32 + nt * 16 + l16];
    float sSum[2] = {0.f, 0.f}, sSq[2] = {0.f, 0.f};

    int step = 0;
    for (int it = 0; it < RPT; ++it) {
        float4_t acc[2][2];
        #pragma unroll
        for (int mt = 0; mt < 2; ++mt)
            #pragma unroll
            for (int nt = 0; nt < 2; ++nt) acc[mt][nt] = (float4_t)0.f;

        #pragma unroll
        for (int kt = 0; kt < 2; ++kt) {
            __syncthreads();   // A(step) [+Bs on step 0] resident; prior epi reads done
            if (step + 1 < 2 * RPT) {
                int ns = step + 1;
                stageA(ns >> 1, ns & 1, ns & 1);
            }
            const ushort_t* As = Abuf[step & 1];
            #pragma unroll
            for (int kk = 0; kk < 4; ++kk) {
                int j = kk * 4 + quad;
                short8_t a0 = *(const short8_t*)&As[(wm * 32 + l16) * 128 + ((j ^ l16) * 8)];
                short8_t a1 = *(const short8_t*)&As[(wm * 32 + 16 + l16) * 128 + ((j ^ l16) * 8)];
                if (kt == 0) {   // bnrelu0 on X fragments
                    int kb = kk * 32 + quad * 8;
                    float4 c0 = *(const float4*)&s_sc[kb], c1 = *(const float4*)&s_sc[kb + 4];
                    float4 h0 = *(const float4*)&s_sh[kb], h1 = *(const float4*)&s_sh[kb + 4];
                    #pragma unroll
                    for (int z = 0; z < 2; ++z) {
                        ushort_t u[8];
                        *(short8_t*)u = z ? a1 : a0;
                        uint_t w[4];
                        w[0] = pack2(fmaxf(fmaf(b2f(u[0]), c0.x, h0.x), 0.f),
                                     fmaxf(fmaf(b2f(u[1]), c0.y, h0.y), 0.f));
                        w[1] = pack2(fmaxf(fmaf(b2f(u[2]), c0.z, h0.z), 0.f),
                                     fmaxf(fmaf(b2f(u[3]), c0.w, h0.w), 0.f));
                        w[2] = pack2(fmaxf(fmaf(b2f(u[4]), c1.x, h1.x), 0.f),
                                     fmaxf(fmaf(b2f(u[5]), c1.y, h1.y), 0.f));
                        w[3] = pack2(fmaxf(fmaf(b2f(u[6]), c1.z, h1.z), 0.f),
                                     fmaxf(fmaf(b2f(u[7]), c1.w, h1.w), 0.f));
                        short8_t rr;
                        *(uint4*)&rr = *(const uint4*)w;
                        if (z) a1 = rr; else a0 = rr;
                    }
                }
                #pragma unroll
                for (int nt = 0; nt < 2; ++nt) {
                    int br = wn * 32 + nt * 16 + l16;
                    short8_t bf = *(const short8_t*)&Bs[br * 256 + kt * 128 + ((j ^ l16) * 8)];
                    acc[0][nt] = __builtin_amdgcn_mfma_f32_16x16x32_bf16(a0, bf, acc[0][nt], 0, 0, 0);
                    acc[1][nt] = __builtin_amdgcn_mfma_f32_16x16x32_bf16(a1, bf, acc[1][nt], 0, 0, 0);
                }
            }
            ++step;
        }

        // ---- bias + stats accumulate ----
        #pragma unroll
        for (int mt = 0; mt < 2; ++mt)
            #pragma unroll
            for (int nt = 0; nt < 2; ++nt)
                #pragma unroll
                for (int r = 0; r < 4; ++r) {
                    float v = acc[mt][nt][r] + bvs[nt];
                    acc[mt][nt][r] = v;
                    sSum[nt] += v; sSq[nt] = fmaf(v, v, sSq[nt]);
                }
        if (it == RPT - 1) {
            #pragma unroll
            for (int nt = 0; nt < 2; ++nt) {
                float s = sSum[nt], q = sSq[nt];
                s += __shfl_xor(s, 16); q += __shfl_xor(q, 16);
                s += __shfl_xor(s, 32); q += __shfl_xor(q, 32);
                if (lane < 16) {
                    int colL = wn * 32 + nt * 16 + l16;
                    sred[(wave * 64 + colL) * 2 + 0] = s;
                    sred[(wave * 64 + colL) * 2 + 1] = q;
                }
            }
        }
        __syncthreads();   // kt=1 reads of Abuf[1] done; sred visible

        // ---- swizzled transpose into Abuf[1] (free; in-flight DMA targets buf0) ----
        char* eb = (char*)Abuf[1];
        #pragma unroll
        for (int mt = 0; mt < 2; ++mt)
            #pragma unroll
            for (int nt = 0; nt < 2; ++nt) {
                int colL = wn * 32 + nt * 16 + l16;
                int bc = colL * 2;
                #pragma unroll
                for (int r = 0; r < 4; ++r) {
                    int row = wm * 32 + mt * 16 + quad * 4 + r;
                    int addr = row * 128 + ((((bc >> 4) ^ (row & 7)) << 4) | (bc & 15));
                    *(ushort_t*)(eb + addr) = f2b(acc[mt][nt][r]);
                }
            }
        if (it == RPT - 1 && tid < 128) {
            int colL = tid & 63, qs = tid >> 6;
            int wb = (colL >> 5) * 2;   // the two waves (wm=0,1) owning this col
            float v = sred[(wb * 64 + colL) * 2 + qs] + sred[((wb + 1) * 64 + colL) * 2 + qs];
            atomicAdd(accum + qs * 128 + n0 + colL, v);
        }
        __syncthreads();

        // ---- coalesced 16 B stores of the 64-col half (128 B per row) ----
        int r0s = row0 + it * 64;
        #pragma unroll
        for (int p = 0; p < 2; ++p) {
            int s = p * 256 + tid;
            int row = s >> 3, g = s & 7;
            uint4 v = *(const uint4*)(eb + row * 128 + ((g ^ (row & 7)) << 4));
            *(uint4*)((char*)(C + (size_t)(r0s + row) * 128 + n0) + g * 16) = v;
        }
    }
}

// ---------------------------------------------------------------------------
// Persistent pipelined MFMA GEMM for K=128 layers: C = act(A)@W + bias.
// ---------------------------------------------------------------------------
template<int N, int MODE, int STATS, int RPT, typename CT>
__launch_bounds__(256)
__global__ void mfma_gemm3_k(const ushort_t* __restrict__ A, const ushort_t* __restrict__ WT,
                             const float* __restrict__ bias,
                             const float* __restrict__ scale, const float* __restrict__ shift,
                             CT* __restrict__ C, float* __restrict__ accum) {
    constexpr int WN = N / 2;        // cols per wave-column (64 or 32)
    constexpr int NT = WN / 16;      // 4 (N=128) or 2 (N=64)

    __shared__ __attribute__((aligned(16))) ushort_t Bs[N * 128];
    __shared__ __attribute__((aligned(16))) ushort_t Abuf[2][64 * 128];
    __shared__ float sred[STATS ? 4 * N * 2 : 1];
    __shared__ float s_sc[MODE == 1 ? 128 : 1];
    __shared__ float s_sh[MODE == 1 ? 128 : 1];

    const int tid = threadIdx.x;
    const int lane = tid & 63;
    const int wave = tid >> 6;
    const int wm = wave & 1;
    const int wn = wave >> 1;
    const int quad = lane >> 4;
    const int l16 = lane & 15;
    const int srow = lane >> 4;
    const int sp16 = lane & 15;

    if (MODE == 1 && tid < 128) { s_sc[tid] = scale[tid]; s_sh[tid] = shift[tid]; }

    #pragma unroll
    for (int i = 0; i < N / 16; ++i) {
        int t = i * 4 + wave;
        int r = t * 4 + srow;
        int sp = sp16 ^ (r & 15);
        gld_lds16(WT + (size_t)r * 128 + sp * 8, Bs + t * 512);
    }
    {
        int r0 = blockIdx.x * (RPT * 64);
        #pragma unroll
        for (int i = 0; i < 4; ++i) {
            int t = i * 4 + wave;
            int r = t * 4 + srow;
            int sp = sp16 ^ (r & 15);
            gld_lds16(A + (size_t)(r0 + r) * 128 + sp * 8, Abuf[0] + t * 512);
        }
    }

    float bvs[NT];
    #pragma unroll
    for (int nt = 0; nt < NT; ++nt) bvs[nt] = bias[wn * WN + nt * 16 + l16];
    float sSum[STATS ? NT : 1] = {0.f}, sSq[STATS ? NT : 1] = {0.f};

    for (int it = 0; it < RPT; ++it) {
        __syncthreads();
        if (it + 1 < RPT) {
            int r0 = blockIdx.x * (RPT * 64) + (it + 1) * 64;
            #pragma unroll
            for (int i = 0; i < 4; ++i) {
                int t = i * 4 + wave;
                int r = t * 4 + srow;
                int sp = sp16 ^ (r & 15);
                gld_lds16(A + (size_t)(r0 + r) * 128 + sp * 8, Abuf[(it + 1) & 1] + t * 512);
            }
        }
        const ushort_t* As = Abuf[it & 1];

        float4_t acc[2][NT];
        #pragma unroll
        for (int mt = 0; mt < 2; ++mt)
            #pragma unroll
            for (int nt = 0; nt < NT; ++nt) acc[mt][nt] = (float4_t)0.f;

        #pragma unroll
        for (int kk = 0; kk < 4; ++kk) {
            int j = kk * 4 + quad;
            short8_t a0 = *(const short8_t*)&As[(wm * 32 + l16) * 128 + ((j ^ l16) * 8)];
            short8_t a1 = *(const short8_t*)&As[(wm * 32 + 16 + l16) * 128 + ((j ^ l16) * 8)];
            if (MODE == 1) {
                int kb = kk * 32 + quad * 8;
                float4 c0 = *(const float4*)&s_sc[kb], c1 = *(const float4*)&s_sc[kb + 4];
                float4 h0 = *(const float4*)&s_sh[kb], h1 = *(const float4*)&s_sh[kb + 4];
                #pragma unroll
                for (int z = 0; z < 2; ++z) {
                    ushort_t u[8];
                    *(short8_t*)u = z ? a1 : a0;
                    uint_t w[4];
                    w[0] = pack2(fmaxf(fmaf(b2f(u[0]), c0.x, h0.x), 0.f),
                                 fmaxf(fmaf(b2f(u[1]), c0.y, h0.y), 0.f));
                    w[1] = pack2(fmaxf(fmaf(b2f(u[2]), c0.z, h0.z), 0.f),
                                 fmaxf(fmaf(b2f(u[3]), c0.w, h0.w), 0.f));
                    w[2] = pack2(fmaxf(fmaf(b2f(u[4]), c1.x, h1.x), 0.f),
                                 fmaxf(fmaf(b2f(u[5]), c1.y, h1.y), 0.f));
                    w[3] = pack2(fmaxf(fmaf(b2f(u[6]), c1.z, h1.z), 0.f),
                                 fmaxf(fmaf(b2f(u[7]), c1.w, h1.w), 0.f));
                    short8_t rr;
                    *(uint4*)&rr = *(const uint4*)w;
                    if (z) a1 = rr; else a0 = rr;
                }
            }
            #pragma unroll
            for (int nt = 0; nt < NT; ++nt) {
                short8_t bf = *(const short8_t*)&Bs[(wn * WN + nt * 16 + l16) * 128 + ((j ^ l16) * 8)];
                acc[0][nt] = __builtin_amdgcn_mfma_f32_16x16x32_bf16(a0, bf, acc[0][nt], 0, 0, 0);
                acc[1][nt] = __builtin_amdgcn_mfma_f32_16x16x32_bf16(a1, bf, acc[1][nt], 0, 0, 0);
            }
        }

        #pragma unroll
        for (int mt = 0; mt < 2; ++mt)
            #pragma unroll
            for (int nt = 0; nt < NT; ++nt)
                #pragma unroll
                for (int r = 0; r < 4; ++r) {
                    float v = acc[mt][nt][r] + bvs[nt];
                    acc[mt][nt][r] = v;
                    if (STATS) { sSum[nt] += v; sSq[nt] = fmaf(v, v, sSq[nt]); }
                }
        if (STATS && it == RPT - 1) {
            #pragma unroll
            for (int nt = 0; nt < NT; ++nt) {
                float s = sSum[nt], q = sSq[nt];
                s += __shfl_xor(s, 16); q += __shfl_xor(q, 16);
                s += __shfl_xor(s, 32); q += __shfl_xor(q, 32);
                if (lane < 16) {
                    int col = wn * WN + nt * 16 + l16;
                    sred[(wave * N + col) * 2 + 0] = s;
                    sred[(wave * N + col) * 2 + 1] = q;
                }
            }
        }
        __syncthreads();

        char* eb = (char*)Abuf[it & 1];
        #pragma unroll
        for (int mt = 0; mt < 2; ++mt)
            #pragma unroll
            for (int nt = 0; nt < NT; ++nt) {
                int col = wn * WN + nt * 16 + l16;
                int bc = col * (int)sizeof(CT);
                #pragma unroll
                for (int r = 0; r < 4; ++r) {
                    int row = wm * 32 + mt * 16 + quad * 4 + r;
                    int addr = row * 256 + ((((bc >> 4) ^ (row & 15)) << 4) | (bc & 15));
                    if constexpr (sizeof(CT) == 4) *(float*)(eb + addr) = acc[mt][nt][r];
                    else                           *(ushort_t*)(eb + addr) = f2b(acc[mt][nt][r]);
                }
            }
        if (STATS && it == RPT - 1) {
            int col = tid & (N - 1), qs = tid / N;
            int wb = (col / WN) * 2;
            float v = sred[(wb * N + col) * 2 + qs] + sred[((wb + 1) * N + col) * 2 + qs];
            atomicAdd(accum + qs * 128 + col, v);
        }
        __syncthreads();

        int r0 = blockIdx.x * (RPT * 64) + it * 64;
        #pragma unroll
        for (int p = 0; p < 4; ++p) {
            int s = p * 256 + tid;
            int row = s >> 4, g = s & 15;
            uint4 v = *(const uint4*)(eb + row * 256 + ((g ^ (row & 15)) << 4));
            *(uint4*)((char*)(C + (size_t)(r0 + row) * N) + g * 16) = v;
        }
    }
}

// ---------------------------------------------------------------------------
// fp32 vector GEMM (layer 0: K=32, fp32 input), grid-strided over RPT row
// tiles per block. Weights staged ONCE; A-tile async-stage split (issue loads
// early, ds_write late). Stats in registers across tiles -> one LDS reduce +
// 256 atomics per block (512 blocks -> 131K atomics, the proven-safe count;
// r5's 4096-block version issued 1M atomics -> 90 us contention tail).
// ---------------------------------------------------------------------------
template<int K, int N, int RPT>
__launch_bounds__(256)
__global__ void gemm_f32_k(const float* __restrict__ A, const float* __restrict__ W,
                           const float* __restrict__ bias, ushort_t* __restrict__ C,
                           float* __restrict__ accum) {
    constexpr int TX = N / 4;        // 32
    constexpr int TY = 256 / TX;     // 8
    constexpr int RM = TILE_M / TY;  // 8

    __shared__ float As[2][TILE_M][BK + 1];
    __shared__ float Ws[BK][N];
    __shared__ float redst[2][TY][N];

    const int tid = threadIdx.x;
    const int tx = tid % TX;
    const int ty = tid / TX;
    const int row0 = blockIdx.x * (RPT * TILE_M);
    const int arow = tid >> 2;
    const int acol = (tid & 3) * 8;

    // ---- stage weights once (K=32 -> whole K fits one tile) ----
    #pragma unroll
    for (int i = 0; i < (BK * N) / 256; ++i) {
        int e = i * 256 + tid;
        Ws[e / N][e % N] = W[(size_t)(e / N) * N + e % N];
    }
    // ---- preload tile 0 A ----
    {
        const float4* p = (const float4*)&A[(size_t)(row0 + arow) * K + acol];
        float4 x0 = p[0], x1 = p[1];
        As[0][arow][acol + 0] = x0.x; As[0][arow][acol + 1] = x0.y;
        As[0][arow][acol + 2] = x0.z; As[0][arow][acol + 3] = x0.w;
        As[0][arow][acol + 4] = x1.x; As[0][arow][acol + 5] = x1.y;
        As[0][arow][acol + 6] = x1.z; As[0][arow][acol + 7] = x1.w;
    }

    float4 bv = *(const float4*)&bias[tx * 4];
    float s[4] = {0, 0, 0, 0}, q[4] = {0, 0, 0, 0};

    for (int it = 0; it < RPT; ++it) {
        __syncthreads();   // As[it&1] (and Ws on it=0) resident
        // issue next tile's loads EARLY (latency hides under FMA loop)
        float4 nx0, nx1;
        if (it + 1 < RPT) {
            const float4* p = (const float4*)&A[(size_t)(row0 + (it + 1) * TILE_M + arow) * K + acol];
            nx0 = p[0]; nx1 = p[1];
        }

        float acc[RM][4];
        #pragma unroll
        for (int r = 0; r < RM; ++r)
            #pragma unroll
            for (int c = 0; c < 4; ++c) acc[r][c] = 0.f;
        #pragma unroll
        for (int kk = 0; kk < BK; ++kk) {
            float4 wv = *(const float4*)&Ws[kk][tx * 4];
            #pragma unroll
            for (int r = 0; r < RM; ++r) {
                float a = As[it & 1][ty * RM + r][kk];
                acc[r][0] = fmaf(a, wv.x, acc[r][0]);
                acc[r][1] = fmaf(a, wv.y, acc[r][1]);
                acc[r][2] = fmaf(a, wv.z, acc[r][2]);
                acc[r][3] = fmaf(a, wv.w, acc[r][3]);
            }
        }

        // bias + stats + coalesced bf16 store for this tile
        #pragma unroll
        for (int r = 0; r < RM; ++r) {
            float o[4];
            o[0] = acc[r][0] + bv.x; o[1] = acc[r][1] + bv.y;
            o[2] = acc[r][2] + bv.z; o[3] = acc[r][3] + bv.w;
            #pragma unroll
            for (int c = 0; c < 4; ++c) { s[c] += o[c]; q[c] = fmaf(o[c], o[c], q[c]); }
            size_t off = (size_t)(row0 + it * TILE_M + ty * RM + r) * N + tx * 4;
            uint2 ov;
            ov.x = pack2(o[0], o[1]);
            ov.y = pack2(o[2], o[3]);
            *(uint2*)&C[off] = ov;
        }

        // ds_write the prefetched tile LATE (vmcnt wait lands after compute)
        if (it + 1 < RPT) {
            int b = (it + 1) & 1;
            As[b][arow][acol + 0] = nx0.x; As[b][arow][acol + 1] = nx0.y;
            As[b][arow][acol + 2] = nx0.z; As[b][arow][acol + 3] = nx0.w;
            As[b][arow][acol + 4] = nx1.x; As[b][arow][acol + 5] = nx1.y;
            As[b][arow][acol + 6] = nx1.z; As[b][arow][acol + 7] = nx1.w;
        }
    }

    __syncthreads();   // As reads done; redst region free
    #pragma unroll
    for (int c = 0; c < 4; ++c) {
        redst[0][ty][tx * 4 + c] = s[c];
        redst[1][ty][tx * 4 + c] = q[c];
    }
    __syncthreads();
    {
        int col = tid & (N - 1), qs = tid / N;
        float v = 0.f;
        #pragma unroll
        for (int t = 0; t < TY; ++t) v += redst[qs][t][col];
        atomicAdd(accum + qs * 128 + col, v);
    }
}

// scale = g*rsqrt(var+eps); shift = be - mean*scale, reading accum[256] directly
__global__ void finalize_acc_k(const float* __restrict__ accum,
                               const float* __restrict__ g, const float* __restrict__ be,
                               float* __restrict__ scale, float* __restrict__ shift) {
    const int f = threadIdx.x;  // 128
    float s = accum[f];
    float q = accum[128 + f];
    const float invM = 1.f / (float)M_ROWS;
    float mean = s * invM;
    float var = q * invM - mean * mean;
    float sc = g[f] * rsqrtf(var + 1e-5f);
    scale[f] = sc;
    shift[f] = fmaf(-mean, sc, be[f]);
}

// All four weight transposes in one launch: fp32 W[K][N] -> bf16 WT[N][K]
__global__ void transpose_all_k(const float* __restrict__ W1, const float* __restrict__ W2,
                                const float* __restrict__ W3, const float* __restrict__ W4,
                                ushort_t* __restrict__ wt1, ushort_t* __restrict__ wt2,
                                ushort_t* __restrict__ wt3, ushort_t* __restrict__ wt4) {
    int idx = blockIdx.x * 256 + threadIdx.x;
    if (idx < 32768) {                       // W1: 256 x 128
        int k = idx >> 7, n = idx & 127;
        wt1[(size_t)n * 256 + k] = f2b(W1[idx]);
    } else if (idx < 49152) {                // W2: 128 x 128
        int i = idx - 32768;
        int k = i >> 7, n = i & 127;
        wt2[(size_t)n * 128 + k] = f2b(W2[i]);
    } else if (idx < 65536) {                // W3: 128 x 128
        int i = idx - 49152;
        int k = i >> 7, n = i & 127;
        wt3[(size_t)n * 128 + k] = f2b(W3[i]);
    } else if (idx < 73728) {                // W4: 128 x 64
        int i = idx - 65536;
        int k = i >> 6, n = i & 63;
        wt4[(size_t)n * 128 + k] = f2b(W4[i]);
    }
}

// ---------------------------------------------------------------------------
// Chunked causal cummax, one block per (ba) sequence (T=256, 128 feats).
// ---------------------------------------------------------------------------
template<int INPLACE>
__global__ __launch_bounds__(512) void scan_k(const ushort_t* __restrict__ Y,
                                              const float* __restrict__ scale,
                                              const float* __restrict__ shift,
                                              ushort_t* __restrict__ P) {
    const int tid = threadIdx.x;
    const int fp = tid & 63;
    const int chunk = tid >> 6;
    const size_t base = (size_t)blockIdx.x * 256 * 128 + fp * 2;
    const float sc0 = scale[fp * 2], sh0 = shift[fp * 2];
    const float sc1 = scale[fp * 2 + 1], sh1 = shift[fp * 2 + 1];

    __shared__ float cmax[8][128];

    uint_t vals[32];
    float run0 = 0.f, run1 = 0.f;
    #pragma unroll
    for (int i = 0; i < 32; ++i) {
        size_t idx = base + (size_t)(chunk * 32 + i) * 128;
        uint_t u = *(const uint_t*)&Y[idx];
        float v0 = fmaxf(fmaf(b2f((ushort_t)(u & 0xffff)), sc0, sh0), 0.f);
        float v1 = fmaxf(fmaf(b2f((ushort_t)(u >> 16)), sc1, sh1), 0.f);
        run0 = fmaxf(run0, v0);
        run1 = fmaxf(run1, v1);
        vals[i] = pack2(v0, v1);
    }
    cmax[chunk][fp * 2] = run0;
    cmax[chunk][fp * 2 + 1] = run1;
    __syncthreads();
    float p0 = 0.f, p1 = 0.f;
    for (int c = 0; c < chunk; ++c) {
        p0 = fmaxf(p0, cmax[c][fp * 2]);
        p1 = fmaxf(p1, cmax[c][fp * 2 + 1]);
    }
    run0 = p0; run1 = p1;
    ushort_t* dst = INPLACE ? (ushort_t*)Y : P;
    #pragma unroll
    for (int i = 0; i < 32; ++i) {
        uint_t u = vals[i];
        run0 = fmaxf(run0, b2f((ushort_t)(u & 0xffff)));
        run1 = fmaxf(run1, b2f((ushort_t)(u >> 16)));
        *(uint_t*)&dst[base + (size_t)(chunk * 32 + i) * 128] = pack2(run0, run1);
    }
}

extern "C" void kernel_launch(void* const* d_in, const int* in_sizes, int n_in,
                              void* d_out, int out_size, void* d_ws, size_t ws_size,
                              hipStream_t stream) {
    const float* poly = (const float*)d_in[0];
    const float* W0 = (const float*)d_in[1];
    const float* b0 = (const float*)d_in[2];
    const float* g0 = (const float*)d_in[3];
    const float* be0 = (const float*)d_in[4];
    const float* W1 = (const float*)d_in[5];
    const float* b1 = (const float*)d_in[6];
    const float* g1 = (const float*)d_in[7];
    const float* be1 = (const float*)d_in[8];
    const float* W2 = (const float*)d_in[9];
    const float* b2 = (const float*)d_in[10];
    const float* g2 = (const float*)d_in[11];
    const float* be2 = (const float*)d_in[12];
    const float* W3 = (const float*)d_in[13];
    const float* b3 = (const float*)d_in[14];
    const float* g3 = (const float*)d_in[15];
    const float* be3 = (const float*)d_in[16];
    const float* W4 = (const float*)d_in[17];
    const float* b4 = (const float*)d_in[18];
    float* out = (float*)d_out;

    float* st = (float*)d_ws;
    float* accum = st + 1048576;            // 4 layers x 256 floats
    float* scsh = st + 1064960;
    auto scP = [&](int i) { return scsh + i * 256; };
    auto shP = [&](int i) { return scsh + i * 256 + 128; };
    ushort_t* wt1 = (ushort_t*)((char*)d_ws + 4263936);         // 128 x 256
    ushort_t* wt2 = wt1 + 128 * 256;                            // 128 x 128
    ushort_t* wt3 = wt2 + 128 * 128;                            // 128 x 128
    ushort_t* wt4 = wt3 + 128 * 128;                            // 64 x 128
    ushort_t* h0 = (ushort_t*)((char*)d_ws + 4263936 + 147456);
    ushort_t* h1 = h0 + (size_t)M_ROWS * 128;
    ushort_t* y1 = (ushort_t*)out;   // d_out doubles as y1 scratch (M*128 bf16
                                     // == out_size bytes); overwritten by L4.

    const int GP = M_ROWS / (64 * 8);   // 512 (persistent kernels, RPT=8)
    const int GBA = 1024;               // one block per (b,a) sequence

    // zero all stat accumulators (4 layers x 256 floats) before any atomics
    hipMemsetAsync(accum, 0, 1024 * sizeof(float), stream);

    // Layer 0 (fp32 precision): y0 = poly @ W0 + b0 -> h0 (raw bf16) + partials
    gemm_f32_k<32, 128, 8><<<GP, 256, 0, stream>>>(poly, W0, b0, h0, accum);
    transpose_all_k<<<288, 256, 0, stream>>>(W1, W2, W3, W4, wt1, wt2, wt3, wt4);
    finalize_acc_k<<<1, 128, 0, stream>>>(accum, g0, be0, scP(0), shP(0));

    // P = cummax(bnrelu0(y0)) -> h1 ; h0 stays RAW y0
    scan_k<0><<<GBA, 512, 0, stream>>>(h0, scP(0), shP(0), h1);

    // Layer 1: y1 = [bnrelu0(y0), P] @ W1 + b1 -> d_out scratch (N-split, 2 blk/CU)
    gemm1s_k<8><<<2 * GP, 256, 0, stream>>>(h0, h1, wt1, b1, scP(0), shP(0), y1, accum + 256);
    finalize_acc_k<<<1, 128, 0, stream>>>(accum + 256, g1, be1, scP(1), shP(1));

    // Layer 2: y2 = bnrelu1(y1) @ W2 + b2 : d_out -> h0
    mfma_gemm3_k<128, 1, 1, 8, ushort_t><<<GP, 256, 0, stream>>>(
        y1, wt2, b2, scP(1), shP(1), h0, accum + 512);
    finalize_acc_k<<<1, 128, 0, stream>>>(accum + 512, g2, be2, scP(2), shP(2));

    // pooled = cummax(bnrelu2(y2)) in place in h0
    scan_k<1><<<GBA, 512, 0, stream>>>(h0, scP(2), shP(2), nullptr);

    // Layer 3: y3 = pooled @ W3 + b3 -> h0 (in place), persistent pipeline
    mfma_gemm3_k<128, 0, 1, 8, ushort_t><<<GP, 256, 0, stream>>>(
        h0, wt3, b3, nullptr, nullptr, h0, accum + 768);
    finalize_acc_k<<<1, 128, 0, stream>>>(accum + 768, g3, be3, scP(3), shP(3));

    // Layer 4: out = bnrelu3(y3) @ W4 + b4 -> d_out (fp32; overwrites y1 scratch)
    mfma_gemm3_k<64, 1, 0, 8, float><<<GP, 256, 0, stream>>>(
        h0, wt4, b4, scP(3), shP(3), out, nullptr);
}

// Round 8
// 347.417 us; speedup vs baseline: 2.0918x; 1.0233x over previous
//
#include <hip/hip_runtime.h>
#include <hip/hip_bf16.h>

// Problem constants (fixed by setup_inputs)
#define M_ROWS 262144   // B*A*T = 16*64*256
#define TILE_M 64
#define BK 32
#define INVM (1.0f / 262144.0f)

typedef unsigned short ushort_t;
typedef unsigned int uint_t;
typedef __attribute__((ext_vector_type(8))) short short8_t;   // 8 bf16 = 4 VGPRs
typedef __attribute__((ext_vector_type(4))) float float4_t;   // MFMA acc

// bf16 (stored as ushort) <-> fp32 helpers. Load is exact; store is RNE.
__device__ __forceinline__ float b2f(ushort_t u) {
    union { uint_t i; float f; } c; c.i = ((uint_t)u) << 16; return c.f;
}
__device__ __forceinline__ ushort_t f2b(float f) {
    union { float f; uint_t i; } c; c.f = f;
    uint_t u = c.i;
    return (ushort_t)((u + 0x7fffu + ((u >> 16) & 1u)) >> 16);
}
// packed 2xfp32 -> 2xbf16 (v_cvt_pk_bf16_f32 on gfx950, RNE)
__device__ __forceinline__ uint_t pack2(float a, float b) {
    union { __hip_bfloat162 h; uint_t u; } c;
    c.h = __float22bfloat162_rn(make_float2(a, b));
    return c.u;
}

// async global->LDS DMA, 16 B per lane; data lands at ldsbase + lane*16
__device__ __forceinline__ void gld_lds16(const ushort_t* g, ushort_t* l) {
    __builtin_amdgcn_global_load_lds((const __attribute__((address_space(1))) void*)g,
                                     (__attribute__((address_space(3))) void*)l, 16, 0, 0);
}

// BN finalize arithmetic (shared by all consumers): from accumulated sum/sumsq.
__device__ __forceinline__ void bn_coeff(float s, float q, float g, float be,
                                         float& sc, float& sh) {
    float mean = s * INVM;
    float var = q * INVM - mean * mean;
    sc = g * rsqrtf(var + 1e-5f);
    sh = fmaf(-mean, sc, be);
}

// ---------------------------------------------------------------------------
// Layer-1 N-SPLIT pipelined GEMM: C = [bnrelu0(X), P] @ W1 + b1 (K=256).
// Grid = 1024 blocks: blockIdx = tile*2 + nhalf; each block computes a 64-col
// half of N=128 for RPT=8 row-tiles. B half (64 rows x 256 K = 32 KB) resident;
// A double-buffered over (tile, kt) steps with DMA prefetch one step ahead.
// LDS ~67 KB -> 2 blocks/CU (8 waves/CU). Output C must NOT alias X or P
// (sibling blocks read full rows) -> C = d_out scratch.
// Waves 2x2 over the 64x64 sub-tile. Epilogue into Abuf[1] (free after kt=1).
// BN coeffs computed in-block from accumIn (finalize folded in); stats:
// per-block partials reduced in LDS, then atomicAdd into accumOut[256].
// ---------------------------------------------------------------------------
template<int RPT>
__launch_bounds__(256)
__global__ void gemm1s_k(const ushort_t* __restrict__ X, const ushort_t* __restrict__ P,
                         const ushort_t* __restrict__ WT, const float* __restrict__ bias,
                         const float* __restrict__ g, const float* __restrict__ be,
                         const float* __restrict__ accumIn,
                         ushort_t* __restrict__ C, float* __restrict__ accumOut) {
    __shared__ __attribute__((aligned(16))) ushort_t Bs[64 * 256];       // 32 KB
    __shared__ __attribute__((aligned(16))) ushort_t Abuf[2][64 * 128];  // 2x16 KB
    __shared__ float sred[4 * 64 * 2];
    __shared__ float s_sc[128], s_sh[128];

    const int tid = threadIdx.x;
    const int lane = tid & 63;
    const int wave = tid >> 6;
    const int wm = wave & 1, wn = wave >> 1;
    const int quad = lane >> 4, l16 = lane & 15;
    const int srow = lane >> 4, sp16 = lane & 15;   // A staging
    const int brow = lane >> 5, bs32 = lane & 31;   // B staging (512 B rows)
    const int tileId = blockIdx.x >> 1;
    const int n0 = (blockIdx.x & 1) * 64;           // column-half offset
    const int row0 = tileId * (RPT * 64);

    if (tid < 128) {
        float sc, sh;
        bn_coeff(accumIn[tid], accumIn[128 + tid], g[tid], be[tid], sc, sh);
        s_sc[tid] = sc; s_sh[tid] = sh;
    }

    // ---- stage B half (rows n0..n0+63 of WT, 512 B each): 32 chunks x 1 KB ----
    #pragma unroll
    for (int i = 0; i < 8; ++i) {
        int t = i * 4 + wave;
        int r = t * 2 + brow;                        // local B row 0..63
        int sp = (bs32 & 16) | ((bs32 ^ r) & 15);    // half-preserving XOR swizzle
        gld_lds16(WT + (size_t)(n0 + r) * 256 + sp * 8, Bs + t * 512);
    }

    auto stageA = [&](int it, int kt, int buf) {
        const ushort_t* src = kt ? P : X;
        int r0 = row0 + it * 64;
        #pragma unroll
        for (int i = 0; i < 4; ++i) {
            int t = i * 4 + wave;
            int r = t * 4 + srow;
            int sp = sp16 ^ (r & 15);
            gld_lds16(src + (size_t)(r0 + r) * 128 + sp * 8, Abuf[buf] + t * 512);
        }
    };
    stageA(0, 0, 0);

    float bvs[2];
    #pragma unroll
    for (int nt = 0; nt < 2; ++nt) bvs[nt] = bias[n0 + wn * 32 + nt * 16 + l16];
    float sSum[2] = {0.f, 0.f}, sSq[2] = {0.f, 0.f};

    int step = 0;
    for (int it = 0; it < RPT; ++it) {
        float4_t acc[2][2];
        #pragma unroll
        for (int mt = 0; mt < 2; ++mt)
            #pragma unroll
            for (int nt = 0; nt < 2; ++nt) acc[mt][nt] = (float4_t)0.f;

        #pragma unroll
        for (int kt = 0; kt < 2; ++kt) {
            __syncthreads();   // A(step) [+Bs on step 0] resident; prior epi reads done
            if (step + 1 < 2 * RPT) {
                int ns = step + 1;
                stageA(ns >> 1, ns & 1, ns & 1);
            }
            const ushort_t* As = Abuf[step & 1];
            #pragma unroll
            for (int kk = 0; kk < 4; ++kk) {
                int j = kk * 4 + quad;
                short8_t a0 = *(const short8_t*)&As[(wm * 32 + l16) * 128 + ((j ^ l16) * 8)];
                short8_t a1 = *(const short8_t*)&As[(wm * 32 + 16 + l16) * 128 + ((j ^ l16) * 8)];
                if (kt == 0) {   // bnrelu0 on X fragments
                    int kb = kk * 32 + quad * 8;
                    float4 c0 = *(const float4*)&s_sc[kb], c1 = *(const float4*)&s_sc[kb + 4];
                    float4 h0 = *(const float4*)&s_sh[kb], h1 = *(const float4*)&s_sh[kb + 4];
                    #pragma unroll
                    for (int z = 0; z < 2; ++z) {
                        ushort_t u[8];
                        *(short8_t*)u = z ? a1 : a0;
                        uint_t w[4];
                        w[0] = pack2(fmaxf(fmaf(b2f(u[0]), c0.x, h0.x), 0.f),
                                     fmaxf(fmaf(b2f(u[1]), c0.y, h0.y), 0.f));
                        w[1] = pack2(fmaxf(fmaf(b2f(u[2]), c0.z, h0.z), 0.f),
                                     fmaxf(fmaf(b2f(u[3]), c0.w, h0.w), 0.f));
                        w[2] = pack2(fmaxf(fmaf(b2f(u[4]), c1.x, h1.x), 0.f),
                                     fmaxf(fmaf(b2f(u[5]), c1.y, h1.y), 0.f));
                        w[3] = pack2(fmaxf(fmaf(b2f(u[6]), c1.z, h1.z), 0.f),
                                     fmaxf(fmaf(b2f(u[7]), c1.w, h1.w), 0.f));
                        short8_t rr;
                        *(uint4*)&rr = *(const uint4*)w;
                        if (z) a1 = rr; else a0 = rr;
                    }
                }
                #pragma unroll
                for (int nt = 0; nt < 2; ++nt) {
                    int br = wn * 32 + nt * 16 + l16;
                    short8_t bf = *(const short8_t*)&Bs[br * 256 + kt * 128 + ((j ^ l16) * 8)];
                    acc[0][nt] = __builtin_amdgcn_mfma_f32_16x16x32_bf16(a0, bf, acc[0][nt], 0, 0, 0);
                    acc[1][nt] = __builtin_amdgcn_mfma_f32_16x16x32_bf16(a1, bf, acc[1][nt], 0, 0, 0);
                }
            }
            ++step;
        }

        // ---- bias + stats accumulate ----
        #pragma unroll
        for (int mt = 0; mt < 2; ++mt)
            #pragma unroll
            for (int nt = 0; nt < 2; ++nt)
                #pragma unroll
                for (int r = 0; r < 4; ++r) {
                    float v = acc[mt][nt][r] + bvs[nt];
                    acc[mt][nt][r] = v;
                    sSum[nt] += v; sSq[nt] = fmaf(v, v, sSq[nt]);
                }
        if (it == RPT - 1) {
            #pragma unroll
            for (int nt = 0; nt < 2; ++nt) {
                float s = sSum[nt], q = sSq[nt];
                s += __shfl_xor(s, 16); q += __shfl_xor(q, 16);
                s += __shfl_xor(s, 32); q += __shfl_xor(q, 32);
                if (lane < 16) {
                    int colL = wn * 32 + nt * 16 + l16;
                    sred[(wave * 64 + colL) * 2 + 0] = s;
                    sred[(wave * 64 + colL) * 2 + 1] = q;
                }
            }
        }
        __syncthreads();   // kt=1 reads of Abuf[1] done; sred visible

        // ---- swizzled transpose into Abuf[1] (free; in-flight DMA targets buf0) ----
        char* eb = (char*)Abuf[1];
        #pragma unroll
        for (int mt = 0; mt < 2; ++mt)
            #pragma unroll
            for (int nt = 0; nt < 2; ++nt) {
                int colL = wn * 32 + nt * 16 + l16;
                int bc = colL * 2;
                #pragma unroll
                for (int r = 0; r < 4; ++r) {
                    int row = wm * 32 + mt * 16 + quad * 4 + r;
                    int addr = row * 128 + ((((bc >> 4) ^ (row & 7)) << 4) | (bc & 15));
                    *(ushort_t*)(eb + addr) = f2b(acc[mt][nt][r]);
                }
            }
        if (it == RPT - 1 && tid < 128) {
            int colL = tid & 63, qs = tid >> 6;
            int wb = (colL >> 5) * 2;   // the two waves (wm=0,1) owning this col
            float v = sred[(wb * 64 + colL) * 2 + qs] + sred[((wb + 1) * 64 + colL) * 2 + qs];
            atomicAdd(accumOut + qs * 128 + n0 + colL, v);
        }
        __syncthreads();

        // ---- coalesced 16 B stores of the 64-col half (128 B per row) ----
        int r0s = row0 + it * 64;
        #pragma unroll
        for (int p = 0; p < 2; ++p) {
            int s = p * 256 + tid;
            int row = s >> 3, gg2 = s & 7;
            uint4 v = *(const uint4*)(eb + row * 128 + ((gg2 ^ (row & 7)) << 4));
            *(uint4*)((char*)(C + (size_t)(r0s + row) * 128 + n0) + gg2 * 16) = v;
        }
    }
}

// ---------------------------------------------------------------------------
// Persistent pipelined MFMA GEMM for K=128 layers: C = act(A)@W + bias.
// MODE==1: BN coeffs computed in-block from accumIn (finalize folded in).
// ---------------------------------------------------------------------------
template<int N, int MODE, int STATS, int RPT, typename CT>
__launch_bounds__(256)
__global__ void mfma_gemm3_k(const ushort_t* __restrict__ A, const ushort_t* __restrict__ WT,
                             const float* __restrict__ bias,
                             const float* __restrict__ g, const float* __restrict__ be,
                             const float* __restrict__ accumIn,
                             CT* __restrict__ C, float* __restrict__ accumOut) {
    constexpr int WN = N / 2;        // cols per wave-column (64 or 32)
    constexpr int NT = WN / 16;      // 4 (N=128) or 2 (N=64)

    __shared__ __attribute__((aligned(16))) ushort_t Bs[N * 128];
    __shared__ __attribute__((aligned(16))) ushort_t Abuf[2][64 * 128];
    __shared__ float sred[STATS ? 4 * N * 2 : 1];
    __shared__ float s_sc[MODE == 1 ? 128 : 1];
    __shared__ float s_sh[MODE == 1 ? 128 : 1];

    const int tid = threadIdx.x;
    const int lane = tid & 63;
    const int wave = tid >> 6;
    const int wm = wave & 1;
    const int wn = wave >> 1;
    const int quad = lane >> 4;
    const int l16 = lane & 15;
    const int srow = lane >> 4;
    const int sp16 = lane & 15;

    if (MODE == 1 && tid < 128) {
        float sc, sh;
        bn_coeff(accumIn[tid], accumIn[128 + tid], g[tid], be[tid], sc, sh);
        s_sc[tid] = sc; s_sh[tid] = sh;
    }

    #pragma unroll
    for (int i = 0; i < N / 16; ++i) {
        int t = i * 4 + wave;
        int r = t * 4 + srow;
        int sp = sp16 ^ (r & 15);
        gld_lds16(WT + (size_t)r * 128 + sp * 8, Bs + t * 512);
    }
    {
        int r0 = blockIdx.x * (RPT * 64);
        #pragma unroll
        for (int i = 0; i < 4; ++i) {
            int t = i * 4 + wave;
            int r = t * 4 + srow;
            int sp = sp16 ^ (r & 15);
            gld_lds16(A + (size_t)(r0 + r) * 128 + sp * 8, Abuf[0] + t * 512);
        }
    }

    float bvs[NT];
    #pragma unroll
    for (int nt = 0; nt < NT; ++nt) bvs[nt] = bias[wn * WN + nt * 16 + l16];
    float sSum[STATS ? NT : 1] = {0.f}, sSq[STATS ? NT : 1] = {0.f};

    for (int it = 0; it < RPT; ++it) {
        __syncthreads();
        if (it + 1 < RPT) {
            int r0 = blockIdx.x * (RPT * 64) + (it + 1) * 64;
            #pragma unroll
            for (int i = 0; i < 4; ++i) {
                int t = i * 4 + wave;
                int r = t * 4 + srow;
                int sp = sp16 ^ (r & 15);
                gld_lds16(A + (size_t)(r0 + r) * 128 + sp * 8, Abuf[(it + 1) & 1] + t * 512);
            }
        }
        const ushort_t* As = Abuf[it & 1];

        float4_t acc[2][NT];
        #pragma unroll
        for (int mt = 0; mt < 2; ++mt)
            #pragma unroll
            for (int nt = 0; nt < NT; ++nt) acc[mt][nt] = (float4_t)0.f;

        #pragma unroll
        for (int kk = 0; kk < 4; ++kk) {
            int j = kk * 4 + quad;
            short8_t a0 = *(const short8_t*)&As[(wm * 32 + l16) * 128 + ((j ^ l16) * 8)];
            short8_t a1 = *(const short8_t*)&As[(wm * 32 + 16 + l16) * 128 + ((j ^ l16) * 8)];
            if (MODE == 1) {
                int kb = kk * 32 + quad * 8;
                float4 c0 = *(const float4*)&s_sc[kb], c1 = *(const float4*)&s_sc[kb + 4];
                float4 h0 = *(const float4*)&s_sh[kb], h1 = *(const float4*)&s_sh[kb + 4];
                #pragma unroll
                for (int z = 0; z < 2; ++z) {
                    ushort_t u[8];
                    *(short8_t*)u = z ? a1 : a0;
                    uint_t w[4];
                    w[0] = pack2(fmaxf(fmaf(b2f(u[0]), c0.x, h0.x), 0.f),
                                 fmaxf(fmaf(b2f(u[1]), c0.y, h0.y), 0.f));
                    w[1] = pack2(fmaxf(fmaf(b2f(u[2]), c0.z, h0.z), 0.f),
                                 fmaxf(fmaf(b2f(u[3]), c0.w, h0.w), 0.f));
                    w[2] = pack2(fmaxf(fmaf(b2f(u[4]), c1.x, h1.x), 0.f),
                                 fmaxf(fmaf(b2f(u[5]), c1.y, h1.y), 0.f));
                    w[3] = pack2(fmaxf(fmaf(b2f(u[6]), c1.z, h1.z), 0.f),
                                 fmaxf(fmaf(b2f(u[7]), c1.w, h1.w), 0.f));
                    short8_t rr;
                    *(uint4*)&rr = *(const uint4*)w;
                    if (z) a1 = rr; else a0 = rr;
                }
            }
            #pragma unroll
            for (int nt = 0; nt < NT; ++nt) {
                short8_t bf = *(const short8_t*)&Bs[(wn * WN + nt * 16 + l16) * 128 + ((j ^ l16) * 8)];
                acc[0][nt] = __builtin_amdgcn_mfma_f32_16x16x32_bf16(a0, bf, acc[0][nt], 0, 0, 0);
                acc[1][nt] = __builtin_amdgcn_mfma_f32_16x16x32_bf16(a1, bf, acc[1][nt], 0, 0, 0);
            }
        }

        #pragma unroll
        for (int mt = 0; mt < 2; ++mt)
            #pragma unroll
            for (int nt = 0; nt < NT; ++nt)
                #pragma unroll
                for (int r = 0; r < 4; ++r) {
                    float v = acc[mt][nt][r] + bvs[nt];
                    acc[mt][nt][r] = v;
                    if (STATS) { sSum[nt] += v; sSq[nt] = fmaf(v, v, sSq[nt]); }
                }
        if (STATS && it == RPT - 1) {
            #pragma unroll
            for (int nt = 0; nt < NT; ++nt) {
                float s = sSum[nt], q = sSq[nt];
                s += __shfl_xor(s, 16); q += __shfl_xor(q, 16);
                s += __shfl_xor(s, 32); q += __shfl_xor(q, 32);
                if (lane < 16) {
                    int col = wn * WN + nt * 16 + l16;
                    sred[(wave * N + col) * 2 + 0] = s;
                    sred[(wave * N + col) * 2 + 1] = q;
                }
            }
        }
        __syncthreads();

        char* eb = (char*)Abuf[it & 1];
        #pragma unroll
        for (int mt = 0; mt < 2; ++mt)
            #pragma unroll
            for (int nt = 0; nt < NT; ++nt) {
                int col = wn * WN + nt * 16 + l16;
                int bc = col * (int)sizeof(CT);
                #pragma unroll
                for (int r = 0; r < 4; ++r) {
                    int row = wm * 32 + mt * 16 + quad * 4 + r;
                    int addr = row * 256 + ((((bc >> 4) ^ (row & 15)) << 4) | (bc & 15));
                    if constexpr (sizeof(CT) == 4) *(float*)(eb + addr) = acc[mt][nt][r];
                    else                           *(ushort_t*)(eb + addr) = f2b(acc[mt][nt][r]);
                }
            }
        if (STATS && it == RPT - 1) {
            int col = tid & (N - 1), qs = tid / N;
            int wb = (col / WN) * 2;
            float v = sred[(wb * N + col) * 2 + qs] + sred[((wb + 1) * N + col) * 2 + qs];
            atomicAdd(accumOut + qs * 128 + col, v);
        }
        __syncthreads();

        int r0 = blockIdx.x * (RPT * 64) + it * 64;
        #pragma unroll
        for (int p = 0; p < 4; ++p) {
            int s = p * 256 + tid;
            int row = s >> 4, gg2 = s & 15;
            uint4 v = *(const uint4*)(eb + row * 256 + ((gg2 ^ (row & 15)) << 4));
            *(uint4*)((char*)(C + (size_t)(r0 + row) * N) + gg2 * 16) = v;
        }
    }
}

// ---------------------------------------------------------------------------
// fp32 vector GEMM (layer 0: K=32, fp32 input), grid-strided over RPT row
// tiles per block. Weights staged ONCE; A-tile async-stage split (issue loads
// early, ds_write late). Stats in registers across tiles -> one LDS reduce +
// 256 atomics per block (512 blocks -> 131K atomics, proven-safe count).
// ---------------------------------------------------------------------------
template<int K, int N, int RPT>
__launch_bounds__(256)
__global__ void gemm_f32_k(const float* __restrict__ A, const float* __restrict__ W,
                           const float* __restrict__ bias, ushort_t* __restrict__ C,
                           float* __restrict__ accum) {
    constexpr int TX = N / 4;        // 32
    constexpr int TY = 256 / TX;     // 8
    constexpr int RM = TILE_M / TY;  // 8

    __shared__ float As[2][TILE_M][BK + 1];
    __shared__ float Ws[BK][N];
    __shared__ float redst[2][TY][N];

    const int tid = threadIdx.x;
    const int tx = tid % TX;
    const int ty = tid / TX;
    const int row0 = blockIdx.x * (RPT * TILE_M);
    const int arow = tid >> 2;
    const int acol = (tid & 3) * 8;

    // ---- stage weights once (K=32 -> whole K fits one tile) ----
    #pragma unroll
    for (int i = 0; i < (BK * N) / 256; ++i) {
        int e = i * 256 + tid;
        Ws[e / N][e % N] = W[(size_t)(e / N) * N + e % N];
    }
    // ---- preload tile 0 A ----
    {
        const float4* p = (const float4*)&A[(size_t)(row0 + arow) * K + acol];
        float4 x0 = p[0], x1 = p[1];
        As[0][arow][acol + 0] = x0.x; As[0][arow][acol + 1] = x0.y;
        As[0][arow][acol + 2] = x0.z; As[0][arow][acol + 3] = x0.w;
        As[0][arow][acol + 4] = x1.x; As[0][arow][acol + 5] = x1.y;
        As[0][arow][acol + 6] = x1.z; As[0][arow][acol + 7] = x1.w;
    }

    float4 bv = *(const float4*)&bias[tx * 4];
    float s[4] = {0, 0, 0, 0}, q[4] = {0, 0, 0, 0};

    for (int it = 0; it < RPT; ++it) {
        __syncthreads();   // As[it&1] (and Ws on it=0) resident
        // issue next tile's loads EARLY (latency hides under FMA loop)
        float4 nx0, nx1;
        if (it + 1 < RPT) {
            const float4* p = (const float4*)&A[(size_t)(row0 + (it + 1) * TILE_M + arow) * K + acol];
            nx0 = p[0]; nx1 = p[1];
        }

        float acc[RM][4];
        #pragma unroll
        for (int r = 0; r < RM; ++r)
            #pragma unroll
            for (int c = 0; c < 4; ++c) acc[r][c] = 0.f;
        #pragma unroll
        for (int kk = 0; kk < BK; ++kk) {
            float4 wv = *(const float4*)&Ws[kk][tx * 4];
            #pragma unroll
            for (int r = 0; r < RM; ++r) {
                float a = As[it & 1][ty * RM + r][kk];
                acc[r][0] = fmaf(a, wv.x, acc[r][0]);
                acc[r][1] = fmaf(a, wv.y, acc[r][1]);
                acc[r][2] = fmaf(a, wv.z, acc[r][2]);
                acc[r][3] = fmaf(a, wv.w, acc[r][3]);
            }
        }

        // bias + stats + coalesced bf16 store for this tile
        #pragma unroll
        for (int r = 0; r < RM; ++r) {
            float o[4];
            o[0] = acc[r][0] + bv.x; o[1] = acc[r][1] + bv.y;
            o[2] = acc[r][2] + bv.z; o[3] = acc[r][3] + bv.w;
            #pragma unroll
            for (int c = 0; c < 4; ++c) { s[c] += o[c]; q[c] = fmaf(o[c], o[c], q[c]); }
            size_t off = (size_t)(row0 + it * TILE_M + ty * RM + r) * N + tx * 4;
            uint2 ov;
            ov.x = pack2(o[0], o[1]);
            ov.y = pack2(o[2], o[3]);
            *(uint2*)&C[off] = ov;
        }

        // ds_write the prefetched tile LATE (vmcnt wait lands after compute)
        if (it + 1 < RPT) {
            int b = (it + 1) & 1;
            As[b][arow][acol + 0] = nx0.x; As[b][arow][acol + 1] = nx0.y;
            As[b][arow][acol + 2] = nx0.z; As[b][arow][acol + 3] = nx0.w;
            As[b][arow][acol + 4] = nx1.x; As[b][arow][acol + 5] = nx1.y;
            As[b][arow][acol + 6] = nx1.z; As[b][arow][acol + 7] = nx1.w;
        }
    }

    __syncthreads();   // As reads done; redst region free
    #pragma unroll
    for (int c = 0; c < 4; ++c) {
        redst[0][ty][tx * 4 + c] = s[c];
        redst[1][ty][tx * 4 + c] = q[c];
    }
    __syncthreads();
    {
        int col = tid & (N - 1), qs = tid / N;
        float v = 0.f;
        #pragma unroll
        for (int t = 0; t < TY; ++t) v += redst[qs][t][col];
        atomicAdd(accum + qs * 128 + col, v);
    }
}

// All four weight transposes in one launch: fp32 W[K][N] -> bf16 WT[N][K]
__global__ void transpose_all_k(const float* __restrict__ W1, const float* __restrict__ W2,
                                const float* __restrict__ W3, const float* __restrict__ W4,
                                ushort_t* __restrict__ wt1, ushort_t* __restrict__ wt2,
                                ushort_t* __restrict__ wt3, ushort_t* __restrict__ wt4) {
    int idx = blockIdx.x * 256 + threadIdx.x;
    if (idx < 32768) {                       // W1: 256 x 128
        int k = idx >> 7, n = idx & 127;
        wt1[(size_t)n * 256 + k] = f2b(W1[idx]);
    } else if (idx < 49152) {                // W2: 128 x 128
        int i = idx - 32768;
        int k = i >> 7, n = i & 127;
        wt2[(size_t)n * 128 + k] = f2b(W2[i]);
    } else if (idx < 65536) {                // W3: 128 x 128
        int i = idx - 49152;
        int k = i >> 7, n = i & 127;
        wt3[(size_t)n * 128 + k] = f2b(W3[i]);
    } else if (idx < 73728) {                // W4: 128 x 64
        int i = idx - 65536;
        int k = i >> 6, n = i & 63;
        wt4[(size_t)n * 128 + k] = f2b(W4[i]);
    }
}

// ---------------------------------------------------------------------------
// Chunked causal cummax, one block per (ba) sequence (T=256, 128 feats).
// BN coeffs computed per-thread from accumIn (finalize folded in).
// ---------------------------------------------------------------------------
template<int INPLACE>
__global__ __launch_bounds__(512) void scan_k(const ushort_t* __restrict__ Y,
                                              const float* __restrict__ g,
                                              const float* __restrict__ be,
                                              const float* __restrict__ accumIn,
                                              ushort_t* __restrict__ P) {
    const int tid = threadIdx.x;
    const int fp = tid & 63;
    const int chunk = tid >> 6;
    const size_t base = (size_t)blockIdx.x * 256 * 128 + fp * 2;
    float sc0, sh0, sc1, sh1;
    bn_coeff(accumIn[fp * 2],     accumIn[128 + fp * 2],     g[fp * 2],     be[fp * 2],     sc0, sh0);
    bn_coeff(accumIn[fp * 2 + 1], accumIn[128 + fp * 2 + 1], g[fp * 2 + 1], be[fp * 2 + 1], sc1, sh1);

    __shared__ float cmax[8][128];

    uint_t vals[32];
    float run0 = 0.f, run1 = 0.f;
    #pragma unroll
    for (int i = 0; i < 32; ++i) {
        size_t idx = base + (size_t)(chunk * 32 + i) * 128;
        uint_t u = *(const uint_t*)&Y[idx];
        float v0 = fmaxf(fmaf(b2f((ushort_t)(u & 0xffff)), sc0, sh0), 0.f);
        float v1 = fmaxf(fmaf(b2f((ushort_t)(u >> 16)), sc1, sh1), 0.f);
        run0 = fmaxf(run0, v0);
        run1 = fmaxf(run1, v1);
        vals[i] = pack2(v0, v1);
    }
    cmax[chunk][fp * 2] = run0;
    cmax[chunk][fp * 2 + 1] = run1;
    __syncthreads();
    float p0 = 0.f, p1 = 0.f;
    for (int c = 0; c < chunk; ++c) {
        p0 = fmaxf(p0, cmax[c][fp * 2]);
        p1 = fmaxf(p1, cmax[c][fp * 2 + 1]);
    }
    run0 = p0; run1 = p1;
    ushort_t* dst = INPLACE ? (ushort_t*)Y : P;
    #pragma unroll
    for (int i = 0; i < 32; ++i) {
        uint_t u = vals[i];
        run0 = fmaxf(run0, b2f((ushort_t)(u & 0xffff)));
        run1 = fmaxf(run1, b2f((ushort_t)(u >> 16)));
        *(uint_t*)&dst[base + (size_t)(chunk * 32 + i) * 128] = pack2(run0, run1);
    }
}

extern "C" void kernel_launch(void* const* d_in, const int* in_sizes, int n_in,
                              void* d_out, int out_size, void* d_ws, size_t ws_size,
                              hipStream_t stream) {
    const float* poly = (const float*)d_in[0];
    const float* W0 = (const float*)d_in[1];
    const float* b0 = (const float*)d_in[2];
    const float* g0 = (const float*)d_in[3];
    const float* be0 = (const float*)d_in[4];
    const float* W1 = (const float*)d_in[5];
    const float* b1 = (const float*)d_in[6];
    const float* g1 = (const float*)d_in[7];
    const float* be1 = (const float*)d_in[8];
    const float* W2 = (const float*)d_in[9];
    const float* b2 = (const float*)d_in[10];
    const float* g2 = (const float*)d_in[11];
    const float* be2 = (const float*)d_in[12];
    const float* W3 = (const float*)d_in[13];
    const float* b3 = (const float*)d_in[14];
    const float* g3 = (const float*)d_in[15];
    const float* be3 = (const float*)d_in[16];
    const float* W4 = (const float*)d_in[17];
    const float* b4 = (const float*)d_in[18];
    float* out = (float*)d_out;

    float* st = (float*)d_ws;
    float* accum = st + 1048576;            // 4 layers x 256 floats
    ushort_t* wt1 = (ushort_t*)((char*)d_ws + 4263936);         // 128 x 256
    ushort_t* wt2 = wt1 + 128 * 256;                            // 128 x 128
    ushort_t* wt3 = wt2 + 128 * 128;                            // 128 x 128
    ushort_t* wt4 = wt3 + 128 * 128;                            // 64 x 128
    ushort_t* h0 = (ushort_t*)((char*)d_ws + 4263936 + 147456);
    ushort_t* h1 = h0 + (size_t)M_ROWS * 128;
    ushort_t* y1 = (ushort_t*)out;   // d_out doubles as y1 scratch (M*128 bf16
                                     // == out_size bytes); overwritten by L4.

    const int GP = M_ROWS / (64 * 8);   // 512 (persistent kernels, RPT=8)
    const int GBA = 1024;               // one block per (b,a) sequence

    // zero all stat accumulators (4 layers x 256 floats) before any atomics
    hipMemsetAsync(accum, 0, 1024 * sizeof(float), stream);

    // Layer 0 (fp32 precision): y0 = poly @ W0 + b0 -> h0 (raw bf16) + stats(accum)
    gemm_f32_k<32, 128, 8><<<GP, 256, 0, stream>>>(poly, W0, b0, h0, accum);
    transpose_all_k<<<288, 256, 0, stream>>>(W1, W2, W3, W4, wt1, wt2, wt3, wt4);

    // P = cummax(bnrelu0(y0)) -> h1 ; h0 stays RAW y0 (BN0 finalize folded in)
    scan_k<0><<<GBA, 512, 0, stream>>>(h0, g0, be0, accum, h1);

    // Layer 1: y1 = [bnrelu0(y0), P] @ W1 + b1 -> d_out scratch; stats -> accum+256
    gemm1s_k<8><<<2 * GP, 256, 0, stream>>>(h0, h1, wt1, b1, g0, be0, accum,
                                            y1, accum + 256);

    // Layer 2: y2 = bnrelu1(y1) @ W2 + b2 : d_out -> h0; stats -> accum+512
    mfma_gemm3_k<128, 1, 1, 8, ushort_t><<<GP, 256, 0, stream>>>(
        y1, wt2, b2, g1, be1, accum + 256, h0, accum + 512);

    // pooled = cummax(bnrelu2(y2)) in place in h0 (BN2 finalize folded in)
    scan_k<1><<<GBA, 512, 0, stream>>>(h0, g2, be2, accum + 512, nullptr);

    // Layer 3: y3 = pooled @ W3 + b3 -> h0 (in place); stats -> accum+768
    mfma_gemm3_k<128, 0, 1, 8, ushort_t><<<GP, 256, 0, stream>>>(
        h0, wt3, b3, nullptr, nullptr, nullptr, h0, accum + 768);

    // Layer 4: out = bnrelu3(y3) @ W4 + b4 -> d_out (fp32; overwrites y1 scratch)
    mfma_gemm3_k<64, 1, 0, 8, float><<<GP, 256, 0, stream>>>(
        h0, wt4, b4, g3, be3, accum + 768, out, nullptr);
}

// Round 9
// 344.372 us; speedup vs baseline: 2.1103x; 1.0088x over previous
//
#include <hip/hip_runtime.h>
#include <hip/hip_bf16.h>

// Problem constants (fixed by setup_inputs)
#define M_ROWS 262144   // B*A*T = 16*64*256
#define TILE_M 64
#define BK 32
#define INVM (1.0f / 262144.0f)

typedef unsigned short ushort_t;
typedef unsigned int uint_t;
typedef __attribute__((ext_vector_type(8))) short short8_t;   // 8 bf16 = 4 VGPRs
typedef __attribute__((ext_vector_type(4))) float float4_t;   // MFMA acc

// bf16 (stored as ushort) <-> fp32 helpers. Load is exact; store is RNE.
__device__ __forceinline__ float b2f(ushort_t u) {
    union { uint_t i; float f; } c; c.i = ((uint_t)u) << 16; return c.f;
}
__device__ __forceinline__ ushort_t f2b(float f) {
    union { float f; uint_t i; } c; c.f = f;
    uint_t u = c.i;
    return (ushort_t)((u + 0x7fffu + ((u >> 16) & 1u)) >> 16);
}
// packed 2xfp32 -> 2xbf16 (v_cvt_pk_bf16_f32 on gfx950, RNE)
__device__ __forceinline__ uint_t pack2(float a, float b) {
    union { __hip_bfloat162 h; uint_t u; } c;
    c.h = __float22bfloat162_rn(make_float2(a, b));
    return c.u;
}

// async global->LDS DMA, 16 B per lane; data lands at ldsbase + lane*16
__device__ __forceinline__ void gld_lds16(const ushort_t* g, ushort_t* l) {
    __builtin_amdgcn_global_load_lds((const __attribute__((address_space(1))) void*)g,
                                     (__attribute__((address_space(3))) void*)l, 16, 0, 0);
}

// BN finalize arithmetic (shared by all consumers): from accumulated sum/sumsq.
__device__ __forceinline__ void bn_coeff(float s, float q, float g, float be,
                                         float& sc, float& sh) {
    float mean = s * INVM;
    float var = q * INVM - mean * mean;
    sc = g * rsqrtf(var + 1e-5f);
    sh = fmaf(-mean, sc, be);
}

// ---------------------------------------------------------------------------
// Layer-1 N-SPLIT pipelined GEMM with FUSED causal-cummax:
//   C = [bnrelu0(X), cummax(bnrelu0(X))] @ W1 + b1  (K=256), X read ONCE.
// Grid = 1024 blocks: blockIdx = tile*2 + nhalf; each block = 64-col half of
// N=128 over RPT=8 row-tiles (512 rows = 2 whole sequences, in order).
// Per tile: kt0 MFMA on raw-X frags (act in regs) -> wave0 rewrites the tile
// in place with act+cummax (carries in regs, reset at sequence boundary
// it&3==0) -> kt1 MFMA reads P frags. No P staging, no P HBM traffic.
// BN coeffs computed in-block from accumIn; stats atomicAdd into accumOut.
// ---------------------------------------------------------------------------
template<int RPT>
__launch_bounds__(256)
__global__ void gemm1s_k(const ushort_t* __restrict__ X,
                         const ushort_t* __restrict__ WT, const float* __restrict__ bias,
                         const float* __restrict__ g, const float* __restrict__ be,
                         const float* __restrict__ accumIn,
                         ushort_t* __restrict__ C, float* __restrict__ accumOut) {
    __shared__ __attribute__((aligned(16))) ushort_t Bs[64 * 256];       // 32 KB
    __shared__ __attribute__((aligned(16))) ushort_t Abuf[2][64 * 128];  // 2x16 KB
    __shared__ float sred[4 * 64 * 2];
    __shared__ float s_sc[128], s_sh[128];

    const int tid = threadIdx.x;
    const int lane = tid & 63;
    const int wave = tid >> 6;
    const int wm = wave & 1, wn = wave >> 1;
    const int quad = lane >> 4, l16 = lane & 15;
    const int srow = lane >> 4, sp16 = lane & 15;   // A staging
    const int brow = lane >> 5, bs32 = lane & 31;   // B staging (512 B rows)
    const int tileId = blockIdx.x >> 1;
    const int n0 = (blockIdx.x & 1) * 64;           // column-half offset
    const int row0 = tileId * (RPT * 64);

    if (tid < 128) {
        float sc, sh;
        bn_coeff(accumIn[tid], accumIn[128 + tid], g[tid], be[tid], sc, sh);
        s_sc[tid] = sc; s_sh[tid] = sh;
    }

    // ---- stage B half (rows n0..n0+63 of WT, 512 B each): 32 chunks x 1 KB ----
    #pragma unroll
    for (int i = 0; i < 8; ++i) {
        int t = i * 4 + wave;
        int r = t * 2 + brow;                        // local B row 0..63
        int sp = (bs32 & 16) | ((bs32 ^ r) & 15);    // half-preserving XOR swizzle
        gld_lds16(WT + (size_t)(n0 + r) * 256 + sp * 8, Bs + t * 512);
    }

    auto stageX = [&](int it, int buf) {
        int r0 = row0 + it * 64;
        #pragma unroll
        for (int i = 0; i < 4; ++i) {
            int t = i * 4 + wave;
            int r = t * 4 + srow;
            int sp = sp16 ^ (r & 15);
            gld_lds16(X + (size_t)(r0 + r) * 128 + sp * 8, Abuf[buf] + t * 512);
        }
    };
    stageX(0, 0);

    float bvs[2];
    #pragma unroll
    for (int nt = 0; nt < 2; ++nt) bvs[nt] = bias[n0 + wn * 32 + nt * 16 + l16];
    float sSum[2] = {0.f, 0.f}, sSq[2] = {0.f, 0.f};
    float run0 = 0.f, run1 = 0.f;      // wave0 scan carries (cols 2*lane, 2*lane+1)

    for (int it = 0; it < RPT; ++it) {
        __syncthreads();   // (A) X(it) resident; prior epi-store reads done
        const ushort_t* As = Abuf[it & 1];

        float4_t acc[2][2];
        #pragma unroll
        for (int mt = 0; mt < 2; ++mt)
            #pragma unroll
            for (int nt = 0; nt < 2; ++nt) acc[mt][nt] = (float4_t)0.f;

        // ---- kt0: act-on-fragments from raw X; B kt=0 half ----
        #pragma unroll
        for (int kk = 0; kk < 4; ++kk) {
            int j = kk * 4 + quad;
            short8_t a0 = *(const short8_t*)&As[(wm * 32 + l16) * 128 + ((j ^ l16) * 8)];
            short8_t a1 = *(const short8_t*)&As[(wm * 32 + 16 + l16) * 128 + ((j ^ l16) * 8)];
            {
                int kb = kk * 32 + quad * 8;
                float4 c0 = *(const float4*)&s_sc[kb], c1 = *(const float4*)&s_sc[kb + 4];
                float4 h0 = *(const float4*)&s_sh[kb], h1 = *(const float4*)&s_sh[kb + 4];
                #pragma unroll
                for (int z = 0; z < 2; ++z) {
                    ushort_t u[8];
                    *(short8_t*)u = z ? a1 : a0;
                    uint_t w[4];
                    w[0] = pack2(fmaxf(fmaf(b2f(u[0]), c0.x, h0.x), 0.f),
                                 fmaxf(fmaf(b2f(u[1]), c0.y, h0.y), 0.f));
                    w[1] = pack2(fmaxf(fmaf(b2f(u[2]), c0.z, h0.z), 0.f),
                                 fmaxf(fmaf(b2f(u[3]), c0.w, h0.w), 0.f));
                    w[2] = pack2(fmaxf(fmaf(b2f(u[4]), c1.x, h1.x), 0.f),
                                 fmaxf(fmaf(b2f(u[5]), c1.y, h1.y), 0.f));
                    w[3] = pack2(fmaxf(fmaf(b2f(u[6]), c1.z, h1.z), 0.f),
                                 fmaxf(fmaf(b2f(u[7]), c1.w, h1.w), 0.f));
                    short8_t rr;
                    *(uint4*)&rr = *(const uint4*)w;
                    if (z) a1 = rr; else a0 = rr;
                }
            }
            #pragma unroll
            for (int nt = 0; nt < 2; ++nt) {
                int br = wn * 32 + nt * 16 + l16;
                short8_t bf = *(const short8_t*)&Bs[br * 256 + ((j ^ l16) * 8)];
                acc[0][nt] = __builtin_amdgcn_mfma_f32_16x16x32_bf16(a0, bf, acc[0][nt], 0, 0, 0);
                acc[1][nt] = __builtin_amdgcn_mfma_f32_16x16x32_bf16(a1, bf, acc[1][nt], 0, 0, 0);
            }
        }
        __syncthreads();   // (B) kt0 fragment reads done

        // ---- wave0: act + causal cummax in place over the 64-row tile ----
        if (wave == 0) {
            if ((it & 3) == 0) { run0 = 0.f; run1 = 0.f; }   // sequence boundary
            int j0 = lane >> 2;
            int off = (lane & 3) * 2;
            float sc0 = s_sc[2 * lane], sh0 = s_sh[2 * lane];
            float sc1 = s_sc[2 * lane + 1], sh1 = s_sh[2 * lane + 1];
            ushort_t* Aw = (ushort_t*)Abuf[it & 1];
            #pragma unroll
            for (int h2 = 0; h2 < 4; ++h2) {
                uint_t sv[16];
                #pragma unroll
                for (int i = 0; i < 16; ++i) {
                    int r = h2 * 16 + i;
                    sv[i] = *(const uint_t*)&Aw[r * 128 + ((j0 ^ (r & 15)) * 8) + off];
                }
                #pragma unroll
                for (int i = 0; i < 16; ++i) {
                    int r = h2 * 16 + i;
                    run0 = fmaxf(run0, fmaxf(fmaf(b2f((ushort_t)(sv[i] & 0xffff)), sc0, sh0), 0.f));
                    run1 = fmaxf(run1, fmaxf(fmaf(b2f((ushort_t)(sv[i] >> 16)), sc1, sh1), 0.f));
                    *(uint_t*)&Aw[r * 128 + ((j0 ^ (r & 15)) * 8) + off] = pack2(run0, run1);
                }
            }
        }
        __syncthreads();   // (C) P visible

        if (it + 1 < RPT) stageX(it + 1, (it + 1) & 1);   // DMA overlaps kt1+epi

        // ---- kt1: P fragments (no act); B kt=1 half ----
        #pragma unroll
        for (int kk = 0; kk < 4; ++kk) {
            int j = kk * 4 + quad;
            short8_t a0 = *(const short8_t*)&As[(wm * 32 + l16) * 128 + ((j ^ l16) * 8)];
            short8_t a1 = *(const short8_t*)&As[(wm * 32 + 16 + l16) * 128 + ((j ^ l16) * 8)];
            #pragma unroll
            for (int nt = 0; nt < 2; ++nt) {
                int br = wn * 32 + nt * 16 + l16;
                short8_t bf = *(const short8_t*)&Bs[br * 256 + 128 + ((j ^ l16) * 8)];
                acc[0][nt] = __builtin_amdgcn_mfma_f32_16x16x32_bf16(a0, bf, acc[0][nt], 0, 0, 0);
                acc[1][nt] = __builtin_amdgcn_mfma_f32_16x16x32_bf16(a1, bf, acc[1][nt], 0, 0, 0);
            }
        }

        // ---- bias + stats accumulate ----
        #pragma unroll
        for (int mt = 0; mt < 2; ++mt)
            #pragma unroll
            for (int nt = 0; nt < 2; ++nt)
                #pragma unroll
                for (int r = 0; r < 4; ++r) {
                    float v = acc[mt][nt][r] + bvs[nt];
                    acc[mt][nt][r] = v;
                    sSum[nt] += v; sSq[nt] = fmaf(v, v, sSq[nt]);
                }
        if (it == RPT - 1) {
            #pragma unroll
            for (int nt = 0; nt < 2; ++nt) {
                float s = sSum[nt], q = sSq[nt];
                s += __shfl_xor(s, 16); q += __shfl_xor(q, 16);
                s += __shfl_xor(s, 32); q += __shfl_xor(q, 32);
                if (lane < 16) {
                    int colL = wn * 32 + nt * 16 + l16;
                    sred[(wave * 64 + colL) * 2 + 0] = s;
                    sred[(wave * 64 + colL) * 2 + 1] = q;
                }
            }
        }
        __syncthreads();   // (D) kt1 reads of Abuf done; sred visible

        // ---- swizzled transpose into Abuf[it&1] (dead after kt1) ----
        char* eb = (char*)Abuf[it & 1];
        #pragma unroll
        for (int mt = 0; mt < 2; ++mt)
            #pragma unroll
            for (int nt = 0; nt < 2; ++nt) {
                int colL = wn * 32 + nt * 16 + l16;
                int bc = colL * 2;
                #pragma unroll
                for (int r = 0; r < 4; ++r) {
                    int row = wm * 32 + mt * 16 + quad * 4 + r;
                    int addr = row * 128 + ((((bc >> 4) ^ (row & 7)) << 4) | (bc & 15));
                    *(ushort_t*)(eb + addr) = f2b(acc[mt][nt][r]);
                }
            }
        if (it == RPT - 1 && tid < 128) {
            int colL = tid & 63, qs = tid >> 6;
            int wb = (colL >> 5) * 2;   // the two waves (wm=0,1) owning this col
            float v = sred[(wb * 64 + colL) * 2 + qs] + sred[((wb + 1) * 64 + colL) * 2 + qs];
            atomicAdd(accumOut + qs * 128 + n0 + colL, v);
        }
        __syncthreads();   // (E) epi tile resident

        // ---- coalesced 16 B stores of the 64-col half (128 B per row) ----
        int r0s = row0 + it * 64;
        #pragma unroll
        for (int p = 0; p < 2; ++p) {
            int s = p * 256 + tid;
            int row = s >> 3, gg2 = s & 7;
            uint4 v = *(const uint4*)(eb + row * 128 + ((gg2 ^ (row & 7)) << 4));
            *(uint4*)((char*)(C + (size_t)(r0s + row) * 128 + n0) + gg2 * 16) = v;
        }
    }
}

// ---------------------------------------------------------------------------
// Persistent pipelined MFMA GEMM for K=128 layers: C = act(A)@W + bias.
// MODE==1: act-on-fragments (coeffs from accumIn).
// MODE==2: FUSED act+causal-cummax — wave0 rewrites staged tile in place
//          before MFMA (carries in regs, reset at it&3==0); MFMA reads P raw.
// ---------------------------------------------------------------------------
template<int N, int MODE, int STATS, int RPT, typename CT>
__launch_bounds__(256)
__global__ void mfma_gemm3_k(const ushort_t* __restrict__ A, const ushort_t* __restrict__ WT,
                             const float* __restrict__ bias,
                             const float* __restrict__ g, const float* __restrict__ be,
                             const float* __restrict__ accumIn,
                             CT* __restrict__ C, float* __restrict__ accumOut) {
    constexpr int WN = N / 2;        // cols per wave-column (64 or 32)
    constexpr int NT = WN / 16;      // 4 (N=128) or 2 (N=64)

    __shared__ __attribute__((aligned(16))) ushort_t Bs[N * 128];
    __shared__ __attribute__((aligned(16))) ushort_t Abuf[2][64 * 128];
    __shared__ float sred[STATS ? 4 * N * 2 : 1];
    __shared__ float s_sc[MODE >= 1 ? 128 : 1];
    __shared__ float s_sh[MODE >= 1 ? 128 : 1];

    const int tid = threadIdx.x;
    const int lane = tid & 63;
    const int wave = tid >> 6;
    const int wm = wave & 1;
    const int wn = wave >> 1;
    const int quad = lane >> 4;
    const int l16 = lane & 15;
    const int srow = lane >> 4;
    const int sp16 = lane & 15;

    if (MODE >= 1 && tid < 128) {
        float sc, sh;
        bn_coeff(accumIn[tid], accumIn[128 + tid], g[tid], be[tid], sc, sh);
        s_sc[tid] = sc; s_sh[tid] = sh;
    }

    #pragma unroll
    for (int i = 0; i < N / 16; ++i) {
        int t = i * 4 + wave;
        int r = t * 4 + srow;
        int sp = sp16 ^ (r & 15);
        gld_lds16(WT + (size_t)r * 128 + sp * 8, Bs + t * 512);
    }
    {
        int r0 = blockIdx.x * (RPT * 64);
        #pragma unroll
        for (int i = 0; i < 4; ++i) {
            int t = i * 4 + wave;
            int r = t * 4 + srow;
            int sp = sp16 ^ (r & 15);
            gld_lds16(A + (size_t)(r0 + r) * 128 + sp * 8, Abuf[0] + t * 512);
        }
    }

    float bvs[NT];
    #pragma unroll
    for (int nt = 0; nt < NT; ++nt) bvs[nt] = bias[wn * WN + nt * 16 + l16];
    float sSum[STATS ? NT : 1] = {0.f}, sSq[STATS ? NT : 1] = {0.f};
    float run0 = 0.f, run1 = 0.f;      // MODE==2 scan carries (wave0 lanes)

    for (int it = 0; it < RPT; ++it) {
        __syncthreads();   // tile resident; prior epi-store reads done

        if constexpr (MODE == 2) {
            if (wave == 0) {
                if ((it & 3) == 0) { run0 = 0.f; run1 = 0.f; }   // sequence boundary
                int j0 = lane >> 2;
                int off = (lane & 3) * 2;
                float sc0 = s_sc[2 * lane], sh0 = s_sh[2 * lane];
                float sc1 = s_sc[2 * lane + 1], sh1 = s_sh[2 * lane + 1];
                ushort_t* Aw = (ushort_t*)Abuf[it & 1];
                #pragma unroll
                for (int h2 = 0; h2 < 4; ++h2) {
                    uint_t sv[16];
                    #pragma unroll
                    for (int i = 0; i < 16; ++i) {
                        int r = h2 * 16 + i;
                        sv[i] = *(const uint_t*)&Aw[r * 128 + ((j0 ^ (r & 15)) * 8) + off];
                    }
                    #pragma unroll
                    for (int i = 0; i < 16; ++i) {
                        int r = h2 * 16 + i;
                        run0 = fmaxf(run0, fmaxf(fmaf(b2f((ushort_t)(sv[i] & 0xffff)), sc0, sh0), 0.f));
                        run1 = fmaxf(run1, fmaxf(fmaf(b2f((ushort_t)(sv[i] >> 16)), sc1, sh1), 0.f));
                        *(uint_t*)&Aw[r * 128 + ((j0 ^ (r & 15)) * 8) + off] = pack2(run0, run1);
                    }
                }
            }
            __syncthreads();   // P visible to all waves
        }

        if (it + 1 < RPT) {
            int r0 = blockIdx.x * (RPT * 64) + (it + 1) * 64;
            #pragma unroll
            for (int i = 0; i < 4; ++i) {
                int t = i * 4 + wave;
                int r = t * 4 + srow;
                int sp = sp16 ^ (r & 15);
                gld_lds16(A + (size_t)(r0 + r) * 128 + sp * 8, Abuf[(it + 1) & 1] + t * 512);
            }
        }
        const ushort_t* As = Abuf[it & 1];

        float4_t acc[2][NT];
        #pragma unroll
        for (int mt = 0; mt < 2; ++mt)
            #pragma unroll
            for (int nt = 0; nt < NT; ++nt) acc[mt][nt] = (float4_t)0.f;

        #pragma unroll
        for (int kk = 0; kk < 4; ++kk) {
            int j = kk * 4 + quad;
            short8_t a0 = *(const short8_t*)&As[(wm * 32 + l16) * 128 + ((j ^ l16) * 8)];
            short8_t a1 = *(const short8_t*)&As[(wm * 32 + 16 + l16) * 128 + ((j ^ l16) * 8)];
            if (MODE == 1) {
                int kb = kk * 32 + quad * 8;
                float4 c0 = *(const float4*)&s_sc[kb], c1 = *(const float4*)&s_sc[kb + 4];
                float4 h0 = *(const float4*)&s_sh[kb], h1 = *(const float4*)&s_sh[kb + 4];
                #pragma unroll
                for (int z = 0; z < 2; ++z) {
                    ushort_t u[8];
                    *(short8_t*)u = z ? a1 : a0;
                    uint_t w[4];
                    w[0] = pack2(fmaxf(fmaf(b2f(u[0]), c0.x, h0.x), 0.f),
                                 fmaxf(fmaf(b2f(u[1]), c0.y, h0.y), 0.f));
                    w[1] = pack2(fmaxf(fmaf(b2f(u[2]), c0.z, h0.z), 0.f),
                                 fmaxf(fmaf(b2f(u[3]), c0.w, h0.w), 0.f));
                    w[2] = pack2(fmaxf(fmaf(b2f(u[4]), c1.x, h1.x), 0.f),
                                 fmaxf(fmaf(b2f(u[5]), c1.y, h1.y), 0.f));
                    w[3] = pack2(fmaxf(fmaf(b2f(u[6]), c1.z, h1.z), 0.f),
                                 fmaxf(fmaf(b2f(u[7]), c1.w, h1.w), 0.f));
                    short8_t rr;
                    *(uint4*)&rr = *(const uint4*)w;
                    if (z) a1 = rr; else a0 = rr;
                }
            }
            #pragma unroll
            for (int nt = 0; nt < NT; ++nt) {
                short8_t bf = *(const short8_t*)&Bs[(wn * WN + nt * 16 + l16) * 128 + ((j ^ l16) * 8)];
                acc[0][nt] = __builtin_amdgcn_mfma_f32_16x16x32_bf16(a0, bf, acc[0][nt], 0, 0, 0);
                acc[1][nt] = __builtin_amdgcn_mfma_f32_16x16x32_bf16(a1, bf, acc[1][nt], 0, 0, 0);
            }
        }

        #pragma unroll
        for (int mt = 0; mt < 2; ++mt)
            #pragma unroll
            for (int nt = 0; nt < NT; ++nt)
                #pragma unroll
                for (int r = 0; r < 4; ++r) {
                    float v = acc[mt][nt][r] + bvs[nt];
                    acc[mt][nt][r] = v;
                    if (STATS) { sSum[nt] += v; sSq[nt] = fmaf(v, v, sSq[nt]); }
                }
        if (STATS && it == RPT - 1) {
            #pragma unroll
            for (int nt = 0; nt < NT; ++nt) {
                float s = sSum[nt], q = sSq[nt];
                s += __shfl_xor(s, 16); q += __shfl_xor(q, 16);
                s += __shfl_xor(s, 32); q += __shfl_xor(q, 32);
                if (lane < 16) {
                    int col = wn * WN + nt * 16 + l16;
                    sred[(wave * N + col) * 2 + 0] = s;
                    sred[(wave * N + col) * 2 + 1] = q;
                }
            }
        }
        __syncthreads();

        char* eb = (char*)Abuf[it & 1];
        #pragma unroll
        for (int mt = 0; mt < 2; ++mt)
            #pragma unroll
            for (int nt = 0; nt < NT; ++nt) {
                int col = wn * WN + nt * 16 + l16;
                int bc = col * (int)sizeof(CT);
                #pragma unroll
                for (int r = 0; r < 4; ++r) {
                    int row = wm * 32 + mt * 16 + quad * 4 + r;
                    int addr = row * 256 + ((((bc >> 4) ^ (row & 15)) << 4) | (bc & 15));
                    if constexpr (sizeof(CT) == 4) *(float*)(eb + addr) = acc[mt][nt][r];
                    else                           *(ushort_t*)(eb + addr) = f2b(acc[mt][nt][r]);
                }
            }
        if (STATS && it == RPT - 1) {
            int col = tid & (N - 1), qs = tid / N;
            int wb = (col / WN) * 2;
            float v = sred[(wb * N + col) * 2 + qs] + sred[((wb + 1) * N + col) * 2 + qs];
            atomicAdd(accumOut + qs * 128 + col, v);
        }
        __syncthreads();

        int r0 = blockIdx.x * (RPT * 64) + it * 64;
        #pragma unroll
        for (int p = 0; p < 4; ++p) {
            int s = p * 256 + tid;
            int row = s >> 4, gg2 = s & 15;
            uint4 v = *(const uint4*)(eb + row * 256 + ((gg2 ^ (row & 15)) << 4));
            *(uint4*)((char*)(C + (size_t)(r0 + row) * N) + gg2 * 16) = v;
        }
    }
}

// ---------------------------------------------------------------------------
// fp32 vector GEMM (layer 0: K=32, fp32 input), grid-strided over RPT row
// tiles per block. Weights staged ONCE; A-tile async-stage split (issue loads
// early, ds_write late). Stats in registers across tiles -> one LDS reduce +
// 256 atomics per block (512 blocks -> 131K atomics, proven-safe count).
// ---------------------------------------------------------------------------
template<int K, int N, int RPT>
__launch_bounds__(256)
__global__ void gemm_f32_k(const float* __restrict__ A, const float* __restrict__ W,
                           const float* __restrict__ bias, ushort_t* __restrict__ C,
                           float* __restrict__ accum) {
    constexpr int TX = N / 4;        // 32
    constexpr int TY = 256 / TX;     // 8
    constexpr int RM = TILE_M / TY;  // 8

    __shared__ float As[2][TILE_M][BK + 1];
    __shared__ float Ws[BK][N];
    __shared__ float redst[2][TY][N];

    const int tid = threadIdx.x;
    const int tx = tid % TX;
    const int ty = tid / TX;
    const int row0 = blockIdx.x * (RPT * TILE_M);
    const int arow = tid >> 2;
    const int acol = (tid & 3) * 8;

    // ---- stage weights once (K=32 -> whole K fits one tile) ----
    #pragma unroll
    for (int i = 0; i < (BK * N) / 256; ++i) {
        int e = i * 256 + tid;
        Ws[e / N][e % N] = W[(size_t)(e / N) * N + e % N];
    }
    // ---- preload tile 0 A ----
    {
        const float4* p = (const float4*)&A[(size_t)(row0 + arow) * K + acol];
        float4 x0 = p[0], x1 = p[1];
        As[0][arow][acol + 0] = x0.x; As[0][arow][acol + 1] = x0.y;
        As[0][arow][acol + 2] = x0.z; As[0][arow][acol + 3] = x0.w;
        As[0][arow][acol + 4] = x1.x; As[0][arow][acol + 5] = x1.y;
        As[0][arow][acol + 6] = x1.z; As[0][arow][acol + 7] = x1.w;
    }

    float4 bv = *(const float4*)&bias[tx * 4];
    float s[4] = {0, 0, 0, 0}, q[4] = {0, 0, 0, 0};

    for (int it = 0; it < RPT; ++it) {
        __syncthreads();   // As[it&1] (and Ws on it=0) resident
        // issue next tile's loads EARLY (latency hides under FMA loop)
        float4 nx0, nx1;
        if (it + 1 < RPT) {
            const float4* p = (const float4*)&A[(size_t)(row0 + (it + 1) * TILE_M + arow) * K + acol];
            nx0 = p[0]; nx1 = p[1];
        }

        float acc[RM][4];
        #pragma unroll
        for (int r = 0; r < RM; ++r)
            #pragma unroll
            for (int c = 0; c < 4; ++c) acc[r][c] = 0.f;
        #pragma unroll
        for (int kk = 0; kk < BK; ++kk) {
            float4 wv = *(const float4*)&Ws[kk][tx * 4];
            #pragma unroll
            for (int r = 0; r < RM; ++r) {
                float a = As[it & 1][ty * RM + r][kk];
                acc[r][0] = fmaf(a, wv.x, acc[r][0]);
                acc[r][1] = fmaf(a, wv.y, acc[r][1]);
                acc[r][2] = fmaf(a, wv.z, acc[r][2]);
                acc[r][3] = fmaf(a, wv.w, acc[r][3]);
            }
        }

        // bias + stats + coalesced bf16 store for this tile
        #pragma unroll
        for (int r = 0; r < RM; ++r) {
            float o[4];
            o[0] = acc[r][0] + bv.x; o[1] = acc[r][1] + bv.y;
            o[2] = acc[r][2] + bv.z; o[3] = acc[r][3] + bv.w;
            #pragma unroll
            for (int c = 0; c < 4; ++c) { s[c] += o[c]; q[c] = fmaf(o[c], o[c], q[c]); }
            size_t off = (size_t)(row0 + it * TILE_M + ty * RM + r) * N + tx * 4;
            uint2 ov;
            ov.x = pack2(o[0], o[1]);
            ov.y = pack2(o[2], o[3]);
            *(uint2*)&C[off] = ov;
        }

        // ds_write the prefetched tile LATE (vmcnt wait lands after compute)
        if (it + 1 < RPT) {
            int b = (it + 1) & 1;
            As[b][arow][acol + 0] = nx0.x; As[b][arow][acol + 1] = nx0.y;
            As[b][arow][acol + 2] = nx0.z; As[b][arow][acol + 3] = nx0.w;
            As[b][arow][acol + 4] = nx1.x; As[b][arow][acol + 5] = nx1.y;
            As[b][arow][acol + 6] = nx1.z; As[b][arow][acol + 7] = nx1.w;
        }
    }

    __syncthreads();   // As reads done; redst region free
    #pragma unroll
    for (int c = 0; c < 4; ++c) {
        redst[0][ty][tx * 4 + c] = s[c];
        redst[1][ty][tx * 4 + c] = q[c];
    }
    __syncthreads();
    {
        int col = tid & (N - 1), qs = tid / N;
        float v = 0.f;
        #pragma unroll
        for (int t = 0; t < TY; ++t) v += redst[qs][t][col];
        atomicAdd(accum + qs * 128 + col, v);
    }
}

// All four weight transposes in one launch: fp32 W[K][N] -> bf16 WT[N][K]
__global__ void transpose_all_k(const float* __restrict__ W1, const float* __restrict__ W2,
                                const float* __restrict__ W3, const float* __restrict__ W4,
                                ushort_t* __restrict__ wt1, ushort_t* __restrict__ wt2,
                                ushort_t* __restrict__ wt3, ushort_t* __restrict__ wt4) {
    int idx = blockIdx.x * 256 + threadIdx.x;
    if (idx < 32768) {                       // W1: 256 x 128
        int k = idx >> 7, n = idx & 127;
        wt1[(size_t)n * 256 + k] = f2b(W1[idx]);
    } else if (idx < 49152) {                // W2: 128 x 128
        int i = idx - 32768;
        int k = i >> 7, n = i & 127;
        wt2[(size_t)n * 128 + k] = f2b(W2[i]);
    } else if (idx < 65536) {                // W3: 128 x 128
        int i = idx - 49152;
        int k = i >> 7, n = i & 127;
        wt3[(size_t)n * 128 + k] = f2b(W3[i]);
    } else if (idx < 73728) {                // W4: 128 x 64
        int i = idx - 65536;
        int k = i >> 6, n = i & 63;
        wt4[(size_t)n * 128 + k] = f2b(W4[i]);
    }
}

extern "C" void kernel_launch(void* const* d_in, const int* in_sizes, int n_in,
                              void* d_out, int out_size, void* d_ws, size_t ws_size,
                              hipStream_t stream) {
    const float* poly = (const float*)d_in[0];
    const float* W0 = (const float*)d_in[1];
    const float* b0 = (const float*)d_in[2];
    const float* g0 = (const float*)d_in[3];
    const float* be0 = (const float*)d_in[4];
    const float* W1 = (const float*)d_in[5];
    const float* b1 = (const float*)d_in[6];
    const float* g1 = (const float*)d_in[7];
    const float* be1 = (const float*)d_in[8];
    const float* W2 = (const float*)d_in[9];
    const float* b2 = (const float*)d_in[10];
    const float* g2 = (const float*)d_in[11];
    const float* be2 = (const float*)d_in[12];
    const float* W3 = (const float*)d_in[13];
    const float* b3 = (const float*)d_in[14];
    const float* g3 = (const float*)d_in[15];
    const float* be3 = (const float*)d_in[16];
    const float* W4 = (const float*)d_in[17];
    const float* b4 = (const float*)d_in[18];
    float* out = (float*)d_out;

    float* st = (float*)d_ws;
    float* accum = st + 1048576;            // 4 layers x 256 floats
    ushort_t* wt1 = (ushort_t*)((char*)d_ws + 4263936);         // 128 x 256
    ushort_t* wt2 = wt1 + 128 * 256;                            // 128 x 128
    ushort_t* wt3 = wt2 + 128 * 128;                            // 128 x 128
    ushort_t* wt4 = wt3 + 128 * 128;                            // 64 x 128
    ushort_t* h0 = (ushort_t*)((char*)d_ws + 4263936 + 147456);
    ushort_t* y1 = (ushort_t*)out;   // d_out doubles as y1 scratch (M*128 bf16
                                     // == out_size bytes); overwritten by L4.

    const int GP = M_ROWS / (64 * 8);   // 512 (persistent kernels, RPT=8)

    // zero all stat accumulators (4 layers x 256 floats) before any atomics
    hipMemsetAsync(accum, 0, 1024 * sizeof(float), stream);

    // Layer 0 (fp32 precision): y0 = poly @ W0 + b0 -> h0 (raw bf16) + stats(accum)
    gemm_f32_k<32, 128, 8><<<GP, 256, 0, stream>>>(poly, W0, b0, h0, accum);
    transpose_all_k<<<288, 256, 0, stream>>>(W1, W2, W3, W4, wt1, wt2, wt3, wt4);

    // Layer 1 (FUSED scan): y1 = [bnrelu0(y0), cummax(bnrelu0(y0))] @ W1 + b1
    //   -> d_out scratch; BN0 finalize folded in; stats -> accum+256
    gemm1s_k<8><<<2 * GP, 256, 0, stream>>>(h0, wt1, b1, g0, be0, accum,
                                            y1, accum + 256);

    // Layer 2: y2 = bnrelu1(y1) @ W2 + b2 : d_out -> h0; stats -> accum+512
    mfma_gemm3_k<128, 1, 1, 8, ushort_t><<<GP, 256, 0, stream>>>(
        y1, wt2, b2, g1, be1, accum + 256, h0, accum + 512);

    // Layer 3 (FUSED scan): y3 = cummax(bnrelu2(y2)) @ W3 + b3 -> h0 in place;
    //   BN2 finalize folded in; stats -> accum+768
    mfma_gemm3_k<128, 2, 1, 8, ushort_t><<<GP, 256, 0, stream>>>(
        h0, wt3, b3, g2, be2, accum + 512, h0, accum + 768);

    // Layer 4: out = bnrelu3(y3) @ W4 + b4 -> d_out (fp32; overwrites y1 scratch)
    mfma_gemm3_k<64, 1, 0, 8, float><<<GP, 256, 0, stream>>>(
        h0, wt4, b4, g3, be3, accum + 768, out, nullptr);
}

// Round 11
// 323.847 us; speedup vs baseline: 2.2441x; 1.0634x over previous
//
#include <hip/hip_runtime.h>
#include <hip/hip_bf16.h>

// Problem constants (fixed by setup_inputs)
#define M_ROWS 262144   // B*A*T = 16*64*256
#define TILE_M 64
#define BK 32
#define INVM (1.0f / 262144.0f)

typedef unsigned short ushort_t;
typedef unsigned int uint_t;
typedef __attribute__((ext_vector_type(8))) short short8_t;   // 8 bf16 = 4 VGPRs
typedef __attribute__((ext_vector_type(4))) float float4_t;   // MFMA acc

// bf16 (stored as ushort) <-> fp32 helpers. Load is exact; store is RNE.
__device__ __forceinline__ float b2f(ushort_t u) {
    union { uint_t i; float f; } c; c.i = ((uint_t)u) << 16; return c.f;
}
__device__ __forceinline__ ushort_t f2b(float f) {
    union { float f; uint_t i; } c; c.f = f;
    uint_t u = c.i;
    return (ushort_t)((u + 0x7fffu + ((u >> 16) & 1u)) >> 16);
}
// packed 2xfp32 -> 2xbf16 (v_cvt_pk_bf16_f32 on gfx950, RNE)
__device__ __forceinline__ uint_t pack2(float a, float b) {
    union { __hip_bfloat162 h; uint_t u; } c;
    c.h = __float22bfloat162_rn(make_float2(a, b));
    return c.u;
}

// async global->LDS DMA, 16 B per lane; data lands at ldsbase + lane*16
__device__ __forceinline__ void gld_lds16(const ushort_t* g, ushort_t* l) {
    __builtin_amdgcn_global_load_lds((const __attribute__((address_space(1))) void*)g,
                                     (__attribute__((address_space(3))) void*)l, 16, 0, 0);
}

// BN finalize arithmetic (shared by all consumers): from accumulated sum/sumsq.
__device__ __forceinline__ void bn_coeff(float s, float q, float g, float be,
                                         float& sc, float& sh) {
    float mean = s * INVM;
    float var = q * INVM - mean * mean;
    sc = g * rsqrtf(var + 1e-5f);
    sh = fmaf(-mean, sc, be);
}

// ---------------------------------------------------------------------------
// Layer-1 N-SPLIT pipelined GEMM with FUSED causal-cummax:
//   C = [bnrelu0(X), cummax(bnrelu0(X))] @ W1 + b1  (K=256), X read ONCE.
// Grid = 1024 blocks: blockIdx = tile*2 + nhalf; each block = 64-col half of
// N=128 over RPT=8 row-tiles (512 rows = 2 whole sequences, in order).
// Per tile: kt0 MFMA on raw-X frags (act in regs) -> 4-WAVE SEGMENTED scan
// (each wave locally scans its 16 rows into regs, chain=16; group totals in
// LDS; prefix-combine + inter-tile carry) -> kt1 MFMA reads P frags.
// Prefetch DMA issued at loop-top (full-tile overlap window).
// BN coeffs computed in-block from accumIn; stats atomicAdd into accumOut.
// ---------------------------------------------------------------------------
template<int RPT>
__launch_bounds__(256)
__global__ void gemm1s_k(const ushort_t* __restrict__ X,
                         const ushort_t* __restrict__ WT, const float* __restrict__ bias,
                         const float* __restrict__ g, const float* __restrict__ be,
                         const float* __restrict__ accumIn,
                         ushort_t* __restrict__ C, float* __restrict__ accumOut) {
    __shared__ __attribute__((aligned(16))) ushort_t Bs[64 * 256];       // 32 KB
    __shared__ __attribute__((aligned(16))) ushort_t Abuf[2][64 * 128];  // 2x16 KB
    __shared__ float sred[4 * 64 * 2];
    __shared__ float s_sc[128], s_sh[128];
    __shared__ float gtb[4 * 128];    // scan group totals
    __shared__ float carry[128];      // inter-tile scan carry

    const int tid = threadIdx.x;
    const int lane = tid & 63;
    const int wave = tid >> 6;
    const int wm = wave & 1, wn = wave >> 1;
    const int quad = lane >> 4, l16 = lane & 15;
    const int srow = lane >> 4, sp16 = lane & 15;   // A staging
    const int brow = lane >> 5, bs32 = lane & 31;   // B staging (512 B rows)
    const int tileId = blockIdx.x >> 1;
    const int n0 = (blockIdx.x & 1) * 64;           // column-half offset
    const int row0 = tileId * (RPT * 64);

    if (tid < 128) {
        float sc, sh;
        bn_coeff(accumIn[tid], accumIn[128 + tid], g[tid], be[tid], sc, sh);
        s_sc[tid] = sc; s_sh[tid] = sh;
    }

    // ---- stage B half (rows n0..n0+63 of WT, 512 B each): 32 chunks x 1 KB ----
    #pragma unroll
    for (int i = 0; i < 8; ++i) {
        int t = i * 4 + wave;
        int r = t * 2 + brow;                        // local B row 0..63
        int sp = (bs32 & 16) | ((bs32 ^ r) & 15);    // half-preserving XOR swizzle
        gld_lds16(WT + (size_t)(n0 + r) * 256 + sp * 8, Bs + t * 512);
    }

    auto stageX = [&](int it, int buf) {
        int r0 = row0 + it * 64;
        #pragma unroll
        for (int i = 0; i < 4; ++i) {
            int t = i * 4 + wave;
            int r = t * 4 + srow;
            int sp = sp16 ^ (r & 15);
            gld_lds16(X + (size_t)(r0 + r) * 128 + sp * 8, Abuf[buf] + t * 512);
        }
    };
    stageX(0, 0);

    float bvs[2];
    #pragma unroll
    for (int nt = 0; nt < 2; ++nt) bvs[nt] = bias[n0 + wn * 32 + nt * 16 + l16];
    float sSum[2] = {0.f, 0.f}, sSq[2] = {0.f, 0.f};

    const int j0 = lane >> 2;          // scan addressing: chunk within row
    const int of2 = (lane & 3) * 2;    // ushort offset within chunk (2 cols)
    __syncthreads();   // order s_sc/s_sh writes (tid<128) before hoisted reads
    const float ssc0 = s_sc[2 * lane], ssh0 = s_sh[2 * lane];
    const float ssc1 = s_sc[2 * lane + 1], ssh1 = s_sh[2 * lane + 1];

    for (int it = 0; it < RPT; ++it) {
        __syncthreads();   // (A) X(it) resident; prior epi-store reads done
        if (it + 1 < RPT) stageX(it + 1, (it + 1) & 1);   // DMA overlaps whole tile
        const ushort_t* As = Abuf[it & 1];

        float4_t acc[2][2];
        #pragma unroll
        for (int mt = 0; mt < 2; ++mt)
            #pragma unroll
            for (int nt = 0; nt < 2; ++nt) acc[mt][nt] = (float4_t)0.f;

        // ---- kt0: act-on-fragments from raw X; B kt=0 half ----
        #pragma unroll
        for (int kk = 0; kk < 4; ++kk) {
            int j = kk * 4 + quad;
            short8_t a0 = *(const short8_t*)&As[(wm * 32 + l16) * 128 + ((j ^ l16) * 8)];
            short8_t a1 = *(const short8_t*)&As[(wm * 32 + 16 + l16) * 128 + ((j ^ l16) * 8)];
            {
                int kb = kk * 32 + quad * 8;
                float4 c0 = *(const float4*)&s_sc[kb], c1 = *(const float4*)&s_sc[kb + 4];
                float4 h0 = *(const float4*)&s_sh[kb], h1 = *(const float4*)&s_sh[kb + 4];
                #pragma unroll
                for (int z = 0; z < 2; ++z) {
                    ushort_t u[8];
                    *(short8_t*)u = z ? a1 : a0;
                    uint_t w[4];
                    w[0] = pack2(fmaxf(fmaf(b2f(u[0]), c0.x, h0.x), 0.f),
                                 fmaxf(fmaf(b2f(u[1]), c0.y, h0.y), 0.f));
                    w[1] = pack2(fmaxf(fmaf(b2f(u[2]), c0.z, h0.z), 0.f),
                                 fmaxf(fmaf(b2f(u[3]), c0.w, h0.w), 0.f));
                    w[2] = pack2(fmaxf(fmaf(b2f(u[4]), c1.x, h1.x), 0.f),
                                 fmaxf(fmaf(b2f(u[5]), c1.y, h1.y), 0.f));
                    w[3] = pack2(fmaxf(fmaf(b2f(u[6]), c1.z, h1.z), 0.f),
                                 fmaxf(fmaf(b2f(u[7]), c1.w, h1.w), 0.f));
                    short8_t rr;
                    *(uint4*)&rr = *(const uint4*)w;
                    if (z) a1 = rr; else a0 = rr;
                }
            }
            #pragma unroll
            for (int nt = 0; nt < 2; ++nt) {
                int br = wn * 32 + nt * 16 + l16;
                short8_t bf = *(const short8_t*)&Bs[br * 256 + ((j ^ l16) * 8)];
                acc[0][nt] = __builtin_amdgcn_mfma_f32_16x16x32_bf16(a0, bf, acc[0][nt], 0, 0, 0);
                acc[1][nt] = __builtin_amdgcn_mfma_f32_16x16x32_bf16(a1, bf, acc[1][nt], 0, 0, 0);
            }
        }
        __syncthreads();   // (B) kt0 fragment reads done

        // ---- 4-wave segmented scan, pass 1: local act+cummax (rows wave*16..+15)
        float pv0[16], pv1[16];
        float base0, base1, lv0 = 0.f, lv1 = 0.f;
        {
            if (it & 3) { base0 = carry[2 * lane]; base1 = carry[2 * lane + 1]; }
            else        { base0 = 0.f; base1 = 0.f; }   // sequence boundary
            ushort_t* Aw = (ushort_t*)Abuf[it & 1];
            #pragma unroll
            for (int i = 0; i < 16; ++i) {
                int r = wave * 16 + i;
                uint_t u = *(const uint_t*)&Aw[r * 128 + ((j0 ^ (r & 15)) * 8) + of2];
                lv0 = fmaxf(lv0, fmaxf(fmaf(b2f((ushort_t)(u & 0xffff)), ssc0, ssh0), 0.f));
                lv1 = fmaxf(lv1, fmaxf(fmaf(b2f((ushort_t)(u >> 16)), ssc1, ssh1), 0.f));
                pv0[i] = lv0; pv1[i] = lv1;
            }
            gtb[wave * 128 + 2 * lane] = lv0;
            gtb[wave * 128 + 2 * lane + 1] = lv1;
        }
        __syncthreads();   // (B2) group totals visible; carry reads done

        // ---- pass 2: prefix-combine + write P in place ----
        {
            float o0 = base0, o1 = base1;
            for (int gg = 0; gg < wave; ++gg) {
                o0 = fmaxf(o0, gtb[gg * 128 + 2 * lane]);
                o1 = fmaxf(o1, gtb[gg * 128 + 2 * lane + 1]);
            }
            if (wave == 3) {   // next-tile carry (reads of old carry were pre-B2)
                carry[2 * lane]     = fmaxf(o0, lv0);
                carry[2 * lane + 1] = fmaxf(o1, lv1);
            }
            ushort_t* Aw = (ushort_t*)Abuf[it & 1];
            #pragma unroll
            for (int i = 0; i < 16; ++i) {
                int r = wave * 16 + i;
                *(uint_t*)&Aw[r * 128 + ((j0 ^ (r & 15)) * 8) + of2] =
                    pack2(fmaxf(pv0[i], o0), fmaxf(pv1[i], o1));
            }
        }
        __syncthreads();   // (C) P visible

        // ---- kt1: P fragments (no act); B kt=1 half ----
        #pragma unroll
        for (int kk = 0; kk < 4; ++kk) {
            int j = kk * 4 + quad;
            short8_t a0 = *(const short8_t*)&As[(wm * 32 + l16) * 128 + ((j ^ l16) * 8)];
            short8_t a1 = *(const short8_t*)&As[(wm * 32 + 16 + l16) * 128 + ((j ^ l16) * 8)];
            #pragma unroll
            for (int nt = 0; nt < 2; ++nt) {
                int br = wn * 32 + nt * 16 + l16;
                short8_t bf = *(const short8_t*)&Bs[br * 256 + 128 + ((j ^ l16) * 8)];
                acc[0][nt] = __builtin_amdgcn_mfma_f32_16x16x32_bf16(a0, bf, acc[0][nt], 0, 0, 0);
                acc[1][nt] = __builtin_amdgcn_mfma_f32_16x16x32_bf16(a1, bf, acc[1][nt], 0, 0, 0);
            }
        }

        // ---- bias + stats accumulate ----
        #pragma unroll
        for (int mt = 0; mt < 2; ++mt)
            #pragma unroll
            for (int nt = 0; nt < 2; ++nt)
                #pragma unroll
                for (int r = 0; r < 4; ++r) {
                    float v = acc[mt][nt][r] + bvs[nt];
                    acc[mt][nt][r] = v;
                    sSum[nt] += v; sSq[nt] = fmaf(v, v, sSq[nt]);
                }
        if (it == RPT - 1) {
            #pragma unroll
            for (int nt = 0; nt < 2; ++nt) {
                float s = sSum[nt], q = sSq[nt];
                s += __shfl_xor(s, 16); q += __shfl_xor(q, 16);
                s += __shfl_xor(s, 32); q += __shfl_xor(q, 32);
                if (lane < 16) {
                    int colL = wn * 32 + nt * 16 + l16;
                    sred[(wave * 64 + colL) * 2 + 0] = s;
                    sred[(wave * 64 + colL) * 2 + 1] = q;
                }
            }
        }
        __syncthreads();   // (D) kt1 reads of Abuf done; sred visible

        // ---- swizzled transpose into Abuf[it&1] (dead after kt1) ----
        char* eb = (char*)Abuf[it & 1];
        #pragma unroll
        for (int mt = 0; mt < 2; ++mt)
            #pragma unroll
            for (int nt = 0; nt < 2; ++nt) {
                int colL = wn * 32 + nt * 16 + l16;
                int bc = colL * 2;
                #pragma unroll
                for (int r = 0; r < 4; ++r) {
                    int row = wm * 32 + mt * 16 + quad * 4 + r;
                    int addr = row * 128 + ((((bc >> 4) ^ (row & 7)) << 4) | (bc & 15));
                    *(ushort_t*)(eb + addr) = f2b(acc[mt][nt][r]);
                }
            }
        if (it == RPT - 1 && tid < 128) {
            int colL = tid & 63, qs = tid >> 6;
            int wb = (colL >> 5) * 2;   // the two waves (wm=0,1) owning this col
            float v = sred[(wb * 64 + colL) * 2 + qs] + sred[((wb + 1) * 64 + colL) * 2 + qs];
            atomicAdd(accumOut + qs * 128 + n0 + colL, v);
        }
        __syncthreads();   // (E) epi tile resident

        // ---- coalesced 16 B stores of the 64-col half (128 B per row) ----
        int r0s = row0 + it * 64;
        #pragma unroll
        for (int p = 0; p < 2; ++p) {
            int s = p * 256 + tid;
            int row = s >> 3, gg2 = s & 7;
            uint4 v = *(const uint4*)(eb + row * 128 + ((gg2 ^ (row & 7)) << 4));
            *(uint4*)((char*)(C + (size_t)(r0s + row) * 128 + n0) + gg2 * 16) = v;
        }
    }
}

// ---------------------------------------------------------------------------
// Persistent pipelined MFMA GEMM for K=128 layers: C = act(A)@W + bias.
// MODE==1: act-on-fragments (coeffs from accumIn).
// MODE==2: FUSED act+causal-cummax via 4-wave segmented scan before MFMA
//          (local 16-row chains in regs + group-total prefix + carry).
// ---------------------------------------------------------------------------
template<int N, int MODE, int STATS, int RPT, typename CT>
__launch_bounds__(256)
__global__ void mfma_gemm3_k(const ushort_t* __restrict__ A, const ushort_t* __restrict__ WT,
                             const float* __restrict__ bias,
                             const float* __restrict__ g, const float* __restrict__ be,
                             const float* __restrict__ accumIn,
                             CT* __restrict__ C, float* __restrict__ accumOut) {
    constexpr int WN = N / 2;        // cols per wave-column (64 or 32)
    constexpr int NT = WN / 16;      // 4 (N=128) or 2 (N=64)

    __shared__ __attribute__((aligned(16))) ushort_t Bs[N * 128];
    __shared__ __attribute__((aligned(16))) ushort_t Abuf[2][64 * 128];
    __shared__ float sred[STATS ? 4 * N * 2 : 1];
    __shared__ float s_sc[MODE >= 1 ? 128 : 1];
    __shared__ float s_sh[MODE >= 1 ? 128 : 1];
    __shared__ float gtb[MODE == 2 ? 4 * 128 : 1];
    __shared__ float carry[MODE == 2 ? 128 : 1];

    const int tid = threadIdx.x;
    const int lane = tid & 63;
    const int wave = tid >> 6;
    const int wm = wave & 1;
    const int wn = wave >> 1;
    const int quad = lane >> 4;
    const int l16 = lane & 15;
    const int srow = lane >> 4;
    const int sp16 = lane & 15;

    if (MODE >= 1 && tid < 128) {
        float sc, sh;
        bn_coeff(accumIn[tid], accumIn[128 + tid], g[tid], be[tid], sc, sh);
        s_sc[tid] = sc; s_sh[tid] = sh;
    }

    #pragma unroll
    for (int i = 0; i < N / 16; ++i) {
        int t = i * 4 + wave;
        int r = t * 4 + srow;
        int sp = sp16 ^ (r & 15);
        gld_lds16(WT + (size_t)r * 128 + sp * 8, Bs + t * 512);
    }
    {
        int r0 = blockIdx.x * (RPT * 64);
        #pragma unroll
        for (int i = 0; i < 4; ++i) {
            int t = i * 4 + wave;
            int r = t * 4 + srow;
            int sp = sp16 ^ (r & 15);
            gld_lds16(A + (size_t)(r0 + r) * 128 + sp * 8, Abuf[0] + t * 512);
        }
    }

    float bvs[NT];
    #pragma unroll
    for (int nt = 0; nt < NT; ++nt) bvs[nt] = bias[wn * WN + nt * 16 + l16];
    float sSum[STATS ? NT : 1] = {0.f}, sSq[STATS ? NT : 1] = {0.f};

    const int j0 = lane >> 2;
    const int of2 = (lane & 3) * 2;

    for (int it = 0; it < RPT; ++it) {
        __syncthreads();   // tile resident; prior epi-store reads done

        if (it + 1 < RPT) {
            int r0 = blockIdx.x * (RPT * 64) + (it + 1) * 64;
            #pragma unroll
            for (int i = 0; i < 4; ++i) {
                int t = i * 4 + wave;
                int r = t * 4 + srow;
                int sp = sp16 ^ (r & 15);
                gld_lds16(A + (size_t)(r0 + r) * 128 + sp * 8, Abuf[(it + 1) & 1] + t * 512);
            }
        }

        if constexpr (MODE == 2) {
            // ---- 4-wave segmented scan: pass 1 (local act+cummax) ----
            float pv0[16], pv1[16];
            float base0, base1, lv0 = 0.f, lv1 = 0.f;
            float ssc0 = s_sc[2 * lane], ssh0 = s_sh[2 * lane];
            float ssc1 = s_sc[2 * lane + 1], ssh1 = s_sh[2 * lane + 1];
            {
                if (it & 3) { base0 = carry[2 * lane]; base1 = carry[2 * lane + 1]; }
                else        { base0 = 0.f; base1 = 0.f; }
                ushort_t* Aw = (ushort_t*)Abuf[it & 1];
                #pragma unroll
                for (int i = 0; i < 16; ++i) {
                    int r = wave * 16 + i;
                    uint_t u = *(const uint_t*)&Aw[r * 128 + ((j0 ^ (r & 15)) * 8) + of2];
                    lv0 = fmaxf(lv0, fmaxf(fmaf(b2f((ushort_t)(u & 0xffff)), ssc0, ssh0), 0.f));
                    lv1 = fmaxf(lv1, fmaxf(fmaf(b2f((ushort_t)(u >> 16)), ssc1, ssh1), 0.f));
                    pv0[i] = lv0; pv1[i] = lv1;
                }
                gtb[wave * 128 + 2 * lane] = lv0;
                gtb[wave * 128 + 2 * lane + 1] = lv1;
            }
            __syncthreads();   // group totals visible; carry reads done
            {
                float o0 = base0, o1 = base1;
                for (int gg = 0; gg < wave; ++gg) {
                    o0 = fmaxf(o0, gtb[gg * 128 + 2 * lane]);
                    o1 = fmaxf(o1, gtb[gg * 128 + 2 * lane + 1]);
                }
                if (wave == 3) {
                    carry[2 * lane]     = fmaxf(o0, lv0);
                    carry[2 * lane + 1] = fmaxf(o1, lv1);
                }
                ushort_t* Aw = (ushort_t*)Abuf[it & 1];
                #pragma unroll
                for (int i = 0; i < 16; ++i) {
                    int r = wave * 16 + i;
                    *(uint_t*)&Aw[r * 128 + ((j0 ^ (r & 15)) * 8) + of2] =
                        pack2(fmaxf(pv0[i], o0), fmaxf(pv1[i], o1));
                }
            }
            __syncthreads();   // P visible to all waves
        }

        const ushort_t* As = Abuf[it & 1];

        float4_t acc[2][NT];
        #pragma unroll
        for (int mt = 0; mt < 2; ++mt)
            #pragma unroll
            for (int nt = 0; nt < NT; ++nt) acc[mt][nt] = (float4_t)0.f;

        #pragma unroll
        for (int kk = 0; kk < 4; ++kk) {
            int j = kk * 4 + quad;
            short8_t a0 = *(const short8_t*)&As[(wm * 32 + l16) * 128 + ((j ^ l16) * 8)];
            short8_t a1 = *(const short8_t*)&As[(wm * 32 + 16 + l16) * 128 + ((j ^ l16) * 8)];
            if (MODE == 1) {
                int kb = kk * 32 + quad * 8;
                float4 c0 = *(const float4*)&s_sc[kb], c1 = *(const float4*)&s_sc[kb + 4];
                float4 h0 = *(const float4*)&s_sh[kb], h1 = *(const float4*)&s_sh[kb + 4];
                #pragma unroll
                for (int z = 0; z < 2; ++z) {
                    ushort_t u[8];
                    *(short8_t*)u = z ? a1 : a0;
                    uint_t w[4];
                    w[0] = pack2(fmaxf(fmaf(b2f(u[0]), c0.x, h0.x), 0.f),
                                 fmaxf(fmaf(b2f(u[1]), c0.y, h0.y), 0.f));
                    w[1] = pack2(fmaxf(fmaf(b2f(u[2]), c0.z, h0.z), 0.f),
                                 fmaxf(fmaf(b2f(u[3]), c0.w, h0.w), 0.f));
                    w[2] = pack2(fmaxf(fmaf(b2f(u[4]), c1.x, h1.x), 0.f),
                                 fmaxf(fmaf(b2f(u[5]), c1.y, h1.y), 0.f));
                    w[3] = pack2(fmaxf(fmaf(b2f(u[6]), c1.z, h1.z), 0.f),
                                 fmaxf(fmaf(b2f(u[7]), c1.w, h1.w), 0.f));
                    short8_t rr;
                    *(uint4*)&rr = *(const uint4*)w;
                    if (z) a1 = rr; else a0 = rr;
                }
            }
            #pragma unroll
            for (int nt = 0; nt < NT; ++nt) {
                short8_t bf = *(const short8_t*)&Bs[(wn * WN + nt * 16 + l16) * 128 + ((j ^ l16) * 8)];
                acc[0][nt] = __builtin_amdgcn_mfma_f32_16x16x32_bf16(a0, bf, acc[0][nt], 0, 0, 0);
                acc[1][nt] = __builtin_amdgcn_mfma_f32_16x16x32_bf16(a1, bf, acc[1][nt], 0, 0, 0);
            }
        }

        #pragma unroll
        for (int mt = 0; mt < 2; ++mt)
            #pragma unroll
            for (int nt = 0; nt < NT; ++nt)
                #pragma unroll
                for (int r = 0; r < 4; ++r) {
                    float v = acc[mt][nt][r] + bvs[nt];
                    acc[mt][nt][r] = v;
                    if (STATS) { sSum[nt] += v; sSq[nt] = fmaf(v, v, sSq[nt]); }
                }
        if (STATS && it == RPT - 1) {
            #pragma unroll
            for (int nt = 0; nt < NT; ++nt) {
                float s = sSum[nt], q = sSq[nt];
                s += __shfl_xor(s, 16); q += __shfl_xor(q, 16);
                s += __shfl_xor(s, 32); q += __shfl_xor(q, 32);
                if (lane < 16) {
                    int col = wn * WN + nt * 16 + l16;
                    sred[(wave * N + col) * 2 + 0] = s;
                    sred[(wave * N + col) * 2 + 1] = q;
                }
            }
        }
        __syncthreads();

        char* eb = (char*)Abuf[it & 1];
        #pragma unroll
        for (int mt = 0; mt < 2; ++mt)
            #pragma unroll
            for (int nt = 0; nt < NT; ++nt) {
                int col = wn * WN + nt * 16 + l16;
                int bc = col * (int)sizeof(CT);
                #pragma unroll
                for (int r = 0; r < 4; ++r) {
                    int row = wm * 32 + mt * 16 + quad * 4 + r;
                    int addr = row * 256 + ((((bc >> 4) ^ (row & 15)) << 4) | (bc & 15));
                    if constexpr (sizeof(CT) == 4) *(float*)(eb + addr) = acc[mt][nt][r];
                    else                           *(ushort_t*)(eb + addr) = f2b(acc[mt][nt][r]);
                }
            }
        if (STATS && it == RPT - 1) {
            int col = tid & (N - 1), qs = tid / N;
            int wb = (col / WN) * 2;
            float v = sred[(wb * N + col) * 2 + qs] + sred[((wb + 1) * N + col) * 2 + qs];
            atomicAdd(accumOut + qs * 128 + col, v);
        }
        __syncthreads();

        int r0 = blockIdx.x * (RPT * 64) + it * 64;
        #pragma unroll
        for (int p = 0; p < 4; ++p) {
            int s = p * 256 + tid;
            int row = s >> 4, gg2 = s & 15;
            uint4 v = *(const uint4*)(eb + row * 256 + ((gg2 ^ (row & 15)) << 4));
            *(uint4*)((char*)(C + (size_t)(r0 + row) * N) + gg2 * 16) = v;
        }
    }
}

// ---------------------------------------------------------------------------
// fp32 vector GEMM (layer 0: K=32, fp32 input), grid-strided over RPT row
// tiles per block. Weights staged ONCE; A-tile async-stage split (issue loads
// early, ds_write late). Stats in registers across tiles -> one LDS reduce +
// 256 atomics per block (512 blocks -> 131K atomics, proven-safe count).
// ---------------------------------------------------------------------------
template<int K, int N, int RPT>
__launch_bounds__(256)
__global__ void gemm_f32_k(const float* __restrict__ A, const float* __restrict__ W,
                           const float* __restrict__ bias, ushort_t* __restrict__ C,
                           float* __restrict__ accum) {
    constexpr int TX = N / 4;        // 32
    constexpr int TY = 256 / TX;     // 8
    constexpr int RM = TILE_M / TY;  // 8

    __shared__ float As[2][TILE_M][BK + 1];
    __shared__ float Ws[BK][N];
    __shared__ float redst[2][TY][N];

    const int tid = threadIdx.x;
    const int tx = tid % TX;
    const int ty = tid / TX;
    const int row0 = blockIdx.x * (RPT * TILE_M);
    const int arow = tid >> 2;
    const int acol = (tid & 3) * 8;

    // ---- stage weights once (K=32 -> whole K fits one tile) ----
    #pragma unroll
    for (int i = 0; i < (BK * N) / 256; ++i) {
        int e = i * 256 + tid;
        Ws[e / N][e % N] = W[(size_t)(e / N) * N + e % N];
    }
    // ---- preload tile 0 A ----
    {
        const float4* p = (const float4*)&A[(size_t)(row0 + arow) * K + acol];
        float4 x0 = p[0], x1 = p[1];
        As[0][arow][acol + 0] = x0.x; As[0][arow][acol + 1] = x0.y;
        As[0][arow][acol + 2] = x0.z; As[0][arow][acol + 3] = x0.w;
        As[0][arow][acol + 4] = x1.x; As[0][arow][acol + 5] = x1.y;
        As[0][arow][acol + 6] = x1.z; As[0][arow][acol + 7] = x1.w;
    }

    float4 bv = *(const float4*)&bias[tx * 4];
    float s[4] = {0, 0, 0, 0}, q[4] = {0, 0, 0, 0};

    for (int it = 0; it < RPT; ++it) {
        __syncthreads();   // As[it&1] (and Ws on it=0) resident
        // issue next tile's loads EARLY (latency hides under FMA loop)
        float4 nx0, nx1;
        if (it + 1 < RPT) {
            const float4* p = (const float4*)&A[(size_t)(row0 + (it + 1) * TILE_M + arow) * K + acol];
            nx0 = p[0]; nx1 = p[1];
        }

        float acc[RM][4];
        #pragma unroll
        for (int r = 0; r < RM; ++r)
            #pragma unroll
            for (int c = 0; c < 4; ++c) acc[r][c] = 0.f;
        #pragma unroll
        for (int kk = 0; kk < BK; ++kk) {
            float4 wv = *(const float4*)&Ws[kk][tx * 4];
            #pragma unroll
            for (int r = 0; r < RM; ++r) {
                float a = As[it & 1][ty * RM + r][kk];
                acc[r][0] = fmaf(a, wv.x, acc[r][0]);
                acc[r][1] = fmaf(a, wv.y, acc[r][1]);
                acc[r][2] = fmaf(a, wv.z, acc[r][2]);
                acc[r][3] = fmaf(a, wv.w, acc[r][3]);
            }
        }

        // bias + stats + coalesced bf16 store for this tile
        #pragma unroll
        for (int r = 0; r < RM; ++r) {
            float o[4];
            o[0] = acc[r][0] + bv.x; o[1] = acc[r][1] + bv.y;
            o[2] = acc[r][2] + bv.z; o[3] = acc[r][3] + bv.w;
            #pragma unroll
            for (int c = 0; c < 4; ++c) { s[c] += o[c]; q[c] = fmaf(o[c], o[c], q[c]); }
            size_t off = (size_t)(row0 + it * TILE_M + ty * RM + r) * N + tx * 4;
            uint2 ov;
            ov.x = pack2(o[0], o[1]);
            ov.y = pack2(o[2], o[3]);
            *(uint2*)&C[off] = ov;
        }

        // ds_write the prefetched tile LATE (vmcnt wait lands after compute)
        if (it + 1 < RPT) {
            int b = (it + 1) & 1;
            As[b][arow][acol + 0] = nx0.x; As[b][arow][acol + 1] = nx0.y;
            As[b][arow][acol + 2] = nx0.z; As[b][arow][acol + 3] = nx0.w;
            As[b][arow][acol + 4] = nx1.x; As[b][arow][acol + 5] = nx1.y;
            As[b][arow][acol + 6] = nx1.z; As[b][arow][acol + 7] = nx1.w;
        }
    }

    __syncthreads();   // As reads done; redst region free
    #pragma unroll
    for (int c = 0; c < 4; ++c) {
        redst[0][ty][tx * 4 + c] = s[c];
        redst[1][ty][tx * 4 + c] = q[c];
    }
    __syncthreads();
    {
        int col = tid & (N - 1), qs = tid / N;
        float v = 0.f;
        #pragma unroll
        for (int t = 0; t < TY; ++t) v += redst[qs][t][col];
        atomicAdd(accum + qs * 128 + col, v);
    }
}

// All four weight transposes in one launch: fp32 W[K][N] -> bf16 WT[N][K]
__global__ void transpose_all_k(const float* __restrict__ W1, const float* __restrict__ W2,
                                const float* __restrict__ W3, const float* __restrict__ W4,
                                ushort_t* __restrict__ wt1, ushort_t* __restrict__ wt2,
                                ushort_t* __restrict__ wt3, ushort_t* __restrict__ wt4) {
    int idx = blockIdx.x * 256 + threadIdx.x;
    if (idx < 32768) {                       // W1: 256 x 128
        int k = idx >> 7, n = idx & 127;
        wt1[(size_t)n * 256 + k] = f2b(W1[idx]);
    } else if (idx < 49152) {                // W2: 128 x 128
        int i = idx - 32768;
        int k = i >> 7, n = i & 127;
        wt2[(size_t)n * 128 + k] = f2b(W2[i]);
    } else if (idx < 65536) {                // W3: 128 x 128
        int i = idx - 49152;
        int k = i >> 7, n = i & 127;
        wt3[(size_t)n * 128 + k] = f2b(W3[i]);
    } else if (idx < 73728) {                // W4: 128 x 64
        int i = idx - 65536;
        int k = i >> 6, n = i & 63;
        wt4[(size_t)n * 128 + k] = f2b(W4[i]);
    }
}

extern "C" void kernel_launch(void* const* d_in, const int* in_sizes, int n_in,
                              void* d_out, int out_size, void* d_ws, size_t ws_size,
                              hipStream_t stream) {
    const float* poly = (const float*)d_in[0];
    const float* W0 = (const float*)d_in[1];
    const float* b0 = (const float*)d_in[2];
    const float* g0 = (const float*)d_in[3];
    const float* be0 = (const float*)d_in[4];
    const float* W1 = (const float*)d_in[5];
    const float* b1 = (const float*)d_in[6];
    const float* g1 = (const float*)d_in[7];
    const float* be1 = (const float*)d_in[8];
    const float* W2 = (const float*)d_in[9];
    const float* b2 = (const float*)d_in[10];
    const float* g2 = (const float*)d_in[11];
    const float* be2 = (const float*)d_in[12];
    const float* W3 = (const float*)d_in[13];
    const float* b3 = (const float*)d_in[14];
    const float* g3 = (const float*)d_in[15];
    const float* be3 = (const float*)d_in[16];
    const float* W4 = (const float*)d_in[17];
    const float* b4 = (const float*)d_in[18];
    float* out = (float*)d_out;

    float* st = (float*)d_ws;
    float* accum = st + 1048576;            // 4 layers x 256 floats
    ushort_t* wt1 = (ushort_t*)((char*)d_ws + 4263936);         // 128 x 256
    ushort_t* wt2 = wt1 + 128 * 256;                            // 128 x 128
    ushort_t* wt3 = wt2 + 128 * 128;                            // 128 x 128
    ushort_t* wt4 = wt3 + 128 * 128;                            // 64 x 128
    ushort_t* h0 = (ushort_t*)((char*)d_ws + 4263936 + 147456);
    ushort_t* y1 = (ushort_t*)out;   // d_out doubles as y1 scratch (M*128 bf16
                                     // == out_size bytes); overwritten by L4.

    const int GP = M_ROWS / (64 * 8);   // 512 (persistent kernels, RPT=8)

    // zero all stat accumulators (4 layers x 256 floats) before any atomics
    hipMemsetAsync(accum, 0, 1024 * sizeof(float), stream);

    // Layer 0 (fp32 precision): y0 = poly @ W0 + b0 -> h0 (raw bf16) + stats(accum)
    gemm_f32_k<32, 128, 8><<<GP, 256, 0, stream>>>(poly, W0, b0, h0, accum);
    transpose_all_k<<<288, 256, 0, stream>>>(W1, W2, W3, W4, wt1, wt2, wt3, wt4);

    // Layer 1 (FUSED scan): y1 = [bnrelu0(y0), cummax(bnrelu0(y0))] @ W1 + b1
    //   -> d_out scratch; BN0 finalize folded in; stats -> accum+256
    gemm1s_k<8><<<2 * GP, 256, 0, stream>>>(h0, wt1, b1, g0, be0, accum,
                                            y1, accum + 256);

    // Layer 2: y2 = bnrelu1(y1) @ W2 + b2 : d_out -> h0; stats -> accum+512
    mfma_gemm3_k<128, 1, 1, 8, ushort_t><<<GP, 256, 0, stream>>>(
        y1, wt2, b2, g1, be1, accum + 256, h0, accum + 512);

    // Layer 3 (FUSED scan): y3 = cummax(bnrelu2(y2)) @ W3 + b3 -> h0 in place;
    //   BN2 finalize folded in; stats -> accum+768
    mfma_gemm3_k<128, 2, 1, 8, ushort_t><<<GP, 256, 0, stream>>>(
        h0, wt3, b3, g2, be2, accum + 512, h0, accum + 768);

    // Layer 4: out = bnrelu3(y3) @ W4 + b4 -> d_out (fp32; overwrites y1 scratch)
    mfma_gemm3_k<64, 1, 0, 8, float><<<GP, 256, 0, stream>>>(
        h0, wt4, b4, g3, be3, accum + 768, out, nullptr);
}

// Round 12
// 311.450 us; speedup vs baseline: 2.3334x; 1.0398x over previous
//
#include <hip/hip_runtime.h>
#include <hip/hip_bf16.h>

// Problem constants (fixed by setup_inputs)
#define M_ROWS 262144   // B*A*T = 16*64*256
#define TILE_M 64
#define BK 32
#define INVM (1.0f / 262144.0f)

typedef unsigned short ushort_t;
typedef unsigned int uint_t;
typedef __attribute__((ext_vector_type(8))) short short8_t;   // 8 bf16 = 4 VGPRs
typedef __attribute__((ext_vector_type(4))) float float4_t;   // MFMA acc

// bf16 (stored as ushort) <-> fp32 helpers. Load is exact; store is RNE.
__device__ __forceinline__ float b2f(ushort_t u) {
    union { uint_t i; float f; } c; c.i = ((uint_t)u) << 16; return c.f;
}
__device__ __forceinline__ ushort_t f2b(float f) {
    union { float f; uint_t i; } c; c.f = f;
    uint_t u = c.i;
    return (ushort_t)((u + 0x7fffu + ((u >> 16) & 1u)) >> 16);
}
// packed 2xfp32 -> 2xbf16 (v_cvt_pk_bf16_f32 on gfx950, RNE)
__device__ __forceinline__ uint_t pack2(float a, float b) {
    union { __hip_bfloat162 h; uint_t u; } c;
    c.h = __float22bfloat162_rn(make_float2(a, b));
    return c.u;
}

// async global->LDS DMA, 16 B per lane; data lands at ldsbase + lane*16
__device__ __forceinline__ void gld_lds16(const ushort_t* g, ushort_t* l) {
    __builtin_amdgcn_global_load_lds((const __attribute__((address_space(1))) void*)g,
                                     (__attribute__((address_space(3))) void*)l, 16, 0, 0);
}

// BN finalize arithmetic (shared by all consumers): from accumulated sum/sumsq.
__device__ __forceinline__ void bn_coeff(float s, float q, float g, float be,
                                         float& sc, float& sh) {
    float mean = s * INVM;
    float var = q * INVM - mean * mean;
    sc = g * rsqrtf(var + 1e-5f);
    sh = fmaf(-mean, sc, be);
}

// ---------------------------------------------------------------------------
// Layer-1 N-SPLIT pipelined GEMM with FUSED causal-cummax:
//   C = [bnrelu0(X), cummax(bnrelu0(X))] @ W1 + b1  (K=256), X read ONCE.
// Grid = 1024 blocks: blockIdx = tile*2 + nhalf; each block = 64-col half of
// N=128 over RPT=8 row-tiles (512 rows = 2 whole sequences, in order).
// Per tile: PASS1 = act whole tile IN PLACE (once per element) + local 16-row
// scan into regs + group totals -> kt0 MFMA reads PRE-ACTIVATED frags (act
// block deleted; it was 2x-duplicated across wn waves) -> PASS2 = prefix-
// combine + write P in place (+carry) -> kt1 MFMA reads P frags.
// Prefetch DMA issued at loop-top (full-tile overlap window).
// BN coeffs computed in-block from accumIn; stats atomicAdd into accumOut.
// ---------------------------------------------------------------------------
template<int RPT>
__launch_bounds__(256)
__global__ void gemm1s_k(const ushort_t* __restrict__ X,
                         const ushort_t* __restrict__ WT, const float* __restrict__ bias,
                         const float* __restrict__ g, const float* __restrict__ be,
                         const float* __restrict__ accumIn,
                         ushort_t* __restrict__ C, float* __restrict__ accumOut) {
    __shared__ __attribute__((aligned(16))) ushort_t Bs[64 * 256];       // 32 KB
    __shared__ __attribute__((aligned(16))) ushort_t Abuf[2][64 * 128];  // 2x16 KB
    __shared__ float sred[4 * 64 * 2];
    __shared__ float s_sc[128], s_sh[128];
    __shared__ float gtb[4 * 128];    // scan group totals
    __shared__ float carry[128];      // inter-tile scan carry

    const int tid = threadIdx.x;
    const int lane = tid & 63;
    const int wave = tid >> 6;
    const int wm = wave & 1, wn = wave >> 1;
    const int quad = lane >> 4, l16 = lane & 15;
    const int srow = lane >> 4, sp16 = lane & 15;   // A staging
    const int brow = lane >> 5, bs32 = lane & 31;   // B staging (512 B rows)
    const int tileId = blockIdx.x >> 1;
    const int n0 = (blockIdx.x & 1) * 64;           // column-half offset
    const int row0 = tileId * (RPT * 64);

    if (tid < 128) {
        float sc, sh;
        bn_coeff(accumIn[tid], accumIn[128 + tid], g[tid], be[tid], sc, sh);
        s_sc[tid] = sc; s_sh[tid] = sh;
    }

    // ---- stage B half (rows n0..n0+63 of WT, 512 B each): 32 chunks x 1 KB ----
    #pragma unroll
    for (int i = 0; i < 8; ++i) {
        int t = i * 4 + wave;
        int r = t * 2 + brow;                        // local B row 0..63
        int sp = (bs32 & 16) | ((bs32 ^ r) & 15);    // half-preserving XOR swizzle
        gld_lds16(WT + (size_t)(n0 + r) * 256 + sp * 8, Bs + t * 512);
    }

    auto stageX = [&](int it, int buf) {
        int r0 = row0 + it * 64;
        #pragma unroll
        for (int i = 0; i < 4; ++i) {
            int t = i * 4 + wave;
            int r = t * 4 + srow;
            int sp = sp16 ^ (r & 15);
            gld_lds16(X + (size_t)(r0 + r) * 128 + sp * 8, Abuf[buf] + t * 512);
        }
    };
    stageX(0, 0);

    float bvs[2];
    #pragma unroll
    for (int nt = 0; nt < 2; ++nt) bvs[nt] = bias[n0 + wn * 32 + nt * 16 + l16];
    float sSum[2] = {0.f, 0.f}, sSq[2] = {0.f, 0.f};

    const int j0 = lane >> 2;          // scan addressing: chunk within row
    const int of2 = (lane & 3) * 2;    // ushort offset within chunk (2 cols)
    __syncthreads();   // order s_sc/s_sh writes (tid<128) before hoisted reads
    const float ssc0 = s_sc[2 * lane], ssh0 = s_sh[2 * lane];
    const float ssc1 = s_sc[2 * lane + 1], ssh1 = s_sh[2 * lane + 1];

    for (int it = 0; it < RPT; ++it) {
        __syncthreads();   // (A) X(it) resident; prior epi-store reads done
        if (it + 1 < RPT) stageX(it + 1, (it + 1) & 1);   // DMA overlaps whole tile
        const ushort_t* As = Abuf[it & 1];

        // ---- PASS 1: act whole tile in place + local scan (rows wave*16..+15)
        float pv0[16], pv1[16];
        float base0, base1, lv0 = 0.f, lv1 = 0.f;
        {
            if (it & 3) { base0 = carry[2 * lane]; base1 = carry[2 * lane + 1]; }
            else        { base0 = 0.f; base1 = 0.f; }   // sequence boundary
            ushort_t* Aw = (ushort_t*)Abuf[it & 1];
            #pragma unroll
            for (int i = 0; i < 16; ++i) {
                int r = wave * 16 + i;
                uint_t u = *(const uint_t*)&Aw[r * 128 + ((j0 ^ (r & 15)) * 8) + of2];
                float a0v = fmaxf(fmaf(b2f((ushort_t)(u & 0xffff)), ssc0, ssh0), 0.f);
                float a1v = fmaxf(fmaf(b2f((ushort_t)(u >> 16)), ssc1, ssh1), 0.f);
                *(uint_t*)&Aw[r * 128 + ((j0 ^ (r & 15)) * 8) + of2] = pack2(a0v, a1v);
                lv0 = fmaxf(lv0, a0v);
                lv1 = fmaxf(lv1, a1v);
                pv0[i] = lv0; pv1[i] = lv1;
            }
            gtb[wave * 128 + 2 * lane] = lv0;
            gtb[wave * 128 + 2 * lane + 1] = lv1;
        }
        __syncthreads();   // (B1) act'd tile + group totals visible; carry reads done

        float4_t acc[2][2];
        #pragma unroll
        for (int mt = 0; mt < 2; ++mt)
            #pragma unroll
            for (int nt = 0; nt < 2; ++nt) acc[mt][nt] = (float4_t)0.f;

        // ---- kt0: PRE-ACTIVATED fragments; B kt=0 half (no act block) ----
        #pragma unroll
        for (int kk = 0; kk < 4; ++kk) {
            int j = kk * 4 + quad;
            short8_t a0 = *(const short8_t*)&As[(wm * 32 + l16) * 128 + ((j ^ l16) * 8)];
            short8_t a1 = *(const short8_t*)&As[(wm * 32 + 16 + l16) * 128 + ((j ^ l16) * 8)];
            #pragma unroll
            for (int nt = 0; nt < 2; ++nt) {
                int br = wn * 32 + nt * 16 + l16;
                short8_t bf = *(const short8_t*)&Bs[br * 256 + ((j ^ l16) * 8)];
                acc[0][nt] = __builtin_amdgcn_mfma_f32_16x16x32_bf16(a0, bf, acc[0][nt], 0, 0, 0);
                acc[1][nt] = __builtin_amdgcn_mfma_f32_16x16x32_bf16(a1, bf, acc[1][nt], 0, 0, 0);
            }
        }
        __syncthreads();   // (B2) kt0 fragment reads done

        // ---- PASS 2: prefix-combine + write P in place ----
        {
            float o0 = base0, o1 = base1;
            for (int gg = 0; gg < wave; ++gg) {
                o0 = fmaxf(o0, gtb[gg * 128 + 2 * lane]);
                o1 = fmaxf(o1, gtb[gg * 128 + 2 * lane + 1]);
            }
            if (wave == 3) {   // next-tile carry (old-carry reads were pre-B1)
                carry[2 * lane]     = fmaxf(o0, lv0);
                carry[2 * lane + 1] = fmaxf(o1, lv1);
            }
            ushort_t* Aw = (ushort_t*)Abuf[it & 1];
            #pragma unroll
            for (int i = 0; i < 16; ++i) {
                int r = wave * 16 + i;
                *(uint_t*)&Aw[r * 128 + ((j0 ^ (r & 15)) * 8) + of2] =
                    pack2(fmaxf(pv0[i], o0), fmaxf(pv1[i], o1));
            }
        }
        __syncthreads();   // (C) P visible

        // ---- kt1: P fragments; B kt=1 half ----
        #pragma unroll
        for (int kk = 0; kk < 4; ++kk) {
            int j = kk * 4 + quad;
            short8_t a0 = *(const short8_t*)&As[(wm * 32 + l16) * 128 + ((j ^ l16) * 8)];
            short8_t a1 = *(const short8_t*)&As[(wm * 32 + 16 + l16) * 128 + ((j ^ l16) * 8)];
            #pragma unroll
            for (int nt = 0; nt < 2; ++nt) {
                int br = wn * 32 + nt * 16 + l16;
                short8_t bf = *(const short8_t*)&Bs[br * 256 + 128 + ((j ^ l16) * 8)];
                acc[0][nt] = __builtin_amdgcn_mfma_f32_16x16x32_bf16(a0, bf, acc[0][nt], 0, 0, 0);
                acc[1][nt] = __builtin_amdgcn_mfma_f32_16x16x32_bf16(a1, bf, acc[1][nt], 0, 0, 0);
            }
        }

        // ---- bias + stats accumulate ----
        #pragma unroll
        for (int mt = 0; mt < 2; ++mt)
            #pragma unroll
            for (int nt = 0; nt < 2; ++nt)
                #pragma unroll
                for (int r = 0; r < 4; ++r) {
                    float v = acc[mt][nt][r] + bvs[nt];
                    acc[mt][nt][r] = v;
                    sSum[nt] += v; sSq[nt] = fmaf(v, v, sSq[nt]);
                }
        if (it == RPT - 1) {
            #pragma unroll
            for (int nt = 0; nt < 2; ++nt) {
                float s = sSum[nt], q = sSq[nt];
                s += __shfl_xor(s, 16); q += __shfl_xor(q, 16);
                s += __shfl_xor(s, 32); q += __shfl_xor(q, 32);
                if (lane < 16) {
                    int colL = wn * 32 + nt * 16 + l16;
                    sred[(wave * 64 + colL) * 2 + 0] = s;
                    sred[(wave * 64 + colL) * 2 + 1] = q;
                }
            }
        }
        __syncthreads();   // (D) kt1 reads of Abuf done; sred visible

        // ---- swizzled transpose into Abuf[it&1] (dead after kt1) ----
        char* eb = (char*)Abuf[it & 1];
        #pragma unroll
        for (int mt = 0; mt < 2; ++mt)
            #pragma unroll
            for (int nt = 0; nt < 2; ++nt) {
                int colL = wn * 32 + nt * 16 + l16;
                int bc = colL * 2;
                #pragma unroll
                for (int r = 0; r < 4; ++r) {
                    int row = wm * 32 + mt * 16 + quad * 4 + r;
                    int addr = row * 128 + ((((bc >> 4) ^ (row & 7)) << 4) | (bc & 15));
                    *(ushort_t*)(eb + addr) = f2b(acc[mt][nt][r]);
                }
            }
        if (it == RPT - 1 && tid < 128) {
            int colL = tid & 63, qs = tid >> 6;
            int wb = (colL >> 5) * 2;   // the two waves (wm=0,1) owning this col
            float v = sred[(wb * 64 + colL) * 2 + qs] + sred[((wb + 1) * 64 + colL) * 2 + qs];
            atomicAdd(accumOut + qs * 128 + n0 + colL, v);
        }
        __syncthreads();   // (E) epi tile resident

        // ---- coalesced 16 B stores of the 64-col half (128 B per row) ----
        int r0s = row0 + it * 64;
        #pragma unroll
        for (int p = 0; p < 2; ++p) {
            int s = p * 256 + tid;
            int row = s >> 3, gg2 = s & 7;
            uint4 v = *(const uint4*)(eb + row * 128 + ((gg2 ^ (row & 7)) << 4));
            *(uint4*)((char*)(C + (size_t)(r0s + row) * 128 + n0) + gg2 * 16) = v;
        }
    }
}

// ---------------------------------------------------------------------------
// Persistent pipelined MFMA GEMM for K=128 layers: C = act(A)@W + bias.
// MODE==1: act-on-fragments (coeffs from accumIn).
// MODE==2: FUSED act+causal-cummax via 4-wave segmented scan before MFMA
//          (local 16-row chains in regs + group-total prefix + carry).
// ---------------------------------------------------------------------------
template<int N, int MODE, int STATS, int RPT, typename CT>
__launch_bounds__(256)
__global__ void mfma_gemm3_k(const ushort_t* __restrict__ A, const ushort_t* __restrict__ WT,
                             const float* __restrict__ bias,
                             const float* __restrict__ g, const float* __restrict__ be,
                             const float* __restrict__ accumIn,
                             CT* __restrict__ C, float* __restrict__ accumOut) {
    constexpr int WN = N / 2;        // cols per wave-column (64 or 32)
    constexpr int NT = WN / 16;      // 4 (N=128) or 2 (N=64)

    __shared__ __attribute__((aligned(16))) ushort_t Bs[N * 128];
    __shared__ __attribute__((aligned(16))) ushort_t Abuf[2][64 * 128];
    __shared__ float sred[STATS ? 4 * N * 2 : 1];
    __shared__ float s_sc[MODE >= 1 ? 128 : 1];
    __shared__ float s_sh[MODE >= 1 ? 128 : 1];
    __shared__ float gtb[MODE == 2 ? 4 * 128 : 1];
    __shared__ float carry[MODE == 2 ? 128 : 1];

    const int tid = threadIdx.x;
    const int lane = tid & 63;
    const int wave = tid >> 6;
    const int wm = wave & 1;
    const int wn = wave >> 1;
    const int quad = lane >> 4;
    const int l16 = lane & 15;
    const int srow = lane >> 4;
    const int sp16 = lane & 15;

    if (MODE >= 1 && tid < 128) {
        float sc, sh;
        bn_coeff(accumIn[tid], accumIn[128 + tid], g[tid], be[tid], sc, sh);
        s_sc[tid] = sc; s_sh[tid] = sh;
    }

    #pragma unroll
    for (int i = 0; i < N / 16; ++i) {
        int t = i * 4 + wave;
        int r = t * 4 + srow;
        int sp = sp16 ^ (r & 15);
        gld_lds16(WT + (size_t)r * 128 + sp * 8, Bs + t * 512);
    }
    {
        int r0 = blockIdx.x * (RPT * 64);
        #pragma unroll
        for (int i = 0; i < 4; ++i) {
            int t = i * 4 + wave;
            int r = t * 4 + srow;
            int sp = sp16 ^ (r & 15);
            gld_lds16(A + (size_t)(r0 + r) * 128 + sp * 8, Abuf[0] + t * 512);
        }
    }

    float bvs[NT];
    #pragma unroll
    for (int nt = 0; nt < NT; ++nt) bvs[nt] = bias[wn * WN + nt * 16 + l16];
    float sSum[STATS ? NT : 1] = {0.f}, sSq[STATS ? NT : 1] = {0.f};

    const int j0 = lane >> 2;
    const int of2 = (lane & 3) * 2;

    for (int it = 0; it < RPT; ++it) {
        __syncthreads();   // tile resident; prior epi-store reads done

        if (it + 1 < RPT) {
            int r0 = blockIdx.x * (RPT * 64) + (it + 1) * 64;
            #pragma unroll
            for (int i = 0; i < 4; ++i) {
                int t = i * 4 + wave;
                int r = t * 4 + srow;
                int sp = sp16 ^ (r & 15);
                gld_lds16(A + (size_t)(r0 + r) * 128 + sp * 8, Abuf[(it + 1) & 1] + t * 512);
            }
        }

        if constexpr (MODE == 2) {
            // ---- 4-wave segmented scan: pass 1 (local act+cummax) ----
            float pv0[16], pv1[16];
            float base0, base1, lv0 = 0.f, lv1 = 0.f;
            float ssc0 = s_sc[2 * lane], ssh0 = s_sh[2 * lane];
            float ssc1 = s_sc[2 * lane + 1], ssh1 = s_sh[2 * lane + 1];
            {
                if (it & 3) { base0 = carry[2 * lane]; base1 = carry[2 * lane + 1]; }
                else        { base0 = 0.f; base1 = 0.f; }
                ushort_t* Aw = (ushort_t*)Abuf[it & 1];
                #pragma unroll
                for (int i = 0; i < 16; ++i) {
                    int r = wave * 16 + i;
                    uint_t u = *(const uint_t*)&Aw[r * 128 + ((j0 ^ (r & 15)) * 8) + of2];
                    lv0 = fmaxf(lv0, fmaxf(fmaf(b2f((ushort_t)(u & 0xffff)), ssc0, ssh0), 0.f));
                    lv1 = fmaxf(lv1, fmaxf(fmaf(b2f((ushort_t)(u >> 16)), ssc1, ssh1), 0.f));
                    pv0[i] = lv0; pv1[i] = lv1;
                }
                gtb[wave * 128 + 2 * lane] = lv0;
                gtb[wave * 128 + 2 * lane + 1] = lv1;
            }
            __syncthreads();   // group totals visible; carry reads done
            {
                float o0 = base0, o1 = base1;
                for (int gg = 0; gg < wave; ++gg) {
                    o0 = fmaxf(o0, gtb[gg * 128 + 2 * lane]);
                    o1 = fmaxf(o1, gtb[gg * 128 + 2 * lane + 1]);
                }
                if (wave == 3) {
                    carry[2 * lane]     = fmaxf(o0, lv0);
                    carry[2 * lane + 1] = fmaxf(o1, lv1);
                }
                ushort_t* Aw = (ushort_t*)Abuf[it & 1];
                #pragma unroll
                for (int i = 0; i < 16; ++i) {
                    int r = wave * 16 + i;
                    *(uint_t*)&Aw[r * 128 + ((j0 ^ (r & 15)) * 8) + of2] =
                        pack2(fmaxf(pv0[i], o0), fmaxf(pv1[i], o1));
                }
            }
            __syncthreads();   // P visible to all waves
        }

        const ushort_t* As = Abuf[it & 1];

        float4_t acc[2][NT];
        #pragma unroll
        for (int mt = 0; mt < 2; ++mt)
            #pragma unroll
            for (int nt = 0; nt < NT; ++nt) acc[mt][nt] = (float4_t)0.f;

        #pragma unroll
        for (int kk = 0; kk < 4; ++kk) {
            int j = kk * 4 + quad;
            short8_t a0 = *(const short8_t*)&As[(wm * 32 + l16) * 128 + ((j ^ l16) * 8)];
            short8_t a1 = *(const short8_t*)&As[(wm * 32 + 16 + l16) * 128 + ((j ^ l16) * 8)];
            if (MODE == 1) {
                int kb = kk * 32 + quad * 8;
                float4 c0 = *(const float4*)&s_sc[kb], c1 = *(const float4*)&s_sc[kb + 4];
                float4 h0 = *(const float4*)&s_sh[kb], h1 = *(const float4*)&s_sh[kb + 4];
                #pragma unroll
                for (int z = 0; z < 2; ++z) {
                    ushort_t u[8];
                    *(short8_t*)u = z ? a1 : a0;
                    uint_t w[4];
                    w[0] = pack2(fmaxf(fmaf(b2f(u[0]), c0.x, h0.x), 0.f),
                                 fmaxf(fmaf(b2f(u[1]), c0.y, h0.y), 0.f));
                    w[1] = pack2(fmaxf(fmaf(b2f(u[2]), c0.z, h0.z), 0.f),
                                 fmaxf(fmaf(b2f(u[3]), c0.w, h0.w), 0.f));
                    w[2] = pack2(fmaxf(fmaf(b2f(u[4]), c1.x, h1.x), 0.f),
                                 fmaxf(fmaf(b2f(u[5]), c1.y, h1.y), 0.f));
                    w[3] = pack2(fmaxf(fmaf(b2f(u[6]), c1.z, h1.z), 0.f),
                                 fmaxf(fmaf(b2f(u[7]), c1.w, h1.w), 0.f));
                    short8_t rr;
                    *(uint4*)&rr = *(const uint4*)w;
                    if (z) a1 = rr; else a0 = rr;
                }
            }
            #pragma unroll
            for (int nt = 0; nt < NT; ++nt) {
                short8_t bf = *(const short8_t*)&Bs[(wn * WN + nt * 16 + l16) * 128 + ((j ^ l16) * 8)];
                acc[0][nt] = __builtin_amdgcn_mfma_f32_16x16x32_bf16(a0, bf, acc[0][nt], 0, 0, 0);
                acc[1][nt] = __builtin_amdgcn_mfma_f32_16x16x32_bf16(a1, bf, acc[1][nt], 0, 0, 0);
            }
        }

        #pragma unroll
        for (int mt = 0; mt < 2; ++mt)
            #pragma unroll
            for (int nt = 0; nt < NT; ++nt)
                #pragma unroll
                for (int r = 0; r < 4; ++r) {
                    float v = acc[mt][nt][r] + bvs[nt];
                    acc[mt][nt][r] = v;
                    if (STATS) { sSum[nt] += v; sSq[nt] = fmaf(v, v, sSq[nt]); }
                }
        if (STATS && it == RPT - 1) {
            #pragma unroll
            for (int nt = 0; nt < NT; ++nt) {
                float s = sSum[nt], q = sSq[nt];
                s += __shfl_xor(s, 16); q += __shfl_xor(q, 16);
                s += __shfl_xor(s, 32); q += __shfl_xor(q, 32);
                if (lane < 16) {
                    int col = wn * WN + nt * 16 + l16;
                    sred[(wave * N + col) * 2 + 0] = s;
                    sred[(wave * N + col) * 2 + 1] = q;
                }
            }
        }
        __syncthreads();

        char* eb = (char*)Abuf[it & 1];
        #pragma unroll
        for (int mt = 0; mt < 2; ++mt)
            #pragma unroll
            for (int nt = 0; nt < NT; ++nt) {
                int col = wn * WN + nt * 16 + l16;
                int bc = col * (int)sizeof(CT);
                #pragma unroll
                for (int r = 0; r < 4; ++r) {
                    int row = wm * 32 + mt * 16 + quad * 4 + r;
                    int addr = row * 256 + ((((bc >> 4) ^ (row & 15)) << 4) | (bc & 15));
                    if constexpr (sizeof(CT) == 4) *(float*)(eb + addr) = acc[mt][nt][r];
                    else                           *(ushort_t*)(eb + addr) = f2b(acc[mt][nt][r]);
                }
            }
        if (STATS && it == RPT - 1) {
            int col = tid & (N - 1), qs = tid / N;
            int wb = (col / WN) * 2;
            float v = sred[(wb * N + col) * 2 + qs] + sred[((wb + 1) * N + col) * 2 + qs];
            atomicAdd(accumOut + qs * 128 + col, v);
        }
        __syncthreads();

        int r0 = blockIdx.x * (RPT * 64) + it * 64;
        #pragma unroll
        for (int p = 0; p < 4; ++p) {
            int s = p * 256 + tid;
            int row = s >> 4, gg2 = s & 15;
            uint4 v = *(const uint4*)(eb + row * 256 + ((gg2 ^ (row & 15)) << 4));
            *(uint4*)((char*)(C + (size_t)(r0 + row) * N) + gg2 * 16) = v;
        }
    }
}

// ---------------------------------------------------------------------------
// fp32 vector GEMM (layer 0: K=32, fp32 input), grid-strided over RPT row
// tiles per block. Weights staged ONCE; A-tile async-stage split (issue loads
// early, ds_write late). Stats in registers across tiles -> one LDS reduce +
// 256 atomics per block (512 blocks -> 131K atomics, proven-safe count).
// ---------------------------------------------------------------------------
template<int K, int N, int RPT>
__launch_bounds__(256)
__global__ void gemm_f32_k(const float* __restrict__ A, const float* __restrict__ W,
                           const float* __restrict__ bias, ushort_t* __restrict__ C,
                           float* __restrict__ accum) {
    constexpr int TX = N / 4;        // 32
    constexpr int TY = 256 / TX;     // 8
    constexpr int RM = TILE_M / TY;  // 8

    __shared__ float As[2][TILE_M][BK + 1];
    __shared__ float Ws[BK][N];
    __shared__ float redst[2][TY][N];

    const int tid = threadIdx.x;
    const int tx = tid % TX;
    const int ty = tid / TX;
    const int row0 = blockIdx.x * (RPT * TILE_M);
    const int arow = tid >> 2;
    const int acol = (tid & 3) * 8;

    // ---- stage weights once (K=32 -> whole K fits one tile) ----
    #pragma unroll
    for (int i = 0; i < (BK * N) / 256; ++i) {
        int e = i * 256 + tid;
        Ws[e / N][e % N] = W[(size_t)(e / N) * N + e % N];
    }
    // ---- preload tile 0 A ----
    {
        const float4* p = (const float4*)&A[(size_t)(row0 + arow) * K + acol];
        float4 x0 = p[0], x1 = p[1];
        As[0][arow][acol + 0] = x0.x; As[0][arow][acol + 1] = x0.y;
        As[0][arow][acol + 2] = x0.z; As[0][arow][acol + 3] = x0.w;
        As[0][arow][acol + 4] = x1.x; As[0][arow][acol + 5] = x1.y;
        As[0][arow][acol + 6] = x1.z; As[0][arow][acol + 7] = x1.w;
    }

    float4 bv = *(const float4*)&bias[tx * 4];
    float s[4] = {0, 0, 0, 0}, q[4] = {0, 0, 0, 0};

    for (int it = 0; it < RPT; ++it) {
        __syncthreads();   // As[it&1] (and Ws on it=0) resident
        // issue next tile's loads EARLY (latency hides under FMA loop)
        float4 nx0, nx1;
        if (it + 1 < RPT) {
            const float4* p = (const float4*)&A[(size_t)(row0 + (it + 1) * TILE_M + arow) * K + acol];
            nx0 = p[0]; nx1 = p[1];
        }

        float acc[RM][4];
        #pragma unroll
        for (int r = 0; r < RM; ++r)
            #pragma unroll
            for (int c = 0; c < 4; ++c) acc[r][c] = 0.f;
        #pragma unroll
        for (int kk = 0; kk < BK; ++kk) {
            float4 wv = *(const float4*)&Ws[kk][tx * 4];
            #pragma unroll
            for (int r = 0; r < RM; ++r) {
                float a = As[it & 1][ty * RM + r][kk];
                acc[r][0] = fmaf(a, wv.x, acc[r][0]);
                acc[r][1] = fmaf(a, wv.y, acc[r][1]);
                acc[r][2] = fmaf(a, wv.z, acc[r][2]);
                acc[r][3] = fmaf(a, wv.w, acc[r][3]);
            }
        }

        // bias + stats + coalesced bf16 store for this tile
        #pragma unroll
        for (int r = 0; r < RM; ++r) {
            float o[4];
            o[0] = acc[r][0] + bv.x; o[1] = acc[r][1] + bv.y;
            o[2] = acc[r][2] + bv.z; o[3] = acc[r][3] + bv.w;
            #pragma unroll
            for (int c = 0; c < 4; ++c) { s[c] += o[c]; q[c] = fmaf(o[c], o[c], q[c]); }
            size_t off = (size_t)(row0 + it * TILE_M + ty * RM + r) * N + tx * 4;
            uint2 ov;
            ov.x = pack2(o[0], o[1]);
            ov.y = pack2(o[2], o[3]);
            *(uint2*)&C[off] = ov;
        }

        // ds_write the prefetched tile LATE (vmcnt wait lands after compute)
        if (it + 1 < RPT) {
            int b = (it + 1) & 1;
            As[b][arow][acol + 0] = nx0.x; As[b][arow][acol + 1] = nx0.y;
            As[b][arow][acol + 2] = nx0.z; As[b][arow][acol + 3] = nx0.w;
            As[b][arow][acol + 4] = nx1.x; As[b][arow][acol + 5] = nx1.y;
            As[b][arow][acol + 6] = nx1.z; As[b][arow][acol + 7] = nx1.w;
        }
    }

    __syncthreads();   // As reads done; redst region free
    #pragma unroll
    for (int c = 0; c < 4; ++c) {
        redst[0][ty][tx * 4 + c] = s[c];
        redst[1][ty][tx * 4 + c] = q[c];
    }
    __syncthreads();
    {
        int col = tid & (N - 1), qs = tid / N;
        float v = 0.f;
        #pragma unroll
        for (int t = 0; t < TY; ++t) v += redst[qs][t][col];
        atomicAdd(accum + qs * 128 + col, v);
    }
}

// All four weight transposes in one launch: fp32 W[K][N] -> bf16 WT[N][K]
__global__ void transpose_all_k(const float* __restrict__ W1, const float* __restrict__ W2,
                                const float* __restrict__ W3, const float* __restrict__ W4,
                                ushort_t* __restrict__ wt1, ushort_t* __restrict__ wt2,
                                ushort_t* __restrict__ wt3, ushort_t* __restrict__ wt4) {
    int idx = blockIdx.x * 256 + threadIdx.x;
    if (idx < 32768) {                       // W1: 256 x 128
        int k = idx >> 7, n = idx & 127;
        wt1[(size_t)n * 256 + k] = f2b(W1[idx]);
    } else if (idx < 49152) {                // W2: 128 x 128
        int i = idx - 32768;
        int k = i >> 7, n = i & 127;
        wt2[(size_t)n * 128 + k] = f2b(W2[i]);
    } else if (idx < 65536) {                // W3: 128 x 128
        int i = idx - 49152;
        int k = i >> 7, n = i & 127;
        wt3[(size_t)n * 128 + k] = f2b(W3[i]);
    } else if (idx < 73728) {                // W4: 128 x 64
        int i = idx - 65536;
        int k = i >> 6, n = i & 63;
        wt4[(size_t)n * 128 + k] = f2b(W4[i]);
    }
}

extern "C" void kernel_launch(void* const* d_in, const int* in_sizes, int n_in,
                              void* d_out, int out_size, void* d_ws, size_t ws_size,
                              hipStream_t stream) {
    const float* poly = (const float*)d_in[0];
    const float* W0 = (const float*)d_in[1];
    const float* b0 = (const float*)d_in[2];
    const float* g0 = (const float*)d_in[3];
    const float* be0 = (const float*)d_in[4];
    const float* W1 = (const float*)d_in[5];
    const float* b1 = (const float*)d_in[6];
    const float* g1 = (const float*)d_in[7];
    const float* be1 = (const float*)d_in[8];
    const float* W2 = (const float*)d_in[9];
    const float* b2 = (const float*)d_in[10];
    const float* g2 = (const float*)d_in[11];
    const float* be2 = (const float*)d_in[12];
    const float* W3 = (const float*)d_in[13];
    const float* b3 = (const float*)d_in[14];
    const float* g3 = (const float*)d_in[15];
    const float* be3 = (const float*)d_in[16];
    const float* W4 = (const float*)d_in[17];
    const float* b4 = (const float*)d_in[18];
    float* out = (float*)d_out;

    float* st = (float*)d_ws;
    float* accum = st + 1048576;            // 4 layers x 256 floats
    ushort_t* wt1 = (ushort_t*)((char*)d_ws + 4263936);         // 128 x 256
    ushort_t* wt2 = wt1 + 128 * 256;                            // 128 x 128
    ushort_t* wt3 = wt2 + 128 * 128;                            // 128 x 128
    ushort_t* wt4 = wt3 + 128 * 128;                            // 64 x 128
    ushort_t* h0 = (ushort_t*)((char*)d_ws + 4263936 + 147456);
    ushort_t* y1 = (ushort_t*)out;   // d_out doubles as y1 scratch (M*128 bf16
                                     // == out_size bytes); overwritten by L4.

    const int GP = M_ROWS / (64 * 8);   // 512 (persistent kernels, RPT=8)

    // zero all stat accumulators (4 layers x 256 floats) before any atomics
    hipMemsetAsync(accum, 0, 1024 * sizeof(float), stream);

    // Layer 0 (fp32 precision): y0 = poly @ W0 + b0 -> h0 (raw bf16) + stats(accum)
    gemm_f32_k<32, 128, 8><<<GP, 256, 0, stream>>>(poly, W0, b0, h0, accum);
    transpose_all_k<<<288, 256, 0, stream>>>(W1, W2, W3, W4, wt1, wt2, wt3, wt4);

    // Layer 1 (FUSED scan): y1 = [bnrelu0(y0), cummax(bnrelu0(y0))] @ W1 + b1
    //   -> d_out scratch; BN0 finalize folded in; stats -> accum+256
    gemm1s_k<8><<<2 * GP, 256, 0, stream>>>(h0, wt1, b1, g0, be0, accum,
                                            y1, accum + 256);

    // Layer 2: y2 = bnrelu1(y1) @ W2 + b2 : d_out -> h0; stats -> accum+512
    mfma_gemm3_k<128, 1, 1, 8, ushort_t><<<GP, 256, 0, stream>>>(
        y1, wt2, b2, g1, be1, accum + 256, h0, accum + 512);

    // Layer 3 (FUSED scan): y3 = cummax(bnrelu2(y2)) @ W3 + b3 -> h0 in place;
    //   BN2 finalize folded in; stats -> accum+768
    mfma_gemm3_k<128, 2, 1, 8, ushort_t><<<GP, 256, 0, stream>>>(
        h0, wt3, b3, g2, be2, accum + 512, h0, accum + 768);

    // Layer 4: out = bnrelu3(y3) @ W4 + b4 -> d_out (fp32; overwrites y1 scratch)
    mfma_gemm3_k<64, 1, 0, 8, float><<<GP, 256, 0, stream>>>(
        h0, wt4, b4, g3, be3, accum + 768, out, nullptr);
}